// Round 10
// baseline (549.394 us; speedup 1.0000x reference)
//
#include <hip/hip_runtime.h>
#include <cstddef>

// IPA + surface cross-attention, B=1, N=512, M=2048, H=12, C_H=16, C_S=384.
// Round 9: k_zpass v3 — W in LDS with wave-uniform BROADCAST ds_reads
// (replaces R7's s_load-latency-bound scalar-W loop); grid 4096 single-chunk
// blocks (64 j each), 2 blocks/CU overlap. Rest unchanged from R8.

#define CS 384
#define INFV 100000.0f

__device__ __forceinline__ float softplusf(float x) { return log1pf(__expf(x)); }

// ---------------------------------------------------------------- pack
__global__ __launch_bounds__(256) void k_pack(
    const float* __restrict__ Wq, const float* __restrict__ Wsq,
    const float* __restrict__ Wkv, const float* __restrict__ Wqp,
    const float* __restrict__ Wkvp, const float* __restrict__ Wsk,
    const float* __restrict__ Wsv, const float* __restrict__ Wout,
    const float* __restrict__ bq, const float* __restrict__ bsq,
    const float* __restrict__ bkv, const float* __restrict__ bqp,
    const float* __restrict__ bkvp, const float* __restrict__ bsk,
    const float* __restrict__ bsv,
    float* __restrict__ wt1, float* __restrict__ wt2, float* __restrict__ wt3,
    float* __restrict__ b1, float* __restrict__ b2)
{
    const int b = blockIdx.x, t = threadIdx.x;
    if (b >= 1092) {
        int idx = (b - 1092) * 256 + t;
        if (idx < 1344) {
            float v;
            if (idx < 192) v = bq[idx];
            else if (idx < 384) v = bsq[idx - 192];
            else if (idx < 768) v = bkv[idx - 384];
            else if (idx < 912) v = bqp[idx - 768];
            else v = bkvp[idx - 912];
            b1[idx] = v;
        } else if (idx < 1728) {
            int i2 = idx - 1344;
            b2[i2] = (i2 < 192) ? bsk[i2] : bsv[i2 - 192];
        }
        return;
    }
    const float* src; float* dst; int C, coff, tile, ldd;
    if (b < 72)       { src = Wq;   C = 192; dst = wt1; coff = 0;   ldd = 384;  tile = b; }
    else if (b < 144) { src = Wsq;  C = 192; dst = wt1; coff = 192; ldd = 384;  tile = b - 72; }
    else if (b < 288) { src = Wkv;  C = 384; dst = wt1; coff = 384; ldd = 384;  tile = b - 144; }
    else if (b < 348) { src = Wqp;  C = 144; dst = wt1; coff = 768; ldd = 384;  tile = b - 288; }
    else if (b < 516) { src = Wkvp; C = 432; dst = wt1; coff = 912; ldd = 384;  tile = b - 348; }
    else if (b < 588) { src = Wsk;  C = 192; dst = wt2; coff = 0;   ldd = 384;  tile = b - 516; }
    else if (b < 660) { src = Wsv;  C = 192; dst = wt2; coff = 192; ldd = 384;  tile = b - 588; }
    else              { src = Wout; C = 384; dst = wt3; coff = 0;   ldd = 1152; tile = b - 660; }
    const int cT = (C + 31) >> 5;
    const int tk = tile / cT, tc = tile % cT;
    __shared__ float l[32][33];
    const int tr = t >> 5, tcc = t & 31;
    #pragma unroll
    for (int rr = 0; rr < 4; ++rr) {
        int kloc = tr * 4 + rr;
        int cg = tc * 32 + tcc;
        l[kloc][tcc] = (cg < C) ? src[(size_t)(tk * 32 + kloc) * C + cg] : 0.f;
    }
    __syncthreads();
    #pragma unroll
    for (int rr = 0; rr < 4; ++rr) {
        int cloc = tr * 4 + rr;
        int cg = tc * 32 + cloc;
        if (cg < C) dst[(size_t)(coff + cg) * ldd + tk * 32 + tcc] = l[tcc][cloc];
    }
}

// ---------------------------------------------------------------- packz
__global__ __launch_bounds__(256) void k_packz(
    const float* __restrict__ Wb, const float* __restrict__ bb,
    const float* __restrict__ Wdz, const float* __restrict__ bdz,
    float* __restrict__ wz, float* __restrict__ bz)
{
    const float s3 = 0.5773502691896258f;
    int idx = blockIdx.x * 256 + threadIdx.x;
    if (idx < 5632) {
        int c = idx >> 7, kk = idx & 127;
        wz[idx] = (c < 12) ? s3 * Wb[kk * 12 + c] : Wdz[kk * 32 + (c - 12)];
    } else if (idx < 5676) {
        int c = idx - 5632;
        bz[c] = (c < 12) ? s3 * bb[c] : bdz[c - 12];
    }
}

// ---------------------------------------------------------------- transpose
__global__ __launch_bounds__(256) void k_transp(
    const float* __restrict__ A, float* __restrict__ At)
{
    __shared__ float tile[32][33];
    const int r0 = blockIdx.y * 32, c0 = blockIdx.x * 32;
    const int tr = threadIdx.x >> 5, tc = threadIdx.x & 31;
    #pragma unroll
    for (int rr = 0; rr < 4; ++rr)
        tile[tr + rr * 8][tc] = A[(size_t)(r0 + tr + rr * 8) * 384 + c0 + tc];
    __syncthreads();
    #pragma unroll
    for (int rr = 0; rr < 4; ++rr)
        At[(size_t)(c0 + tr + rr * 8) * 512 + r0 + tc] = tile[tc][tr + rr * 8];
}

// ---------------------------------------------------------------- gemm
template<int KTOT, bool HB>
__global__ __launch_bounds__(256) void k_gemm(
    const float* __restrict__ A, const float* __restrict__ Wt,
    const float* __restrict__ bias, float* __restrict__ C, int ldc)
{
    __shared__ float As[64][68];
    __shared__ float Ws[64][68];
    const int t = threadIdx.x;
    const int c0 = blockIdx.x * 64, m0 = blockIdx.y * 64;
    const int sr = t >> 4, sk4 = (t & 15) << 2;
    const int wid = t >> 6, lane = t & 63;
    const int wr = (wid >> 1) * 32, wc = (wid & 1) * 32;
    const int lr = lane >> 3, lc = lane & 7;
    float acc[4][4];
    #pragma unroll
    for (int j = 0; j < 4; ++j) {
        float bv = HB ? bias[c0 + wc + lc + 8 * j] : 0.f;
        #pragma unroll
        for (int i = 0; i < 4; ++i) acc[i][j] = bv;
    }
    for (int kc = 0; kc < KTOT; kc += 64) {
        __syncthreads();
        #pragma unroll
        for (int rep = 0; rep < 4; ++rep) {
            int row = sr + rep * 16;
            *(float4*)&As[row][sk4] = *(const float4*)&A[(size_t)(m0 + row) * KTOT + kc + sk4];
            *(float4*)&Ws[row][sk4] = *(const float4*)&Wt[(size_t)(c0 + row) * KTOT + kc + sk4];
        }
        __syncthreads();
        #pragma unroll 4
        for (int k4 = 0; k4 < 16; ++k4) {
            float4 a[4], w[4];
            #pragma unroll
            for (int i = 0; i < 4; ++i) a[i] = *(float4*)&As[wr + lr + 8 * i][k4 * 4];
            #pragma unroll
            for (int j = 0; j < 4; ++j) w[j] = *(float4*)&Ws[wc + lc + 8 * j][k4 * 4];
            #pragma unroll
            for (int i = 0; i < 4; ++i) {
                #pragma unroll
                for (int j = 0; j < 4; ++j) {
                    acc[i][j] = fmaf(a[i].x, w[j].x, acc[i][j]);
                    acc[i][j] = fmaf(a[i].y, w[j].y, acc[i][j]);
                    acc[i][j] = fmaf(a[i].z, w[j].z, acc[i][j]);
                    acc[i][j] = fmaf(a[i].w, w[j].w, acc[i][j]);
                }
            }
        }
    }
    #pragma unroll
    for (int i = 0; i < 4; ++i) {
        #pragma unroll
        for (int j = 0; j < 4; ++j)
            C[(size_t)(m0 + wr + lr + 8 * i) * ldc + c0 + wc + lc + 8 * j] = acc[i][j];
    }
}

// ---------------------------------------------------------------- scatter
__global__ __launch_bounds__(256) void k_scatter(
    const float* __restrict__ proj, const float* __restrict__ rots,
    const float* __restrict__ trans,
    float* __restrict__ qw, float* __restrict__ kw, float* __restrict__ vw,
    float* __restrict__ sqw, float* __restrict__ qpw, float* __restrict__ kpw,
    float* __restrict__ vpw)
{
    __shared__ float p[4][1344];
    const int n0 = blockIdx.x * 4, t = threadIdx.x;
    for (int idx = t; idx < 1344; idx += 256) {
        #pragma unroll
        for (int r = 0; r < 4; ++r) p[r][idx] = proj[(size_t)(n0 + r) * 1344 + idx];
    }
    __syncthreads();
    for (int idx = t; idx < 3072; idx += 256) {
        int r = idx / 768, c = idx % 768;
        int n = n0 + r;
        float v = p[r][c];
        if (c < 192) qw[(size_t)n * 192 + c] = v;
        else if (c < 384) sqw[(size_t)n * 192 + (c - 192)] = v;
        else {
            int cc = c - 384, h = cc >> 5, sub = cc & 31;
            if (sub < 16) kw[(size_t)n * 192 + h * 16 + sub] = v;
            else          vw[(size_t)n * 192 + h * 16 + (sub - 16)] = v;
        }
    }
    for (int idx = t; idx < 2304; idx += 256) {
        int r = idx / 576, rem = idx % 576;
        int n = n0 + r;
        const float* R = &rots[(size_t)n * 9];
        const float* tr = &trans[(size_t)n * 3];
        if (rem < 144) {
            int pp = rem / 3, d = rem % 3;
            float v = fmaf(R[d*3+0], p[r][768 + pp],
                      fmaf(R[d*3+1], p[r][768 + 48 + pp],
                      fmaf(R[d*3+2], p[r][768 + 96 + pp], tr[d])));
            qpw[(size_t)n * 144 + pp * 3 + d] = v;
        } else {
            int rem2 = rem - 144; int pp = rem2 / 3, d = rem2 % 3;
            float v = fmaf(R[d*3+0], p[r][912 + pp],
                      fmaf(R[d*3+1], p[r][912 + 144 + pp],
                      fmaf(R[d*3+2], p[r][912 + 288 + pp], tr[d])));
            int h = pp / 12, ii = pp % 12;
            if (ii < 4) kpw[(size_t)n * 144 + h * 12 + ii * 3 + d] = v;
            else        vpw[(size_t)n * 288 + h * 24 + (ii - 4) * 3 + d] = v;
        }
    }
}

// ---------------------------------------------------------------- sfeat
__global__ __launch_bounds__(256) void k_sfeat(
    const float* __restrict__ sf, const float* __restrict__ Wse,
    const float* __restrict__ bse, float* __restrict__ sfeat)
{
    __shared__ float wl[16 * 384];
    __shared__ float sfl[8][16];
    const int m0 = blockIdx.x * 8, t = threadIdx.x;
    for (int idx = t; idx < 6144; idx += 256) wl[idx] = Wse[idx];
    if (t < 128) sfl[t >> 4][t & 15] = sf[(size_t)(m0 + (t >> 4)) * 16 + (t & 15)];
    __syncthreads();
    #pragma unroll
    for (int u = 0; u < 12; ++u) {
        int idx = t + u * 256;
        int r = idx / 384, c = idx % 384;
        float a = bse[c];
        #pragma unroll
        for (int kk = 0; kk < 16; ++kk) a = fmaf(sfl[r][kk], wl[kk * 384 + c], a);
        sfeat[(size_t)(m0 + r) * 384 + c] = a;
    }
}

// ---------------------------------------------------------------- zpass v3
// bpz[i][c][j] = z[i][j][:] @ wz[c][:] + bz[c].
// Grid: 4096 blocks, each owns 64 consecutive global j rows (i uniform).
// W[44][128] in LDS, read via wave-uniform BROADCAST ds_read_b128 (free);
// z tile [64][132] padded. Wave cg owns 11 c's; lane jl owns 1 j.
__global__ __launch_bounds__(256) void k_zpass(
    const float* __restrict__ z, const float* __restrict__ wz,
    const float* __restrict__ bz, float* __restrict__ bpz)
{
    __shared__ float zt[64][132];
    __shared__ float wt[44 * 128];
    const int t = threadIdx.x;
    const int jg0 = blockIdx.x * 64;            // global row in [0, 262144)
    const int i = jg0 >> 9;
    const int jloc = jg0 & 511;
    const int jl = t & 63;
    const int cgs = __builtin_amdgcn_readfirstlane(t >> 6);  // wave-uniform
    // stage W (linear, 1408 float4) and z tile (2048 float4, padded rows)
    #pragma unroll
    for (int u = 0; u < 6; ++u) {
        int idx = t + u * 256;
        if (idx < 1408) *(float4*)&wt[idx * 4] = *(const float4*)&wz[idx * 4];
    }
    #pragma unroll
    for (int u = 0; u < 8; ++u) {
        int idx = t + u * 256;
        int r = idx >> 5, c4 = (idx & 31) << 2;
        *(float4*)&zt[r][c4] = *(const float4*)&z[((size_t)(jg0 + r)) * 128 + c4];
    }
    float bv[11];
    #pragma unroll
    for (int u = 0; u < 11; ++u) bv[u] = bz[cgs * 11 + u];
    __syncthreads();
    float acc[11];
    #pragma unroll
    for (int u = 0; u < 11; ++u) acc[u] = bv[u];
    const float* wbase = &wt[cgs * 11 * 128];
    #pragma unroll 4
    for (int k4 = 0; k4 < 128; k4 += 4) {
        float4 zv = *(float4*)&zt[jl][k4];
        float4 wv[11];
        #pragma unroll
        for (int u = 0; u < 11; ++u)
            wv[u] = *(const float4*)&wbase[u * 128 + k4];   // broadcast read
        #pragma unroll
        for (int u = 0; u < 11; ++u) {
            acc[u] = fmaf(zv.x, wv[u].x, acc[u]);
            acc[u] = fmaf(zv.y, wv[u].y, acc[u]);
            acc[u] = fmaf(zv.z, wv[u].z, acc[u]);
            acc[u] = fmaf(zv.w, wv[u].w, acc[u]);
        }
    }
    #pragma unroll
    for (int u = 0; u < 11; ++u)
        bpz[((size_t)i * 44 + cgs * 11 + u) * 512 + jloc + jl] = acc[u];
}

// ---------------------------------------------------------------- attn_a
__global__ __launch_bounds__(256) void k_attn_a(
    const float* __restrict__ qw, const float* __restrict__ kw,
    const float* __restrict__ qpw, const float* __restrict__ kpw,
    const float* __restrict__ bpz, const float* __restrict__ mask,
    const float* __restrict__ hwp, float* __restrict__ abuf)
{
    __shared__ float pls[4][520];
    __shared__ float qs[64], qps[48], cpt4[4];
    const int i = blockIdx.x, hg = blockIdx.y;
    const int t = threadIdx.x;
    if (t < 64) qs[t] = qw[(size_t)i * 192 + hg * 64 + t];
    if (t < 48) qps[t] = qpw[(size_t)i * 144 + hg * 48 + t];
    if (t < 4) cpt4[t] = -0.5f * 0.13608276348795434f * softplusf(hwp[hg * 4 + t]);
    const float mask_i = mask[i];
    __syncthreads();
    #pragma unroll 2
    for (int it = 0; it < 8; ++it) {
        int idx = t + it * 256;
        int hh = idx >> 9, j = idx & 511;
        int h = hg * 4 + hh;
        float kj[16], kpj[12];
        { const float4* kr = (const float4*)&kw[(size_t)j * 192 + h * 16];
          *(float4*)&kj[0] = kr[0]; *(float4*)&kj[4] = kr[1];
          *(float4*)&kj[8] = kr[2]; *(float4*)&kj[12] = kr[3]; }
        { const float4* kr = (const float4*)&kpw[(size_t)j * 144 + h * 12];
          *(float4*)&kpj[0] = kr[0]; *(float4*)&kpj[4] = kr[1]; *(float4*)&kpj[8] = kr[2]; }
        float qk = 0.f;
        #pragma unroll
        for (int c = 0; c < 16; ++c) qk = fmaf(qs[hh * 16 + c], kj[c], qk);
        float pts = 0.f;
        #pragma unroll
        for (int p = 0; p < 4; ++p) {
            float dx = qps[hh*12+p*3+0] - kpj[p*3+0];
            float dy = qps[hh*12+p*3+1] - kpj[p*3+1];
            float dz = qps[hh*12+p*3+2] - kpj[p*3+2];
            pts += dx*dx + dy*dy + dz*dz;
        }
        float lg = fmaf(0.14433756729740643f, qk, bpz[((size_t)i * 44 + h) * 512 + j]);
        lg = fmaf(cpt4[hh], pts, lg);
        lg += INFV * (mask_i * mask[j] - 1.0f);
        pls[hh][j] = lg;
    }
    __syncthreads();
    const int w = t >> 6, lane = t & 63;
    float v[8];
    #pragma unroll
    for (int k = 0; k < 8; ++k) v[k] = pls[w][lane + k * 64];
    float mx = v[0];
    #pragma unroll
    for (int k = 1; k < 8; ++k) mx = fmaxf(mx, v[k]);
    #pragma unroll
    for (int off = 32; off; off >>= 1) mx = fmaxf(mx, __shfl_xor(mx, off));
    float sm = 0.f;
    #pragma unroll
    for (int k = 0; k < 8; ++k) { v[k] = __expf(v[k] - mx); sm += v[k]; }
    #pragma unroll
    for (int off = 32; off; off >>= 1) sm += __shfl_xor(sm, off);
    const float inv = 1.0f / sm;
    float* dst = abuf + ((size_t)(hg * 4 + w) * 512 + i) * 512;
    #pragma unroll
    for (int k = 0; k < 8; ++k) dst[lane + k * 64] = v[k] * inv;
}

// ---------------------------------------------------------------- attn_pair
__global__ __launch_bounds__(256) void k_attn_pair(
    const float* __restrict__ abuf, const float* __restrict__ bpz,
    float* __restrict__ ocat)
{
    __shared__ float al[12][512];
    const int i = blockIdx.x, t = threadIdx.x;
    #pragma unroll
    for (int u = 0; u < 12; ++u) {
        al[u][t] = abuf[(size_t)u * 262144 + (size_t)i * 512 + t];
        al[u][t + 256] = abuf[(size_t)u * 262144 + (size_t)i * 512 + t + 256];
    }
    __syncthreads();
    const int c = t & 31;
    const int h1 = t >> 5;
    const bool dual = (t < 128);
    const float* pz = bpz + ((size_t)i * 44 + 12 + c) * 512;
    const float* a1 = al[h1];
    const float* a2 = al[dual ? h1 + 8 : 0];
    float acc1 = 0.f, acc2 = 0.f;
    for (int j = 0; j < 512; j += 4) {
        float4 p = *(const float4*)&pz[j];
        acc1 = fmaf(a1[j+0], p.x, acc1);
        acc1 = fmaf(a1[j+1], p.y, acc1);
        acc1 = fmaf(a1[j+2], p.z, acc1);
        acc1 = fmaf(a1[j+3], p.w, acc1);
        if (dual) {
            acc2 = fmaf(a2[j+0], p.x, acc2);
            acc2 = fmaf(a2[j+1], p.y, acc2);
            acc2 = fmaf(a2[j+2], p.z, acc2);
            acc2 = fmaf(a2[j+3], p.w, acc2);
        }
    }
    ocat[(size_t)i * 1152 + 576 + h1 * 32 + c] = acc1;
    if (dual) ocat[(size_t)i * 1152 + 576 + (h1 + 8) * 32 + c] = acc2;
}

// ---------------------------------------------------------------- gemm_ov
__global__ __launch_bounds__(256) void k_gemm_ov(
    const float* __restrict__ abuf, const float* __restrict__ vw,
    const float* __restrict__ vpw, float* __restrict__ cbuf)
{
    __shared__ float As[64][68];
    __shared__ float Bs[64][44];
    const int i0 = blockIdx.x * 64, h = blockIdx.y;
    const int t = threadIdx.x;
    const int sr = t >> 4, sk4 = (t & 15) << 2;
    const int r1 = t >> 3;
    const int cb = t & 7;
    float acc[2][5];
    #pragma unroll
    for (int u = 0; u < 5; ++u) { acc[0][u] = 0.f; acc[1][u] = 0.f; }
    for (int kc = 0; kc < 512; kc += 64) {
        __syncthreads();
        #pragma unroll
        for (int rep = 0; rep < 4; ++rep) {
            int row = sr + rep * 16;
            *(float4*)&As[row][sk4] =
                *(const float4*)&abuf[(size_t)h * 262144 + (size_t)(i0 + row) * 512 + kc + sk4];
        }
        #pragma unroll
        for (int u = 0; u < 10; ++u) {
            int idx = t + u * 256;
            int r = idx / 40, cc = idx % 40;
            Bs[r][cc] = (cc < 16) ? vw[(size_t)(kc + r) * 192 + h * 16 + cc]
                                  : vpw[(size_t)(kc + r) * 288 + h * 24 + (cc - 16)];
        }
        __syncthreads();
        #pragma unroll 4
        for (int kk = 0; kk < 64; ++kk) {
            float av1 = As[r1][kk], av2 = As[r1 + 32][kk];
            #pragma unroll
            for (int u = 0; u < 5; ++u) {
                float b = Bs[kk][cb + 8 * u];
                acc[0][u] = fmaf(av1, b, acc[0][u]);
                acc[1][u] = fmaf(av2, b, acc[1][u]);
            }
        }
    }
    #pragma unroll
    for (int u = 0; u < 5; ++u) {
        cbuf[((size_t)h * 512 + i0 + r1) * 40 + cb + 8 * u] = acc[0][u];
        cbuf[((size_t)h * 512 + i0 + r1 + 32) * 40 + cb + 8 * u] = acc[1][u];
    }
}

// ---------------------------------------------------------------- optfin
__global__ __launch_bounds__(256) void k_optfin(
    const float* __restrict__ cbuf, const float* __restrict__ rots,
    const float* __restrict__ trans, float* __restrict__ ocat)
{
    __shared__ float cl[4][12][40];
    const int i0 = blockIdx.x * 4, t = threadIdx.x;
    for (int idx = t; idx < 1920; idx += 256) {
        int ii = idx / 480, rem = idx % 480;
        int h = rem / 40, c = rem % 40;
        cl[ii][h][c] = cbuf[((size_t)h * 512 + i0 + ii) * 40 + c];
    }
    __syncthreads();
    for (int idx = t; idx < 768; idx += 256) {
        int ii = idx / 192, o = idx % 192;
        ocat[(size_t)(i0 + ii) * 1152 + o] = cl[ii][o >> 4][o & 15];
    }
    for (int idx = t; idx < 384; idx += 256) {
        int ii = idx / 96, hp = idx % 96;
        int h = hp >> 3, p = hp & 7;
        int i = i0 + ii;
        const float* R = &rots[(size_t)i * 9];
        float gx = cl[ii][h][16 + p*3 + 0] - trans[(size_t)i*3 + 0];
        float gy = cl[ii][h][16 + p*3 + 1] - trans[(size_t)i*3 + 1];
        float gz = cl[ii][h][16 + p*3 + 2] - trans[(size_t)i*3 + 2];
        float lx = R[0]*gx + R[3]*gy + R[6]*gz;
        float ly = R[1]*gx + R[4]*gy + R[7]*gz;
        float lz = R[2]*gx + R[5]*gy + R[8]*gz;
        float nm = sqrtf(lx*lx + ly*ly + lz*lz + 1e-8f);
        int col = h * 8 + p;
        size_t base = (size_t)i * 1152;
        ocat[base + 192 + col] = lx;
        ocat[base + 288 + col] = ly;
        ocat[base + 384 + col] = lz;
        ocat[base + 480 + col] = nm;
    }
}

// ---------------------------------------------------------------- tlog
__global__ __launch_bounds__(256) void k_tlog(
    const float* __restrict__ sqw, const float* __restrict__ skv,
    const float* __restrict__ trans, const float* __restrict__ mask,
    const float* __restrict__ sp, const float* __restrict__ smask,
    const float* __restrict__ sbwp, float* __restrict__ logits,
    float* __restrict__ stat_m, float* __restrict__ stat_il)
{
    __shared__ float sk_s[32][16];
    __shared__ float sq_s[32][16];
    __shared__ float trans_s[96];
    __shared__ float mask_s[32];
    __shared__ float spm_s[96];
    __shared__ float smask_s[32];
    const int h = blockIdx.y;
    const int m0 = blockIdx.x * 32;
    const int t = threadIdx.x;
    const int tmg = t >> 5, tnl = t & 31;
    const float sbw = softplusf(sbwp[0]);
    for (int idx = t; idx < 512; idx += 256) {
        int row = idx >> 4, c = idx & 15;
        sk_s[row][c] = skv[(size_t)(m0 + row) * 384 + h * 16 + c];
    }
    if (t < 96) spm_s[t] = sp[(size_t)m0 * 3 + t];
    if (t < 32) smask_s[t] = smask[m0 + t];
    __syncthreads();
    float skr[4][16];
    float spx[4], spy[4], spz[4], smk[4];
    #pragma unroll
    for (int mi = 0; mi < 4; ++mi) {
        int row = tmg * 4 + mi;
        #pragma unroll
        for (int c4 = 0; c4 < 16; c4 += 4)
            *(float4*)&skr[mi][c4] = *(float4*)&sk_s[row][c4];
        spx[mi] = spm_s[row*3+0]; spy[mi] = spm_s[row*3+1]; spz[mi] = spm_s[row*3+2];
        smk[mi] = smask_s[row];
    }
    float mxr[4], lr[4];
    #pragma unroll
    for (int mi = 0; mi < 4; ++mi) { mxr[mi] = -1e30f; lr[mi] = 0.f; }
    for (int nt = 0; nt < 16; ++nt) {
        __syncthreads();
        const int nb = nt * 32;
        if (t < 128) {
            int nn = t >> 2, c4 = (t & 3) << 2;
            *(float4*)&sq_s[nn][c4] = *(const float4*)&sqw[(size_t)(nb + nn) * 192 + h * 16 + c4];
        }
        if (t < 96) trans_s[t] = trans[(size_t)nb * 3 + t];
        if (t < 32) mask_s[t] = mask[nb + t];
        __syncthreads();
        float q[16];
        #pragma unroll
        for (int c4 = 0; c4 < 16; c4 += 4)
            *(float4*)&q[c4] = *(float4*)&sq_s[tnl][c4];
        const float tx = trans_s[tnl*3+0], ty = trans_s[tnl*3+1], tz = trans_s[tnl*3+2];
        const float mkn = mask_s[tnl];
        #pragma unroll
        for (int mi = 0; mi < 4; ++mi) {
            float dot = 0.f;
            #pragma unroll
            for (int c = 0; c < 16; ++c) dot = fmaf(skr[mi][c], q[c], dot);
            float dx = tx - spx[mi], dy = ty - spy[mi], dz = tz - spz[mi];
            float mterm = INFV * (mkn * smk[mi] - 1.0f) - 0.5f * sbw * (dx*dx + dy*dy + dz*dz);
            float lg = fmaf(0.25f, dot, mterm);
            logits[((size_t)(m0 + tmg * 4 + mi) * 12 + h) * 512 + nb + tnl] = lg;
            float newm = fmaxf(mxr[mi], lg);
            lr[mi] = lr[mi] * __expf(mxr[mi] - newm) + __expf(lg - newm);
            mxr[mi] = newm;
        }
    }
    #pragma unroll
    for (int off = 1; off < 32; off <<= 1) {
        #pragma unroll
        for (int mi = 0; mi < 4; ++mi) {
            float m2 = __shfl_xor(mxr[mi], off), l2 = __shfl_xor(lr[mi], off);
            float newm = fmaxf(mxr[mi], m2);
            lr[mi] = lr[mi] * __expf(mxr[mi] - newm) + l2 * __expf(m2 - newm);
            mxr[mi] = newm;
        }
    }
    if (tnl == 0) {
        #pragma unroll
        for (int mi = 0; mi < 4; ++mi) {
            int m = m0 + tmg * 4 + mi;
            stat_m[(size_t)m * 12 + h] = mxr[mi];
            stat_il[(size_t)m * 12 + h] = 1.0f / lr[mi];
        }
    }
}

// ---------------------------------------------------------------- rstat
__global__ __launch_bounds__(256) void k_rstat(
    const float* __restrict__ lbuf, float* __restrict__ rspm,
    float* __restrict__ rsps)
{
    __shared__ float smx[4][64], ssm[4][64];
    const int n0 = blockIdx.x * 64, mc = blockIdx.y, h = blockIdx.z;
    const int t = threadIdx.x, ln = t & 63, mg = t >> 6;
    const int mb = mc * 512;
    const int n = n0 + ln;
    float mx = -1e30f, sm = 0.f;
    #pragma unroll 2
    for (int it = 0; it < 128; ++it) {
        int m = mb + it * 4 + mg;
        float lg = lbuf[((size_t)m * 12 + h) * 512 + n];
        float nm = fmaxf(mx, lg);
        sm = sm * __expf(mx - nm) + __expf(lg - nm);
        mx = nm;
    }
    smx[mg][ln] = mx; ssm[mg][ln] = sm;
    __syncthreads();
    if (t < 64) {
        float M = smx[0][t], S = ssm[0][t];
        #pragma unroll
        for (int g = 1; g < 4; ++g) {
            float m2 = smx[g][t], s2 = ssm[g][t];
            float nm = fmaxf(M, m2);
            S = S * __expf(M - nm) + s2 * __expf(m2 - nm);
            M = nm;
        }
        rspm[((size_t)h * 4 + mc) * 512 + n0 + t] = M;
        rsps[((size_t)h * 4 + mc) * 512 + n0 + t] = S;
    }
}

// ---------------------------------------------------------------- rcomb
__global__ __launch_bounds__(256) void k_rcomb(
    const float* __restrict__ rspm, const float* __restrict__ rsps,
    float* __restrict__ rmax, float* __restrict__ rinv)
{
    int gid = blockIdx.x * 256 + threadIdx.x;
    if (gid >= 6144) return;
    int h = gid >> 9, n = gid & 511;
    float M = -1e30f, S = 0.f;
    #pragma unroll
    for (int mc = 0; mc < 4; ++mc) {
        float m2 = rspm[((size_t)h * 4 + mc) * 512 + n];
        float s2 = rsps[((size_t)h * 4 + mc) * 512 + n];
        float nm = fmaxf(M, m2);
        S = S * __expf(M - nm) + s2 * __expf(m2 - nm);
        M = nm;
    }
    rmax[gid] = M;
    rinv[gid] = 1.0f / S;
}

// ---------------------------------------------------------------- pv
__global__ __launch_bounds__(256) void k_pv(
    const float* __restrict__ lbuf, const float* __restrict__ skv,
    const float* __restrict__ rmax, const float* __restrict__ rinv,
    float* __restrict__ pvp)
{
    __shared__ float sv_s[512][17];
    const int n0 = blockIdx.x * 64, mc = blockIdx.y, h = blockIdx.z;
    const int t = threadIdx.x, ln = t & 63, mg = t >> 6;
    const int mb = mc * 512;
    for (int idx = t; idx < 2048; idx += 256) {
        int ml = idx >> 2, c4 = (idx & 3) << 2;
        float4 v4 = *(const float4*)&skv[(size_t)(mb + ml) * 384 + 192 + h * 16 + c4];
        sv_s[ml][c4+0]=v4.x; sv_s[ml][c4+1]=v4.y; sv_s[ml][c4+2]=v4.z; sv_s[ml][c4+3]=v4.w;
    }
    const int n = n0 + ln;
    const float rm = rmax[h * 512 + n], ri = rinv[h * 512 + n];
    float acc[16];
    #pragma unroll
    for (int c = 0; c < 16; ++c) acc[c] = 0.f;
    __syncthreads();
    #pragma unroll 2
    for (int it = 0; it < 128; ++it) {
        int ml = it * 4 + mg;
        float w = __expf(lbuf[((size_t)(mb + ml) * 12 + h) * 512 + n] - rm) * ri;
        #pragma unroll
        for (int c = 0; c < 16; ++c) acc[c] = fmaf(w, sv_s[ml][c], acc[c]);
    }
    __syncthreads();
    float* red = &sv_s[0][0];
    #pragma unroll
    for (int c = 0; c < 16; ++c) red[(mg * 64 + ln) * 17 + c] = acc[c];
    __syncthreads();
    {
        int nl = t >> 2, c4 = (t & 3) << 2;
        float4 o;
        #pragma unroll
        for (int e = 0; e < 4; ++e) {
            float s = 0.f;
            #pragma unroll
            for (int g = 0; g < 4; ++g) s += red[(g * 64 + nl) * 17 + c4 + e];
            (&o.x)[e] = s;
        }
        *(float4*)&pvp[(((size_t)h * 4 + mc) * 512 + n0 + nl) * 16 + c4] = o;
    }
}

// ---------------------------------------------------------------- pvcomb
__global__ __launch_bounds__(256) void k_pvcomb(
    const float* __restrict__ pvp, float* __restrict__ ocat)
{
    int gid = blockIdx.x * 256 + threadIdx.x;
    int n = gid / 192, rem = gid % 192;
    float o = 0.f;
    #pragma unroll
    for (int mc = 0; mc < 4; ++mc)
        o += pvp[(((size_t)(rem >> 4) * 4 + mc) * 512 + n) * 16 + (rem & 15)];
    ocat[(size_t)n * 1152 + 960 + rem] = o;
}

// ---------------------------------------------------------------- tw
__global__ __launch_bounds__(256) void k_tw(
    const float* __restrict__ logits, const float* __restrict__ stat_m,
    const float* __restrict__ stat_il, float* __restrict__ w)
{
    __shared__ float mxs[12], ils[12];
    const int m = blockIdx.x, t = threadIdx.x;
    if (t < 12) { mxs[t] = stat_m[(size_t)m * 12 + t]; ils[t] = stat_il[(size_t)m * 12 + t]; }
    __syncthreads();
    const float* lp = logits + (size_t)m * 12 * 512;
    float a0 = 0.f, a1 = 0.f;
    #pragma unroll
    for (int h = 0; h < 12; ++h) {
        a0 += __expf(lp[h * 512 + t] - mxs[h]) * ils[h];
        a1 += __expf(lp[h * 512 + 256 + t] - mxs[h]) * ils[h];
    }
    w[(size_t)m * 512 + t] = a0 * (1.0f / 12.0f);
    w[(size_t)m * 512 + 256 + t] = a1 * (1.0f / 12.0f);
}

// ---------------------------------------------------------------- surf out
__global__ __launch_bounds__(256) void k_surf_out(
    const float* __restrict__ sfeat, const float* __restrict__ saggw,
    const float* __restrict__ Wso, const float* __restrict__ bso,
    float* __restrict__ out)
{
    __shared__ float wl[12304];
    const int t = threadIdx.x;
    for (int idx = t; idx < 12288; idx += 256) {
        int k = idx >> 4, c = idx & 15;
        wl[(k / 192) * 3076 + (k % 192) * 16 + c] = Wso[idx];
    }
    const int m = blockIdx.x * 64 + (t >> 2);
    const int kq = t & 3;
    const float* src = (kq < 2) ? &sfeat[(size_t)m * 384 + kq * 192]
                                : &saggw[(size_t)m * 384 + (kq - 2) * 192];
    __syncthreads();
    float acc[16];
    #pragma unroll
    for (int c = 0; c < 16; ++c) acc[c] = 0.f;
    const float* wb = &wl[kq * 3076];
    for (int k = 0; k < 192; k += 4) {
        float4 v = *(const float4*)&src[k];
        #pragma unroll
        for (int e = 0; e < 4; ++e) {
            float sv = (&v.x)[e];
            #pragma unroll
            for (int c = 0; c < 16; ++c)
                acc[c] = fmaf(sv, wb[(k + e) * 16 + c], acc[c]);
        }
    }
    #pragma unroll
    for (int c = 0; c < 16; ++c) {
        acc[c] += __shfl_xor(acc[c], 1);
        acc[c] += __shfl_xor(acc[c], 2);
    }
    #pragma unroll
    for (int c = 0; c < 16; ++c) {
        if ((c >> 2) == kq) out[196608 + (size_t)m * 16 + c] = acc[c] + bso[c];
    }
}

// ----------------------------------------------------------------
extern "C" void kernel_launch(void* const* d_in, const int* in_sizes, int n_in,
                              void* d_out, int out_size, void* d_ws, size_t ws_size,
                              hipStream_t stream)
{
    (void)in_sizes; (void)n_in; (void)out_size; (void)ws_size;
    const float* s     = (const float*)d_in[0];
    const float* z     = (const float*)d_in[1];
    const float* rots  = (const float*)d_in[2];
    const float* trans = (const float*)d_in[3];
    const float* mask  = (const float*)d_in[4];
    const float* sp    = (const float*)d_in[5];
    const float* sf    = (const float*)d_in[6];
    const float* smask = (const float*)d_in[7];
    const float* Wq    = (const float*)d_in[8];  const float* bq   = (const float*)d_in[9];
    const float* Wkv   = (const float*)d_in[10]; const float* bkv  = (const float*)d_in[11];
    const float* Wqp   = (const float*)d_in[12]; const float* bqp  = (const float*)d_in[13];
    const float* Wkvp  = (const float*)d_in[14]; const float* bkvp = (const float*)d_in[15];
    const float* Wse   = (const float*)d_in[16]; const float* bse  = (const float*)d_in[17];
    const float* Wsq   = (const float*)d_in[18]; const float* bsq  = (const float*)d_in[19];
    const float* Wsk   = (const float*)d_in[20]; const float* bsk  = (const float*)d_in[21];
    const float* Wsv   = (const float*)d_in[22]; const float* bsv  = (const float*)d_in[23];
    const float* Wb    = (const float*)d_in[24]; const float* bb   = (const float*)d_in[25];
    const float* Wdz   = (const float*)d_in[26]; const float* bdz  = (const float*)d_in[27];
    const float* hw    = (const float*)d_in[28]; const float* sbw  = (const float*)d_in[29];
    const float* Wout  = (const float*)d_in[30]; const float* bout = (const float*)d_in[31];
    const float* Wso   = (const float*)d_in[32]; const float* bso  = (const float*)d_in[33];
    float* out = (float*)d_out;

    float* qw    = (float*)d_ws;
    float* kw    = qw    + (size_t)512 * 192;
    float* vw    = kw    + (size_t)512 * 192;
    float* sqw   = vw    + (size_t)512 * 192;
    float* qpw   = sqw   + (size_t)512 * 192;
    float* kpw   = qpw   + (size_t)512 * 144;
    float* vpw   = kpw   + (size_t)512 * 144;
    float* sfeat = vpw   + (size_t)512 * 288;
    float* skv   = sfeat + (size_t)2048 * 384;
    float* ocat  = skv   + (size_t)2048 * 384;
    float* sagg  = ocat  + (size_t)512 * 1152;
    // region: proj (688K fl) -> bpz (11.5M fl) -> logits (12.6M fl), stream-serialized
    float* region = sagg + (size_t)2048 * 384;
    float* proj   = region;
    float* bpz    = region;
    float* logits = region;
    float* wt1   = region + (size_t)2048 * 12 * 512;
    float* wt2   = wt1   + (size_t)1344 * 384;
    float* wt3   = wt2   + (size_t)384 * 384;
    float* b1    = wt3   + (size_t)384 * 1152;
    float* b2    = b1    + 1344;
    float* st    = b2    + 384;
    float* wbuf  = st    + (size_t)384 * 512;
    float* statm = wbuf  + (size_t)2048 * 512;
    float* stati = statm + (size_t)2048 * 12;
    float* abuf  = stati + (size_t)2048 * 12;      // a[12][512][512]
    float* cbuf  = abuf  + (size_t)12 * 512 * 512; // c[12][512][40]
    float* wz    = cbuf  + (size_t)12 * 512 * 40;  // Wz[44][128]
    float* bz    = wz    + (size_t)44 * 128;       // bz[44]
    float* rspm  = bz    + 64;                     // [12][4][512]
    float* rsps  = rspm  + (size_t)12 * 4 * 512;
    float* rmax  = rsps  + (size_t)12 * 4 * 512;   // [12][512]
    float* rinv  = rmax  + (size_t)12 * 512;
    float* pvp   = rinv  + (size_t)12 * 512;       // [12][4][512][16]

    k_pack<<<dim3(1099), dim3(256), 0, stream>>>(Wq, Wsq, Wkv, Wqp, Wkvp, Wsk, Wsv, Wout,
        bq, bsq, bkv, bqp, bkvp, bsk, bsv, wt1, wt2, wt3, b1, b2);
    k_packz<<<dim3(23), dim3(256), 0, stream>>>(Wb, bb, Wdz, bdz, wz, bz);
    k_transp<<<dim3(12, 16), dim3(256), 0, stream>>>(s, st);
    k_gemm<384, true><<<dim3(21, 8), dim3(256), 0, stream>>>(s, wt1, b1, proj, 1344);
    k_scatter<<<dim3(128), dim3(256), 0, stream>>>(proj, rots, trans,
        qw, kw, vw, sqw, qpw, kpw, vpw);
    k_sfeat<<<dim3(256), dim3(256), 0, stream>>>(sf, Wse, bse, sfeat);
    k_gemm<384, true><<<dim3(6, 32), dim3(256), 0, stream>>>(sfeat, wt2, b2, skv, 384);
    k_zpass<<<dim3(4096), dim3(256), 0, stream>>>(z, wz, bz, bpz);
    k_attn_a<<<dim3(512, 3), dim3(256), 0, stream>>>(qw, kw, qpw, kpw, bpz, mask, hw, abuf);
    k_attn_pair<<<dim3(512), dim3(256), 0, stream>>>(abuf, bpz, ocat);
    k_gemm_ov<<<dim3(8, 12), dim3(256), 0, stream>>>(abuf, vw, vpw, cbuf);
    k_optfin<<<dim3(128), dim3(256), 0, stream>>>(cbuf, rots, trans, ocat);
    k_tlog<<<dim3(64, 12), dim3(256), 0, stream>>>(sqw, skv, trans, mask, sp, smask,
        sbw, logits, statm, stati);
    k_rstat<<<dim3(8, 4, 12), dim3(256), 0, stream>>>(logits, rspm, rsps);
    k_rcomb<<<dim3(24), dim3(256), 0, stream>>>(rspm, rsps, rmax, rinv);
    k_pv<<<dim3(8, 4, 12), dim3(256), 0, stream>>>(logits, skv, rmax, rinv, pvp);
    k_pvcomb<<<dim3(384), dim3(256), 0, stream>>>(pvp, ocat);
    k_tw<<<dim3(2048), dim3(256), 0, stream>>>(logits, statm, stati, wbuf);
    k_gemm<512, false><<<dim3(6, 32), dim3(256), 0, stream>>>(wbuf, st, nullptr, sagg, 384);
    k_surf_out<<<dim3(32), dim3(256), 0, stream>>>(sfeat, sagg, Wso, bso, out);
    k_gemm<1152, true><<<dim3(6, 8), dim3(256), 0, stream>>>(ocat, wt3, bout, out, 384);
}

// Round 11
// 530.026 us; speedup vs baseline: 1.0365x; 1.0365x over previous
//
#include <hip/hip_runtime.h>
#include <cstddef>

// IPA + surface cross-attention, B=1, N=512, M=2048, H=12, C_H=16, C_S=384.
// Round 10: k_zpass v4 — j×2 register blocking + k-split(64): 13 LDS issues
// per 88 FMA instrs (VALU-bound), 45KB LDS -> 3 blocks/CU. Rest unchanged.

#define CS 384
#define INFV 100000.0f

__device__ __forceinline__ float softplusf(float x) { return log1pf(__expf(x)); }

// ---------------------------------------------------------------- pack
__global__ __launch_bounds__(256) void k_pack(
    const float* __restrict__ Wq, const float* __restrict__ Wsq,
    const float* __restrict__ Wkv, const float* __restrict__ Wqp,
    const float* __restrict__ Wkvp, const float* __restrict__ Wsk,
    const float* __restrict__ Wsv, const float* __restrict__ Wout,
    const float* __restrict__ bq, const float* __restrict__ bsq,
    const float* __restrict__ bkv, const float* __restrict__ bqp,
    const float* __restrict__ bkvp, const float* __restrict__ bsk,
    const float* __restrict__ bsv,
    float* __restrict__ wt1, float* __restrict__ wt2, float* __restrict__ wt3,
    float* __restrict__ b1, float* __restrict__ b2)
{
    const int b = blockIdx.x, t = threadIdx.x;
    if (b >= 1092) {
        int idx = (b - 1092) * 256 + t;
        if (idx < 1344) {
            float v;
            if (idx < 192) v = bq[idx];
            else if (idx < 384) v = bsq[idx - 192];
            else if (idx < 768) v = bkv[idx - 384];
            else if (idx < 912) v = bqp[idx - 768];
            else v = bkvp[idx - 912];
            b1[idx] = v;
        } else if (idx < 1728) {
            int i2 = idx - 1344;
            b2[i2] = (i2 < 192) ? bsk[i2] : bsv[i2 - 192];
        }
        return;
    }
    const float* src; float* dst; int C, coff, tile, ldd;
    if (b < 72)       { src = Wq;   C = 192; dst = wt1; coff = 0;   ldd = 384;  tile = b; }
    else if (b < 144) { src = Wsq;  C = 192; dst = wt1; coff = 192; ldd = 384;  tile = b - 72; }
    else if (b < 288) { src = Wkv;  C = 384; dst = wt1; coff = 384; ldd = 384;  tile = b - 144; }
    else if (b < 348) { src = Wqp;  C = 144; dst = wt1; coff = 768; ldd = 384;  tile = b - 288; }
    else if (b < 516) { src = Wkvp; C = 432; dst = wt1; coff = 912; ldd = 384;  tile = b - 348; }
    else if (b < 588) { src = Wsk;  C = 192; dst = wt2; coff = 0;   ldd = 384;  tile = b - 516; }
    else if (b < 660) { src = Wsv;  C = 192; dst = wt2; coff = 192; ldd = 384;  tile = b - 588; }
    else              { src = Wout; C = 384; dst = wt3; coff = 0;   ldd = 1152; tile = b - 660; }
    const int cT = (C + 31) >> 5;
    const int tk = tile / cT, tc = tile % cT;
    __shared__ float l[32][33];
    const int tr = t >> 5, tcc = t & 31;
    #pragma unroll
    for (int rr = 0; rr < 4; ++rr) {
        int kloc = tr * 4 + rr;
        int cg = tc * 32 + tcc;
        l[kloc][tcc] = (cg < C) ? src[(size_t)(tk * 32 + kloc) * C + cg] : 0.f;
    }
    __syncthreads();
    #pragma unroll
    for (int rr = 0; rr < 4; ++rr) {
        int cloc = tr * 4 + rr;
        int cg = tc * 32 + cloc;
        if (cg < C) dst[(size_t)(coff + cg) * ldd + tk * 32 + tcc] = l[tcc][cloc];
    }
}

// ---------------------------------------------------------------- packz
__global__ __launch_bounds__(256) void k_packz(
    const float* __restrict__ Wb, const float* __restrict__ bb,
    const float* __restrict__ Wdz, const float* __restrict__ bdz,
    float* __restrict__ wz, float* __restrict__ bz)
{
    const float s3 = 0.5773502691896258f;
    int idx = blockIdx.x * 256 + threadIdx.x;
    if (idx < 5632) {
        int c = idx >> 7, kk = idx & 127;
        wz[idx] = (c < 12) ? s3 * Wb[kk * 12 + c] : Wdz[kk * 32 + (c - 12)];
    } else if (idx < 5676) {
        int c = idx - 5632;
        bz[c] = (c < 12) ? s3 * bb[c] : bdz[c - 12];
    }
}

// ---------------------------------------------------------------- transpose
__global__ __launch_bounds__(256) void k_transp(
    const float* __restrict__ A, float* __restrict__ At)
{
    __shared__ float tile[32][33];
    const int r0 = blockIdx.y * 32, c0 = blockIdx.x * 32;
    const int tr = threadIdx.x >> 5, tc = threadIdx.x & 31;
    #pragma unroll
    for (int rr = 0; rr < 4; ++rr)
        tile[tr + rr * 8][tc] = A[(size_t)(r0 + tr + rr * 8) * 384 + c0 + tc];
    __syncthreads();
    #pragma unroll
    for (int rr = 0; rr < 4; ++rr)
        At[(size_t)(c0 + tr + rr * 8) * 512 + r0 + tc] = tile[tc][tr + rr * 8];
}

// ---------------------------------------------------------------- gemm
template<int KTOT, bool HB>
__global__ __launch_bounds__(256) void k_gemm(
    const float* __restrict__ A, const float* __restrict__ Wt,
    const float* __restrict__ bias, float* __restrict__ C, int ldc)
{
    __shared__ float As[64][68];
    __shared__ float Ws[64][68];
    const int t = threadIdx.x;
    const int c0 = blockIdx.x * 64, m0 = blockIdx.y * 64;
    const int sr = t >> 4, sk4 = (t & 15) << 2;
    const int wid = t >> 6, lane = t & 63;
    const int wr = (wid >> 1) * 32, wc = (wid & 1) * 32;
    const int lr = lane >> 3, lc = lane & 7;
    float acc[4][4];
    #pragma unroll
    for (int j = 0; j < 4; ++j) {
        float bv = HB ? bias[c0 + wc + lc + 8 * j] : 0.f;
        #pragma unroll
        for (int i = 0; i < 4; ++i) acc[i][j] = bv;
    }
    for (int kc = 0; kc < KTOT; kc += 64) {
        __syncthreads();
        #pragma unroll
        for (int rep = 0; rep < 4; ++rep) {
            int row = sr + rep * 16;
            *(float4*)&As[row][sk4] = *(const float4*)&A[(size_t)(m0 + row) * KTOT + kc + sk4];
            *(float4*)&Ws[row][sk4] = *(const float4*)&Wt[(size_t)(c0 + row) * KTOT + kc + sk4];
        }
        __syncthreads();
        #pragma unroll 4
        for (int k4 = 0; k4 < 16; ++k4) {
            float4 a[4], w[4];
            #pragma unroll
            for (int i = 0; i < 4; ++i) a[i] = *(float4*)&As[wr + lr + 8 * i][k4 * 4];
            #pragma unroll
            for (int j = 0; j < 4; ++j) w[j] = *(float4*)&Ws[wc + lc + 8 * j][k4 * 4];
            #pragma unroll
            for (int i = 0; i < 4; ++i) {
                #pragma unroll
                for (int j = 0; j < 4; ++j) {
                    acc[i][j] = fmaf(a[i].x, w[j].x, acc[i][j]);
                    acc[i][j] = fmaf(a[i].y, w[j].y, acc[i][j]);
                    acc[i][j] = fmaf(a[i].z, w[j].z, acc[i][j]);
                    acc[i][j] = fmaf(a[i].w, w[j].w, acc[i][j]);
                }
            }
        }
    }
    #pragma unroll
    for (int i = 0; i < 4; ++i) {
        #pragma unroll
        for (int j = 0; j < 4; ++j)
            C[(size_t)(m0 + wr + lr + 8 * i) * ldc + c0 + wc + lc + 8 * j] = acc[i][j];
    }
}

// ---------------------------------------------------------------- scatter
__global__ __launch_bounds__(256) void k_scatter(
    const float* __restrict__ proj, const float* __restrict__ rots,
    const float* __restrict__ trans,
    float* __restrict__ qw, float* __restrict__ kw, float* __restrict__ vw,
    float* __restrict__ sqw, float* __restrict__ qpw, float* __restrict__ kpw,
    float* __restrict__ vpw)
{
    __shared__ float p[4][1344];
    const int n0 = blockIdx.x * 4, t = threadIdx.x;
    for (int idx = t; idx < 1344; idx += 256) {
        #pragma unroll
        for (int r = 0; r < 4; ++r) p[r][idx] = proj[(size_t)(n0 + r) * 1344 + idx];
    }
    __syncthreads();
    for (int idx = t; idx < 3072; idx += 256) {
        int r = idx / 768, c = idx % 768;
        int n = n0 + r;
        float v = p[r][c];
        if (c < 192) qw[(size_t)n * 192 + c] = v;
        else if (c < 384) sqw[(size_t)n * 192 + (c - 192)] = v;
        else {
            int cc = c - 384, h = cc >> 5, sub = cc & 31;
            if (sub < 16) kw[(size_t)n * 192 + h * 16 + sub] = v;
            else          vw[(size_t)n * 192 + h * 16 + (sub - 16)] = v;
        }
    }
    for (int idx = t; idx < 2304; idx += 256) {
        int r = idx / 576, rem = idx % 576;
        int n = n0 + r;
        const float* R = &rots[(size_t)n * 9];
        const float* tr = &trans[(size_t)n * 3];
        if (rem < 144) {
            int pp = rem / 3, d = rem % 3;
            float v = fmaf(R[d*3+0], p[r][768 + pp],
                      fmaf(R[d*3+1], p[r][768 + 48 + pp],
                      fmaf(R[d*3+2], p[r][768 + 96 + pp], tr[d])));
            qpw[(size_t)n * 144 + pp * 3 + d] = v;
        } else {
            int rem2 = rem - 144; int pp = rem2 / 3, d = rem2 % 3;
            float v = fmaf(R[d*3+0], p[r][912 + pp],
                      fmaf(R[d*3+1], p[r][912 + 144 + pp],
                      fmaf(R[d*3+2], p[r][912 + 288 + pp], tr[d])));
            int h = pp / 12, ii = pp % 12;
            if (ii < 4) kpw[(size_t)n * 144 + h * 12 + ii * 3 + d] = v;
            else        vpw[(size_t)n * 288 + h * 24 + (ii - 4) * 3 + d] = v;
        }
    }
}

// ---------------------------------------------------------------- sfeat
__global__ __launch_bounds__(256) void k_sfeat(
    const float* __restrict__ sf, const float* __restrict__ Wse,
    const float* __restrict__ bse, float* __restrict__ sfeat)
{
    __shared__ float wl[16 * 384];
    __shared__ float sfl[8][16];
    const int m0 = blockIdx.x * 8, t = threadIdx.x;
    for (int idx = t; idx < 6144; idx += 256) wl[idx] = Wse[idx];
    if (t < 128) sfl[t >> 4][t & 15] = sf[(size_t)(m0 + (t >> 4)) * 16 + (t & 15)];
    __syncthreads();
    #pragma unroll
    for (int u = 0; u < 12; ++u) {
        int idx = t + u * 256;
        int r = idx / 384, c = idx % 384;
        float a = bse[c];
        #pragma unroll
        for (int kk = 0; kk < 16; ++kk) a = fmaf(sfl[r][kk], wl[kk * 384 + c], a);
        sfeat[(size_t)(m0 + r) * 384 + c] = a;
    }
}

// ---------------------------------------------------------------- zpass v4
// bpz[i][c][j] = z[i][j][:] @ wz[c][:] + bz[c].
// 2048 blocks x 128 j-rows; lane owns 2 j (jl, jl+64); wave owns 11 c's.
// k split in 2 halves of 64 -> zt[128][68] (34.8KB) + wt[44][64] (11KB).
// Per k4: 2 per-lane z b128 + 11 broadcast W b128 vs 88 FMA instrs.
__global__ __launch_bounds__(256) void k_zpass(
    const float* __restrict__ z, const float* __restrict__ wz,
    const float* __restrict__ bz, float* __restrict__ bpz)
{
    __shared__ float zt[128][68];
    __shared__ float wt[44][64];
    const int t = threadIdx.x;
    const int jg0 = blockIdx.x * 128;
    const int i = jg0 >> 9;
    const int jloc = jg0 & 511;
    const int jl = t & 63;
    const int cgs = __builtin_amdgcn_readfirstlane(t >> 6);  // wave-uniform
    float acc[2][11];
    #pragma unroll
    for (int u = 0; u < 11; ++u) {
        float b = bz[cgs * 11 + u];
        acc[0][u] = b; acc[1][u] = b;
    }
    for (int kc = 0; kc < 128; kc += 64) {
        __syncthreads();
        // stage W half: 44 rows x 16 float4
        for (int idx = t; idx < 704; idx += 256) {
            int c = idx >> 4, k4 = (idx & 15) << 2;
            *(float4*)&wt[c][k4] = *(const float4*)&wz[c * 128 + kc + k4];
        }
        // stage z half: 128 rows x 16 float4
        #pragma unroll
        for (int u = 0; u < 8; ++u) {
            int idx = t + u * 256;
            int r = idx >> 4, k4 = (idx & 15) << 2;
            *(float4*)&zt[r][k4] = *(const float4*)&z[((size_t)(jg0 + r)) * 128 + kc + k4];
        }
        __syncthreads();
        const float* wbase = &wt[cgs * 11][0];
        #pragma unroll 4
        for (int k4 = 0; k4 < 64; k4 += 4) {
            float4 z0 = *(float4*)&zt[jl][k4];
            float4 z1 = *(float4*)&zt[jl + 64][k4];
            #pragma unroll
            for (int u = 0; u < 11; ++u) {
                float4 wv = *(const float4*)&wbase[u * 64 + k4];  // broadcast
                acc[0][u] = fmaf(z0.x, wv.x,
                            fmaf(z0.y, wv.y,
                            fmaf(z0.z, wv.z,
                            fmaf(z0.w, wv.w, acc[0][u]))));
                acc[1][u] = fmaf(z1.x, wv.x,
                            fmaf(z1.y, wv.y,
                            fmaf(z1.z, wv.z,
                            fmaf(z1.w, wv.w, acc[1][u]))));
            }
        }
    }
    #pragma unroll
    for (int u = 0; u < 11; ++u) {
        size_t base = ((size_t)i * 44 + cgs * 11 + u) * 512 + jloc;
        bpz[base + jl] = acc[0][u];
        bpz[base + 64 + jl] = acc[1][u];
    }
}

// ---------------------------------------------------------------- attn_a
__global__ __launch_bounds__(256) void k_attn_a(
    const float* __restrict__ qw, const float* __restrict__ kw,
    const float* __restrict__ qpw, const float* __restrict__ kpw,
    const float* __restrict__ bpz, const float* __restrict__ mask,
    const float* __restrict__ hwp, float* __restrict__ abuf)
{
    __shared__ float pls[4][520];
    __shared__ float qs[64], qps[48], cpt4[4];
    const int i = blockIdx.x, hg = blockIdx.y;
    const int t = threadIdx.x;
    if (t < 64) qs[t] = qw[(size_t)i * 192 + hg * 64 + t];
    if (t < 48) qps[t] = qpw[(size_t)i * 144 + hg * 48 + t];
    if (t < 4) cpt4[t] = -0.5f * 0.13608276348795434f * softplusf(hwp[hg * 4 + t]);
    const float mask_i = mask[i];
    __syncthreads();
    #pragma unroll 2
    for (int it = 0; it < 8; ++it) {
        int idx = t + it * 256;
        int hh = idx >> 9, j = idx & 511;
        int h = hg * 4 + hh;
        float kj[16], kpj[12];
        { const float4* kr = (const float4*)&kw[(size_t)j * 192 + h * 16];
          *(float4*)&kj[0] = kr[0]; *(float4*)&kj[4] = kr[1];
          *(float4*)&kj[8] = kr[2]; *(float4*)&kj[12] = kr[3]; }
        { const float4* kr = (const float4*)&kpw[(size_t)j * 144 + h * 12];
          *(float4*)&kpj[0] = kr[0]; *(float4*)&kpj[4] = kr[1]; *(float4*)&kpj[8] = kr[2]; }
        float qk = 0.f;
        #pragma unroll
        for (int c = 0; c < 16; ++c) qk = fmaf(qs[hh * 16 + c], kj[c], qk);
        float pts = 0.f;
        #pragma unroll
        for (int p = 0; p < 4; ++p) {
            float dx = qps[hh*12+p*3+0] - kpj[p*3+0];
            float dy = qps[hh*12+p*3+1] - kpj[p*3+1];
            float dz = qps[hh*12+p*3+2] - kpj[p*3+2];
            pts += dx*dx + dy*dy + dz*dz;
        }
        float lg = fmaf(0.14433756729740643f, qk, bpz[((size_t)i * 44 + h) * 512 + j]);
        lg = fmaf(cpt4[hh], pts, lg);
        lg += INFV * (mask_i * mask[j] - 1.0f);
        pls[hh][j] = lg;
    }
    __syncthreads();
    const int w = t >> 6, lane = t & 63;
    float v[8];
    #pragma unroll
    for (int k = 0; k < 8; ++k) v[k] = pls[w][lane + k * 64];
    float mx = v[0];
    #pragma unroll
    for (int k = 1; k < 8; ++k) mx = fmaxf(mx, v[k]);
    #pragma unroll
    for (int off = 32; off; off >>= 1) mx = fmaxf(mx, __shfl_xor(mx, off));
    float sm = 0.f;
    #pragma unroll
    for (int k = 0; k < 8; ++k) { v[k] = __expf(v[k] - mx); sm += v[k]; }
    #pragma unroll
    for (int off = 32; off; off >>= 1) sm += __shfl_xor(sm, off);
    const float inv = 1.0f / sm;
    float* dst = abuf + ((size_t)(hg * 4 + w) * 512 + i) * 512;
    #pragma unroll
    for (int k = 0; k < 8; ++k) dst[lane + k * 64] = v[k] * inv;
}

// ---------------------------------------------------------------- attn_pair
__global__ __launch_bounds__(256) void k_attn_pair(
    const float* __restrict__ abuf, const float* __restrict__ bpz,
    float* __restrict__ ocat)
{
    __shared__ float al[12][512];
    const int i = blockIdx.x, t = threadIdx.x;
    #pragma unroll
    for (int u = 0; u < 12; ++u) {
        al[u][t] = abuf[(size_t)u * 262144 + (size_t)i * 512 + t];
        al[u][t + 256] = abuf[(size_t)u * 262144 + (size_t)i * 512 + t + 256];
    }
    __syncthreads();
    const int c = t & 31;
    const int h1 = t >> 5;
    const bool dual = (t < 128);
    const float* pz = bpz + ((size_t)i * 44 + 12 + c) * 512;
    const float* a1 = al[h1];
    const float* a2 = al[dual ? h1 + 8 : 0];
    float acc1 = 0.f, acc2 = 0.f;
    for (int j = 0; j < 512; j += 4) {
        float4 p = *(const float4*)&pz[j];
        acc1 = fmaf(a1[j+0], p.x, acc1);
        acc1 = fmaf(a1[j+1], p.y, acc1);
        acc1 = fmaf(a1[j+2], p.z, acc1);
        acc1 = fmaf(a1[j+3], p.w, acc1);
        if (dual) {
            acc2 = fmaf(a2[j+0], p.x, acc2);
            acc2 = fmaf(a2[j+1], p.y, acc2);
            acc2 = fmaf(a2[j+2], p.z, acc2);
            acc2 = fmaf(a2[j+3], p.w, acc2);
        }
    }
    ocat[(size_t)i * 1152 + 576 + h1 * 32 + c] = acc1;
    if (dual) ocat[(size_t)i * 1152 + 576 + (h1 + 8) * 32 + c] = acc2;
}

// ---------------------------------------------------------------- gemm_ov
__global__ __launch_bounds__(256) void k_gemm_ov(
    const float* __restrict__ abuf, const float* __restrict__ vw,
    const float* __restrict__ vpw, float* __restrict__ cbuf)
{
    __shared__ float As[64][68];
    __shared__ float Bs[64][44];
    const int i0 = blockIdx.x * 64, h = blockIdx.y;
    const int t = threadIdx.x;
    const int sr = t >> 4, sk4 = (t & 15) << 2;
    const int r1 = t >> 3;
    const int cb = t & 7;
    float acc[2][5];
    #pragma unroll
    for (int u = 0; u < 5; ++u) { acc[0][u] = 0.f; acc[1][u] = 0.f; }
    for (int kc = 0; kc < 512; kc += 64) {
        __syncthreads();
        #pragma unroll
        for (int rep = 0; rep < 4; ++rep) {
            int row = sr + rep * 16;
            *(float4*)&As[row][sk4] =
                *(const float4*)&abuf[(size_t)h * 262144 + (size_t)(i0 + row) * 512 + kc + sk4];
        }
        #pragma unroll
        for (int u = 0; u < 10; ++u) {
            int idx = t + u * 256;
            int r = idx / 40, cc = idx % 40;
            Bs[r][cc] = (cc < 16) ? vw[(size_t)(kc + r) * 192 + h * 16 + cc]
                                  : vpw[(size_t)(kc + r) * 288 + h * 24 + (cc - 16)];
        }
        __syncthreads();
        #pragma unroll 4
        for (int kk = 0; kk < 64; ++kk) {
            float av1 = As[r1][kk], av2 = As[r1 + 32][kk];
            #pragma unroll
            for (int u = 0; u < 5; ++u) {
                float b = Bs[kk][cb + 8 * u];
                acc[0][u] = fmaf(av1, b, acc[0][u]);
                acc[1][u] = fmaf(av2, b, acc[1][u]);
            }
        }
    }
    #pragma unroll
    for (int u = 0; u < 5; ++u) {
        cbuf[((size_t)h * 512 + i0 + r1) * 40 + cb + 8 * u] = acc[0][u];
        cbuf[((size_t)h * 512 + i0 + r1 + 32) * 40 + cb + 8 * u] = acc[1][u];
    }
}

// ---------------------------------------------------------------- optfin
__global__ __launch_bounds__(256) void k_optfin(
    const float* __restrict__ cbuf, const float* __restrict__ rots,
    const float* __restrict__ trans, float* __restrict__ ocat)
{
    __shared__ float cl[4][12][40];
    const int i0 = blockIdx.x * 4, t = threadIdx.x;
    for (int idx = t; idx < 1920; idx += 256) {
        int ii = idx / 480, rem = idx % 480;
        int h = rem / 40, c = rem % 40;
        cl[ii][h][c] = cbuf[((size_t)h * 512 + i0 + ii) * 40 + c];
    }
    __syncthreads();
    for (int idx = t; idx < 768; idx += 256) {
        int ii = idx / 192, o = idx % 192;
        ocat[(size_t)(i0 + ii) * 1152 + o] = cl[ii][o >> 4][o & 15];
    }
    for (int idx = t; idx < 384; idx += 256) {
        int ii = idx / 96, hp = idx % 96;
        int h = hp >> 3, p = hp & 7;
        int i = i0 + ii;
        const float* R = &rots[(size_t)i * 9];
        float gx = cl[ii][h][16 + p*3 + 0] - trans[(size_t)i*3 + 0];
        float gy = cl[ii][h][16 + p*3 + 1] - trans[(size_t)i*3 + 1];
        float gz = cl[ii][h][16 + p*3 + 2] - trans[(size_t)i*3 + 2];
        float lx = R[0]*gx + R[3]*gy + R[6]*gz;
        float ly = R[1]*gx + R[4]*gy + R[7]*gz;
        float lz = R[2]*gx + R[5]*gy + R[8]*gz;
        float nm = sqrtf(lx*lx + ly*ly + lz*lz + 1e-8f);
        int col = h * 8 + p;
        size_t base = (size_t)i * 1152;
        ocat[base + 192 + col] = lx;
        ocat[base + 288 + col] = ly;
        ocat[base + 384 + col] = lz;
        ocat[base + 480 + col] = nm;
    }
}

// ---------------------------------------------------------------- tlog
__global__ __launch_bounds__(256) void k_tlog(
    const float* __restrict__ sqw, const float* __restrict__ skv,
    const float* __restrict__ trans, const float* __restrict__ mask,
    const float* __restrict__ sp, const float* __restrict__ smask,
    const float* __restrict__ sbwp, float* __restrict__ logits,
    float* __restrict__ stat_m, float* __restrict__ stat_il)
{
    __shared__ float sk_s[32][16];
    __shared__ float sq_s[32][16];
    __shared__ float trans_s[96];
    __shared__ float mask_s[32];
    __shared__ float spm_s[96];
    __shared__ float smask_s[32];
    const int h = blockIdx.y;
    const int m0 = blockIdx.x * 32;
    const int t = threadIdx.x;
    const int tmg = t >> 5, tnl = t & 31;
    const float sbw = softplusf(sbwp[0]);
    for (int idx = t; idx < 512; idx += 256) {
        int row = idx >> 4, c = idx & 15;
        sk_s[row][c] = skv[(size_t)(m0 + row) * 384 + h * 16 + c];
    }
    if (t < 96) spm_s[t] = sp[(size_t)m0 * 3 + t];
    if (t < 32) smask_s[t] = smask[m0 + t];
    __syncthreads();
    float skr[4][16];
    float spx[4], spy[4], spz[4], smk[4];
    #pragma unroll
    for (int mi = 0; mi < 4; ++mi) {
        int row = tmg * 4 + mi;
        #pragma unroll
        for (int c4 = 0; c4 < 16; c4 += 4)
            *(float4*)&skr[mi][c4] = *(float4*)&sk_s[row][c4];
        spx[mi] = spm_s[row*3+0]; spy[mi] = spm_s[row*3+1]; spz[mi] = spm_s[row*3+2];
        smk[mi] = smask_s[row];
    }
    float mxr[4], lr[4];
    #pragma unroll
    for (int mi = 0; mi < 4; ++mi) { mxr[mi] = -1e30f; lr[mi] = 0.f; }
    for (int nt = 0; nt < 16; ++nt) {
        __syncthreads();
        const int nb = nt * 32;
        if (t < 128) {
            int nn = t >> 2, c4 = (t & 3) << 2;
            *(float4*)&sq_s[nn][c4] = *(const float4*)&sqw[(size_t)(nb + nn) * 192 + h * 16 + c4];
        }
        if (t < 96) trans_s[t] = trans[(size_t)nb * 3 + t];
        if (t < 32) mask_s[t] = mask[nb + t];
        __syncthreads();
        float q[16];
        #pragma unroll
        for (int c4 = 0; c4 < 16; c4 += 4)
            *(float4*)&q[c4] = *(float4*)&sq_s[tnl][c4];
        const float tx = trans_s[tnl*3+0], ty = trans_s[tnl*3+1], tz = trans_s[tnl*3+2];
        const float mkn = mask_s[tnl];
        #pragma unroll
        for (int mi = 0; mi < 4; ++mi) {
            float dot = 0.f;
            #pragma unroll
            for (int c = 0; c < 16; ++c) dot = fmaf(skr[mi][c], q[c], dot);
            float dx = tx - spx[mi], dy = ty - spy[mi], dz = tz - spz[mi];
            float mterm = INFV * (mkn * smk[mi] - 1.0f) - 0.5f * sbw * (dx*dx + dy*dy + dz*dz);
            float lg = fmaf(0.25f, dot, mterm);
            logits[((size_t)(m0 + tmg * 4 + mi) * 12 + h) * 512 + nb + tnl] = lg;
            float newm = fmaxf(mxr[mi], lg);
            lr[mi] = lr[mi] * __expf(mxr[mi] - newm) + __expf(lg - newm);
            mxr[mi] = newm;
        }
    }
    #pragma unroll
    for (int off = 1; off < 32; off <<= 1) {
        #pragma unroll
        for (int mi = 0; mi < 4; ++mi) {
            float m2 = __shfl_xor(mxr[mi], off), l2 = __shfl_xor(lr[mi], off);
            float newm = fmaxf(mxr[mi], m2);
            lr[mi] = lr[mi] * __expf(mxr[mi] - newm) + l2 * __expf(m2 - newm);
            mxr[mi] = newm;
        }
    }
    if (tnl == 0) {
        #pragma unroll
        for (int mi = 0; mi < 4; ++mi) {
            int m = m0 + tmg * 4 + mi;
            stat_m[(size_t)m * 12 + h] = mxr[mi];
            stat_il[(size_t)m * 12 + h] = 1.0f / lr[mi];
        }
    }
}

// ---------------------------------------------------------------- rstat
__global__ __launch_bounds__(256) void k_rstat(
    const float* __restrict__ lbuf, float* __restrict__ rspm,
    float* __restrict__ rsps)
{
    __shared__ float smx[4][64], ssm[4][64];
    const int n0 = blockIdx.x * 64, mc = blockIdx.y, h = blockIdx.z;
    const int t = threadIdx.x, ln = t & 63, mg = t >> 6;
    const int mb = mc * 512;
    const int n = n0 + ln;
    float mx = -1e30f, sm = 0.f;
    #pragma unroll 2
    for (int it = 0; it < 128; ++it) {
        int m = mb + it * 4 + mg;
        float lg = lbuf[((size_t)m * 12 + h) * 512 + n];
        float nm = fmaxf(mx, lg);
        sm = sm * __expf(mx - nm) + __expf(lg - nm);
        mx = nm;
    }
    smx[mg][ln] = mx; ssm[mg][ln] = sm;
    __syncthreads();
    if (t < 64) {
        float M = smx[0][t], S = ssm[0][t];
        #pragma unroll
        for (int g = 1; g < 4; ++g) {
            float m2 = smx[g][t], s2 = ssm[g][t];
            float nm = fmaxf(M, m2);
            S = S * __expf(M - nm) + s2 * __expf(m2 - nm);
            M = nm;
        }
        rspm[((size_t)h * 4 + mc) * 512 + n0 + t] = M;
        rsps[((size_t)h * 4 + mc) * 512 + n0 + t] = S;
    }
}

// ---------------------------------------------------------------- rcomb
__global__ __launch_bounds__(256) void k_rcomb(
    const float* __restrict__ rspm, const float* __restrict__ rsps,
    float* __restrict__ rmax, float* __restrict__ rinv)
{
    int gid = blockIdx.x * 256 + threadIdx.x;
    if (gid >= 6144) return;
    int h = gid >> 9, n = gid & 511;
    float M = -1e30f, S = 0.f;
    #pragma unroll
    for (int mc = 0; mc < 4; ++mc) {
        float m2 = rspm[((size_t)h * 4 + mc) * 512 + n];
        float s2 = rsps[((size_t)h * 4 + mc) * 512 + n];
        float nm = fmaxf(M, m2);
        S = S * __expf(M - nm) + s2 * __expf(m2 - nm);
        M = nm;
    }
    rmax[gid] = M;
    rinv[gid] = 1.0f / S;
}

// ---------------------------------------------------------------- pv
__global__ __launch_bounds__(256) void k_pv(
    const float* __restrict__ lbuf, const float* __restrict__ skv,
    const float* __restrict__ rmax, const float* __restrict__ rinv,
    float* __restrict__ pvp)
{
    __shared__ float sv_s[512][17];
    const int n0 = blockIdx.x * 64, mc = blockIdx.y, h = blockIdx.z;
    const int t = threadIdx.x, ln = t & 63, mg = t >> 6;
    const int mb = mc * 512;
    for (int idx = t; idx < 2048; idx += 256) {
        int ml = idx >> 2, c4 = (idx & 3) << 2;
        float4 v4 = *(const float4*)&skv[(size_t)(mb + ml) * 384 + 192 + h * 16 + c4];
        sv_s[ml][c4+0]=v4.x; sv_s[ml][c4+1]=v4.y; sv_s[ml][c4+2]=v4.z; sv_s[ml][c4+3]=v4.w;
    }
    const int n = n0 + ln;
    const float rm = rmax[h * 512 + n], ri = rinv[h * 512 + n];
    float acc[16];
    #pragma unroll
    for (int c = 0; c < 16; ++c) acc[c] = 0.f;
    __syncthreads();
    #pragma unroll 2
    for (int it = 0; it < 128; ++it) {
        int ml = it * 4 + mg;
        float w = __expf(lbuf[((size_t)(mb + ml) * 12 + h) * 512 + n] - rm) * ri;
        #pragma unroll
        for (int c = 0; c < 16; ++c) acc[c] = fmaf(w, sv_s[ml][c], acc[c]);
    }
    __syncthreads();
    float* red = &sv_s[0][0];
    #pragma unroll
    for (int c = 0; c < 16; ++c) red[(mg * 64 + ln) * 17 + c] = acc[c];
    __syncthreads();
    {
        int nl = t >> 2, c4 = (t & 3) << 2;
        float4 o;
        #pragma unroll
        for (int e = 0; e < 4; ++e) {
            float s = 0.f;
            #pragma unroll
            for (int g = 0; g < 4; ++g) s += red[(g * 64 + nl) * 17 + c4 + e];
            (&o.x)[e] = s;
        }
        *(float4*)&pvp[(((size_t)h * 4 + mc) * 512 + n0 + nl) * 16 + c4] = o;
    }
}

// ---------------------------------------------------------------- pvcomb
__global__ __launch_bounds__(256) void k_pvcomb(
    const float* __restrict__ pvp, float* __restrict__ ocat)
{
    int gid = blockIdx.x * 256 + threadIdx.x;
    int n = gid / 192, rem = gid % 192;
    float o = 0.f;
    #pragma unroll
    for (int mc = 0; mc < 4; ++mc)
        o += pvp[(((size_t)(rem >> 4) * 4 + mc) * 512 + n) * 16 + (rem & 15)];
    ocat[(size_t)n * 1152 + 960 + rem] = o;
}

// ---------------------------------------------------------------- tw
__global__ __launch_bounds__(256) void k_tw(
    const float* __restrict__ logits, const float* __restrict__ stat_m,
    const float* __restrict__ stat_il, float* __restrict__ w)
{
    __shared__ float mxs[12], ils[12];
    const int m = blockIdx.x, t = threadIdx.x;
    if (t < 12) { mxs[t] = stat_m[(size_t)m * 12 + t]; ils[t] = stat_il[(size_t)m * 12 + t]; }
    __syncthreads();
    const float* lp = logits + (size_t)m * 12 * 512;
    float a0 = 0.f, a1 = 0.f;
    #pragma unroll
    for (int h = 0; h < 12; ++h) {
        a0 += __expf(lp[h * 512 + t] - mxs[h]) * ils[h];
        a1 += __expf(lp[h * 512 + 256 + t] - mxs[h]) * ils[h];
    }
    w[(size_t)m * 512 + t] = a0 * (1.0f / 12.0f);
    w[(size_t)m * 512 + 256 + t] = a1 * (1.0f / 12.0f);
}

// ---------------------------------------------------------------- surf out
__global__ __launch_bounds__(256) void k_surf_out(
    const float* __restrict__ sfeat, const float* __restrict__ saggw,
    const float* __restrict__ Wso, const float* __restrict__ bso,
    float* __restrict__ out)
{
    __shared__ float wl[12304];
    const int t = threadIdx.x;
    for (int idx = t; idx < 12288; idx += 256) {
        int k = idx >> 4, c = idx & 15;
        wl[(k / 192) * 3076 + (k % 192) * 16 + c] = Wso[idx];
    }
    const int m = blockIdx.x * 64 + (t >> 2);
    const int kq = t & 3;
    const float* src = (kq < 2) ? &sfeat[(size_t)m * 384 + kq * 192]
                                : &saggw[(size_t)m * 384 + (kq - 2) * 192];
    __syncthreads();
    float acc[16];
    #pragma unroll
    for (int c = 0; c < 16; ++c) acc[c] = 0.f;
    const float* wb = &wl[kq * 3076];
    for (int k = 0; k < 192; k += 4) {
        float4 v = *(const float4*)&src[k];
        #pragma unroll
        for (int e = 0; e < 4; ++e) {
            float sv = (&v.x)[e];
            #pragma unroll
            for (int c = 0; c < 16; ++c)
                acc[c] = fmaf(sv, wb[(k + e) * 16 + c], acc[c]);
        }
    }
    #pragma unroll
    for (int c = 0; c < 16; ++c) {
        acc[c] += __shfl_xor(acc[c], 1);
        acc[c] += __shfl_xor(acc[c], 2);
    }
    #pragma unroll
    for (int c = 0; c < 16; ++c) {
        if ((c >> 2) == kq) out[196608 + (size_t)m * 16 + c] = acc[c] + bso[c];
    }
}

// ----------------------------------------------------------------
extern "C" void kernel_launch(void* const* d_in, const int* in_sizes, int n_in,
                              void* d_out, int out_size, void* d_ws, size_t ws_size,
                              hipStream_t stream)
{
    (void)in_sizes; (void)n_in; (void)out_size; (void)ws_size;
    const float* s     = (const float*)d_in[0];
    const float* z     = (const float*)d_in[1];
    const float* rots  = (const float*)d_in[2];
    const float* trans = (const float*)d_in[3];
    const float* mask  = (const float*)d_in[4];
    const float* sp    = (const float*)d_in[5];
    const float* sf    = (const float*)d_in[6];
    const float* smask = (const float*)d_in[7];
    const float* Wq    = (const float*)d_in[8];  const float* bq   = (const float*)d_in[9];
    const float* Wkv   = (const float*)d_in[10]; const float* bkv  = (const float*)d_in[11];
    const float* Wqp   = (const float*)d_in[12]; const float* bqp  = (const float*)d_in[13];
    const float* Wkvp  = (const float*)d_in[14]; const float* bkvp = (const float*)d_in[15];
    const float* Wse   = (const float*)d_in[16]; const float* bse  = (const float*)d_in[17];
    const float* Wsq   = (const float*)d_in[18]; const float* bsq  = (const float*)d_in[19];
    const float* Wsk   = (const float*)d_in[20]; const float* bsk  = (const float*)d_in[21];
    const float* Wsv   = (const float*)d_in[22]; const float* bsv  = (const float*)d_in[23];
    const float* Wb    = (const float*)d_in[24]; const float* bb   = (const float*)d_in[25];
    const float* Wdz   = (const float*)d_in[26]; const float* bdz  = (const float*)d_in[27];
    const float* hw    = (const float*)d_in[28]; const float* sbw  = (const float*)d_in[29];
    const float* Wout  = (const float*)d_in[30]; const float* bout = (const float*)d_in[31];
    const float* Wso   = (const float*)d_in[32]; const float* bso  = (const float*)d_in[33];
    float* out = (float*)d_out;

    float* qw    = (float*)d_ws;
    float* kw    = qw    + (size_t)512 * 192;
    float* vw    = kw    + (size_t)512 * 192;
    float* sqw   = vw    + (size_t)512 * 192;
    float* qpw   = sqw   + (size_t)512 * 192;
    float* kpw   = qpw   + (size_t)512 * 144;
    float* vpw   = kpw   + (size_t)512 * 144;
    float* sfeat = vpw   + (size_t)512 * 288;
    float* skv   = sfeat + (size_t)2048 * 384;
    float* ocat  = skv   + (size_t)2048 * 384;
    float* sagg  = ocat  + (size_t)512 * 1152;
    // region: proj (688K fl) -> bpz (11.5M fl) -> logits (12.6M fl), stream-serialized
    float* region = sagg + (size_t)2048 * 384;
    float* proj   = region;
    float* bpz    = region;
    float* logits = region;
    float* wt1   = region + (size_t)2048 * 12 * 512;
    float* wt2   = wt1   + (size_t)1344 * 384;
    float* wt3   = wt2   + (size_t)384 * 384;
    float* b1    = wt3   + (size_t)384 * 1152;
    float* b2    = b1    + 1344;
    float* st    = b2    + 384;
    float* wbuf  = st    + (size_t)384 * 512;
    float* statm = wbuf  + (size_t)2048 * 512;
    float* stati = statm + (size_t)2048 * 12;
    float* abuf  = stati + (size_t)2048 * 12;      // a[12][512][512]
    float* cbuf  = abuf  + (size_t)12 * 512 * 512; // c[12][512][40]
    float* wz    = cbuf  + (size_t)12 * 512 * 40;  // Wz[44][128]
    float* bz    = wz    + (size_t)44 * 128;       // bz[44]
    float* rspm  = bz    + 64;                     // [12][4][512]
    float* rsps  = rspm  + (size_t)12 * 4 * 512;
    float* rmax  = rsps  + (size_t)12 * 4 * 512;   // [12][512]
    float* rinv  = rmax  + (size_t)12 * 512;
    float* pvp   = rinv  + (size_t)12 * 512;       // [12][4][512][16]

    k_pack<<<dim3(1099), dim3(256), 0, stream>>>(Wq, Wsq, Wkv, Wqp, Wkvp, Wsk, Wsv, Wout,
        bq, bsq, bkv, bqp, bkvp, bsk, bsv, wt1, wt2, wt3, b1, b2);
    k_packz<<<dim3(23), dim3(256), 0, stream>>>(Wb, bb, Wdz, bdz, wz, bz);
    k_transp<<<dim3(12, 16), dim3(256), 0, stream>>>(s, st);
    k_gemm<384, true><<<dim3(21, 8), dim3(256), 0, stream>>>(s, wt1, b1, proj, 1344);
    k_scatter<<<dim3(128), dim3(256), 0, stream>>>(proj, rots, trans,
        qw, kw, vw, sqw, qpw, kpw, vpw);
    k_sfeat<<<dim3(256), dim3(256), 0, stream>>>(sf, Wse, bse, sfeat);
    k_gemm<384, true><<<dim3(6, 32), dim3(256), 0, stream>>>(sfeat, wt2, b2, skv, 384);
    k_zpass<<<dim3(2048), dim3(256), 0, stream>>>(z, wz, bz, bpz);
    k_attn_a<<<dim3(512, 3), dim3(256), 0, stream>>>(qw, kw, qpw, kpw, bpz, mask, hw, abuf);
    k_attn_pair<<<dim3(512), dim3(256), 0, stream>>>(abuf, bpz, ocat);
    k_gemm_ov<<<dim3(8, 12), dim3(256), 0, stream>>>(abuf, vw, vpw, cbuf);
    k_optfin<<<dim3(128), dim3(256), 0, stream>>>(cbuf, rots, trans, ocat);
    k_tlog<<<dim3(64, 12), dim3(256), 0, stream>>>(sqw, skv, trans, mask, sp, smask,
        sbw, logits, statm, stati);
    k_rstat<<<dim3(8, 4, 12), dim3(256), 0, stream>>>(logits, rspm, rsps);
    k_rcomb<<<dim3(24), dim3(256), 0, stream>>>(rspm, rsps, rmax, rinv);
    k_pv<<<dim3(8, 4, 12), dim3(256), 0, stream>>>(logits, skv, rmax, rinv, pvp);
    k_pvcomb<<<dim3(384), dim3(256), 0, stream>>>(pvp, ocat);
    k_tw<<<dim3(2048), dim3(256), 0, stream>>>(logits, statm, stati, wbuf);
    k_gemm<512, false><<<dim3(6, 32), dim3(256), 0, stream>>>(wbuf, st, nullptr, sagg, 384);
    k_surf_out<<<dim3(32), dim3(256), 0, stream>>>(sfeat, sagg, Wso, bso, out);
    k_gemm<1152, true><<<dim3(6, 8), dim3(256), 0, stream>>>(ocat, wt3, bout, out, 384);
}

// Round 12
// 520.367 us; speedup vs baseline: 1.0558x; 1.0186x over previous
//
#include <hip/hip_runtime.h>
#include <cstddef>

// IPA + surface cross-attention, B=1, N=512, M=2048, H=12, C_H=16, C_S=384.
// Round 11: k_zpass v5 — j×4 register blocking + k-chunk(32):
// 15 LDS issues per 176 FMA instrs -> VALU/memory-bound; 42.5KB LDS,
// grid 1024 x 256 j-rows. Rest unchanged from R10.

#define CS 384
#define INFV 100000.0f

__device__ __forceinline__ float softplusf(float x) { return log1pf(__expf(x)); }

// ---------------------------------------------------------------- pack
__global__ __launch_bounds__(256) void k_pack(
    const float* __restrict__ Wq, const float* __restrict__ Wsq,
    const float* __restrict__ Wkv, const float* __restrict__ Wqp,
    const float* __restrict__ Wkvp, const float* __restrict__ Wsk,
    const float* __restrict__ Wsv, const float* __restrict__ Wout,
    const float* __restrict__ bq, const float* __restrict__ bsq,
    const float* __restrict__ bkv, const float* __restrict__ bqp,
    const float* __restrict__ bkvp, const float* __restrict__ bsk,
    const float* __restrict__ bsv,
    float* __restrict__ wt1, float* __restrict__ wt2, float* __restrict__ wt3,
    float* __restrict__ b1, float* __restrict__ b2)
{
    const int b = blockIdx.x, t = threadIdx.x;
    if (b >= 1092) {
        int idx = (b - 1092) * 256 + t;
        if (idx < 1344) {
            float v;
            if (idx < 192) v = bq[idx];
            else if (idx < 384) v = bsq[idx - 192];
            else if (idx < 768) v = bkv[idx - 384];
            else if (idx < 912) v = bqp[idx - 768];
            else v = bkvp[idx - 912];
            b1[idx] = v;
        } else if (idx < 1728) {
            int i2 = idx - 1344;
            b2[i2] = (i2 < 192) ? bsk[i2] : bsv[i2 - 192];
        }
        return;
    }
    const float* src; float* dst; int C, coff, tile, ldd;
    if (b < 72)       { src = Wq;   C = 192; dst = wt1; coff = 0;   ldd = 384;  tile = b; }
    else if (b < 144) { src = Wsq;  C = 192; dst = wt1; coff = 192; ldd = 384;  tile = b - 72; }
    else if (b < 288) { src = Wkv;  C = 384; dst = wt1; coff = 384; ldd = 384;  tile = b - 144; }
    else if (b < 348) { src = Wqp;  C = 144; dst = wt1; coff = 768; ldd = 384;  tile = b - 288; }
    else if (b < 516) { src = Wkvp; C = 432; dst = wt1; coff = 912; ldd = 384;  tile = b - 348; }
    else if (b < 588) { src = Wsk;  C = 192; dst = wt2; coff = 0;   ldd = 384;  tile = b - 516; }
    else if (b < 660) { src = Wsv;  C = 192; dst = wt2; coff = 192; ldd = 384;  tile = b - 588; }
    else              { src = Wout; C = 384; dst = wt3; coff = 0;   ldd = 1152; tile = b - 660; }
    const int cT = (C + 31) >> 5;
    const int tk = tile / cT, tc = tile % cT;
    __shared__ float l[32][33];
    const int tr = t >> 5, tcc = t & 31;
    #pragma unroll
    for (int rr = 0; rr < 4; ++rr) {
        int kloc = tr * 4 + rr;
        int cg = tc * 32 + tcc;
        l[kloc][tcc] = (cg < C) ? src[(size_t)(tk * 32 + kloc) * C + cg] : 0.f;
    }
    __syncthreads();
    #pragma unroll
    for (int rr = 0; rr < 4; ++rr) {
        int cloc = tr * 4 + rr;
        int cg = tc * 32 + cloc;
        if (cg < C) dst[(size_t)(coff + cg) * ldd + tk * 32 + tcc] = l[tcc][cloc];
    }
}

// ---------------------------------------------------------------- packz
__global__ __launch_bounds__(256) void k_packz(
    const float* __restrict__ Wb, const float* __restrict__ bb,
    const float* __restrict__ Wdz, const float* __restrict__ bdz,
    float* __restrict__ wz, float* __restrict__ bz)
{
    const float s3 = 0.5773502691896258f;
    int idx = blockIdx.x * 256 + threadIdx.x;
    if (idx < 5632) {
        int c = idx >> 7, kk = idx & 127;
        wz[idx] = (c < 12) ? s3 * Wb[kk * 12 + c] : Wdz[kk * 32 + (c - 12)];
    } else if (idx < 5676) {
        int c = idx - 5632;
        bz[c] = (c < 12) ? s3 * bb[c] : bdz[c - 12];
    }
}

// ---------------------------------------------------------------- transpose
__global__ __launch_bounds__(256) void k_transp(
    const float* __restrict__ A, float* __restrict__ At)
{
    __shared__ float tile[32][33];
    const int r0 = blockIdx.y * 32, c0 = blockIdx.x * 32;
    const int tr = threadIdx.x >> 5, tc = threadIdx.x & 31;
    #pragma unroll
    for (int rr = 0; rr < 4; ++rr)
        tile[tr + rr * 8][tc] = A[(size_t)(r0 + tr + rr * 8) * 384 + c0 + tc];
    __syncthreads();
    #pragma unroll
    for (int rr = 0; rr < 4; ++rr)
        At[(size_t)(c0 + tr + rr * 8) * 512 + r0 + tc] = tile[tc][tr + rr * 8];
}

// ---------------------------------------------------------------- gemm
template<int KTOT, bool HB>
__global__ __launch_bounds__(256) void k_gemm(
    const float* __restrict__ A, const float* __restrict__ Wt,
    const float* __restrict__ bias, float* __restrict__ C, int ldc)
{
    __shared__ float As[64][68];
    __shared__ float Ws[64][68];
    const int t = threadIdx.x;
    const int c0 = blockIdx.x * 64, m0 = blockIdx.y * 64;
    const int sr = t >> 4, sk4 = (t & 15) << 2;
    const int wid = t >> 6, lane = t & 63;
    const int wr = (wid >> 1) * 32, wc = (wid & 1) * 32;
    const int lr = lane >> 3, lc = lane & 7;
    float acc[4][4];
    #pragma unroll
    for (int j = 0; j < 4; ++j) {
        float bv = HB ? bias[c0 + wc + lc + 8 * j] : 0.f;
        #pragma unroll
        for (int i = 0; i < 4; ++i) acc[i][j] = bv;
    }
    for (int kc = 0; kc < KTOT; kc += 64) {
        __syncthreads();
        #pragma unroll
        for (int rep = 0; rep < 4; ++rep) {
            int row = sr + rep * 16;
            *(float4*)&As[row][sk4] = *(const float4*)&A[(size_t)(m0 + row) * KTOT + kc + sk4];
            *(float4*)&Ws[row][sk4] = *(const float4*)&Wt[(size_t)(c0 + row) * KTOT + kc + sk4];
        }
        __syncthreads();
        #pragma unroll 4
        for (int k4 = 0; k4 < 16; ++k4) {
            float4 a[4], w[4];
            #pragma unroll
            for (int i = 0; i < 4; ++i) a[i] = *(float4*)&As[wr + lr + 8 * i][k4 * 4];
            #pragma unroll
            for (int j = 0; j < 4; ++j) w[j] = *(float4*)&Ws[wc + lc + 8 * j][k4 * 4];
            #pragma unroll
            for (int i = 0; i < 4; ++i) {
                #pragma unroll
                for (int j = 0; j < 4; ++j) {
                    acc[i][j] = fmaf(a[i].x, w[j].x, acc[i][j]);
                    acc[i][j] = fmaf(a[i].y, w[j].y, acc[i][j]);
                    acc[i][j] = fmaf(a[i].z, w[j].z, acc[i][j]);
                    acc[i][j] = fmaf(a[i].w, w[j].w, acc[i][j]);
                }
            }
        }
    }
    #pragma unroll
    for (int i = 0; i < 4; ++i) {
        #pragma unroll
        for (int j = 0; j < 4; ++j)
            C[(size_t)(m0 + wr + lr + 8 * i) * ldc + c0 + wc + lc + 8 * j] = acc[i][j];
    }
}

// ---------------------------------------------------------------- scatter
__global__ __launch_bounds__(256) void k_scatter(
    const float* __restrict__ proj, const float* __restrict__ rots,
    const float* __restrict__ trans,
    float* __restrict__ qw, float* __restrict__ kw, float* __restrict__ vw,
    float* __restrict__ sqw, float* __restrict__ qpw, float* __restrict__ kpw,
    float* __restrict__ vpw)
{
    __shared__ float p[4][1344];
    const int n0 = blockIdx.x * 4, t = threadIdx.x;
    for (int idx = t; idx < 1344; idx += 256) {
        #pragma unroll
        for (int r = 0; r < 4; ++r) p[r][idx] = proj[(size_t)(n0 + r) * 1344 + idx];
    }
    __syncthreads();
    for (int idx = t; idx < 3072; idx += 256) {
        int r = idx / 768, c = idx % 768;
        int n = n0 + r;
        float v = p[r][c];
        if (c < 192) qw[(size_t)n * 192 + c] = v;
        else if (c < 384) sqw[(size_t)n * 192 + (c - 192)] = v;
        else {
            int cc = c - 384, h = cc >> 5, sub = cc & 31;
            if (sub < 16) kw[(size_t)n * 192 + h * 16 + sub] = v;
            else          vw[(size_t)n * 192 + h * 16 + (sub - 16)] = v;
        }
    }
    for (int idx = t; idx < 2304; idx += 256) {
        int r = idx / 576, rem = idx % 576;
        int n = n0 + r;
        const float* R = &rots[(size_t)n * 9];
        const float* tr = &trans[(size_t)n * 3];
        if (rem < 144) {
            int pp = rem / 3, d = rem % 3;
            float v = fmaf(R[d*3+0], p[r][768 + pp],
                      fmaf(R[d*3+1], p[r][768 + 48 + pp],
                      fmaf(R[d*3+2], p[r][768 + 96 + pp], tr[d])));
            qpw[(size_t)n * 144 + pp * 3 + d] = v;
        } else {
            int rem2 = rem - 144; int pp = rem2 / 3, d = rem2 % 3;
            float v = fmaf(R[d*3+0], p[r][912 + pp],
                      fmaf(R[d*3+1], p[r][912 + 144 + pp],
                      fmaf(R[d*3+2], p[r][912 + 288 + pp], tr[d])));
            int h = pp / 12, ii = pp % 12;
            if (ii < 4) kpw[(size_t)n * 144 + h * 12 + ii * 3 + d] = v;
            else        vpw[(size_t)n * 288 + h * 24 + (ii - 4) * 3 + d] = v;
        }
    }
}

// ---------------------------------------------------------------- sfeat
__global__ __launch_bounds__(256) void k_sfeat(
    const float* __restrict__ sf, const float* __restrict__ Wse,
    const float* __restrict__ bse, float* __restrict__ sfeat)
{
    __shared__ float wl[16 * 384];
    __shared__ float sfl[8][16];
    const int m0 = blockIdx.x * 8, t = threadIdx.x;
    for (int idx = t; idx < 6144; idx += 256) wl[idx] = Wse[idx];
    if (t < 128) sfl[t >> 4][t & 15] = sf[(size_t)(m0 + (t >> 4)) * 16 + (t & 15)];
    __syncthreads();
    #pragma unroll
    for (int u = 0; u < 12; ++u) {
        int idx = t + u * 256;
        int r = idx / 384, c = idx % 384;
        float a = bse[c];
        #pragma unroll
        for (int kk = 0; kk < 16; ++kk) a = fmaf(sfl[r][kk], wl[kk * 384 + c], a);
        sfeat[(size_t)(m0 + r) * 384 + c] = a;
    }
}

// ---------------------------------------------------------------- zpass v5
// bpz[i][c][j] = z[i][j][:] @ wz[c][:] + bz[c].
// 1024 blocks x 256 j-rows; lane owns 4 j (jl+64g); wave owns 11 c's.
// k in 4 chunks of 32 -> zt[256][36] (36.9KB) + wt[44][32] (5.6KB).
// Per k4: 4 per-lane z b128 + 11 broadcast W b128 vs 176 FMA instrs.
__global__ __launch_bounds__(256) void k_zpass(
    const float* __restrict__ z, const float* __restrict__ wz,
    const float* __restrict__ bz, float* __restrict__ bpz)
{
    __shared__ float zt[256][36];
    __shared__ float wt[44][32];
    const int t = threadIdx.x;
    const int jg0 = blockIdx.x * 256;
    const int i = jg0 >> 9;
    const int jloc = jg0 & 511;
    const int jl = t & 63;
    const int cgs = __builtin_amdgcn_readfirstlane(t >> 6);  // wave-uniform
    float acc[4][11];
    #pragma unroll
    for (int u = 0; u < 11; ++u) {
        float b = bz[cgs * 11 + u];
        acc[0][u] = b; acc[1][u] = b; acc[2][u] = b; acc[3][u] = b;
    }
    for (int kc = 0; kc < 128; kc += 32) {
        __syncthreads();
        // stage W chunk: 44 rows x 8 float4
        for (int idx = t; idx < 352; idx += 256) {
            int c = idx >> 3, k4 = (idx & 7) << 2;
            *(float4*)&wt[c][k4] = *(const float4*)&wz[c * 128 + kc + k4];
        }
        // stage z chunk: 256 rows x 8 float4
        #pragma unroll
        for (int u = 0; u < 8; ++u) {
            int idx = t + u * 256;
            int r = idx >> 3, k4 = (idx & 7) << 2;
            *(float4*)&zt[r][k4] = *(const float4*)&z[((size_t)(jg0 + r)) * 128 + kc + k4];
        }
        __syncthreads();
        const float* wbase = &wt[cgs * 11][0];
        #pragma unroll 2
        for (int k4 = 0; k4 < 32; k4 += 4) {
            float4 z0 = *(float4*)&zt[jl][k4];
            float4 z1 = *(float4*)&zt[jl + 64][k4];
            float4 z2 = *(float4*)&zt[jl + 128][k4];
            float4 z3 = *(float4*)&zt[jl + 192][k4];
            #pragma unroll
            for (int u = 0; u < 11; ++u) {
                float4 wv = *(const float4*)&wbase[u * 32 + k4];  // broadcast
                acc[0][u] = fmaf(z0.x, wv.x, fmaf(z0.y, wv.y,
                            fmaf(z0.z, wv.z, fmaf(z0.w, wv.w, acc[0][u]))));
                acc[1][u] = fmaf(z1.x, wv.x, fmaf(z1.y, wv.y,
                            fmaf(z1.z, wv.z, fmaf(z1.w, wv.w, acc[1][u]))));
                acc[2][u] = fmaf(z2.x, wv.x, fmaf(z2.y, wv.y,
                            fmaf(z2.z, wv.z, fmaf(z2.w, wv.w, acc[2][u]))));
                acc[3][u] = fmaf(z3.x, wv.x, fmaf(z3.y, wv.y,
                            fmaf(z3.z, wv.z, fmaf(z3.w, wv.w, acc[3][u]))));
            }
        }
    }
    #pragma unroll
    for (int u = 0; u < 11; ++u) {
        size_t base = ((size_t)i * 44 + cgs * 11 + u) * 512 + jloc;
        bpz[base + jl]       = acc[0][u];
        bpz[base + 64 + jl]  = acc[1][u];
        bpz[base + 128 + jl] = acc[2][u];
        bpz[base + 192 + jl] = acc[3][u];
    }
}

// ---------------------------------------------------------------- attn_a
__global__ __launch_bounds__(256) void k_attn_a(
    const float* __restrict__ qw, const float* __restrict__ kw,
    const float* __restrict__ qpw, const float* __restrict__ kpw,
    const float* __restrict__ bpz, const float* __restrict__ mask,
    const float* __restrict__ hwp, float* __restrict__ abuf)
{
    __shared__ float pls[4][520];
    __shared__ float qs[64], qps[48], cpt4[4];
    const int i = blockIdx.x, hg = blockIdx.y;
    const int t = threadIdx.x;
    if (t < 64) qs[t] = qw[(size_t)i * 192 + hg * 64 + t];
    if (t < 48) qps[t] = qpw[(size_t)i * 144 + hg * 48 + t];
    if (t < 4) cpt4[t] = -0.5f * 0.13608276348795434f * softplusf(hwp[hg * 4 + t]);
    const float mask_i = mask[i];
    __syncthreads();
    #pragma unroll 2
    for (int it = 0; it < 8; ++it) {
        int idx = t + it * 256;
        int hh = idx >> 9, j = idx & 511;
        int h = hg * 4 + hh;
        float kj[16], kpj[12];
        { const float4* kr = (const float4*)&kw[(size_t)j * 192 + h * 16];
          *(float4*)&kj[0] = kr[0]; *(float4*)&kj[4] = kr[1];
          *(float4*)&kj[8] = kr[2]; *(float4*)&kj[12] = kr[3]; }
        { const float4* kr = (const float4*)&kpw[(size_t)j * 144 + h * 12];
          *(float4*)&kpj[0] = kr[0]; *(float4*)&kpj[4] = kr[1]; *(float4*)&kpj[8] = kr[2]; }
        float qk = 0.f;
        #pragma unroll
        for (int c = 0; c < 16; ++c) qk = fmaf(qs[hh * 16 + c], kj[c], qk);
        float pts = 0.f;
        #pragma unroll
        for (int p = 0; p < 4; ++p) {
            float dx = qps[hh*12+p*3+0] - kpj[p*3+0];
            float dy = qps[hh*12+p*3+1] - kpj[p*3+1];
            float dz = qps[hh*12+p*3+2] - kpj[p*3+2];
            pts += dx*dx + dy*dy + dz*dz;
        }
        float lg = fmaf(0.14433756729740643f, qk, bpz[((size_t)i * 44 + h) * 512 + j]);
        lg = fmaf(cpt4[hh], pts, lg);
        lg += INFV * (mask_i * mask[j] - 1.0f);
        pls[hh][j] = lg;
    }
    __syncthreads();
    const int w = t >> 6, lane = t & 63;
    float v[8];
    #pragma unroll
    for (int k = 0; k < 8; ++k) v[k] = pls[w][lane + k * 64];
    float mx = v[0];
    #pragma unroll
    for (int k = 1; k < 8; ++k) mx = fmaxf(mx, v[k]);
    #pragma unroll
    for (int off = 32; off; off >>= 1) mx = fmaxf(mx, __shfl_xor(mx, off));
    float sm = 0.f;
    #pragma unroll
    for (int k = 0; k < 8; ++k) { v[k] = __expf(v[k] - mx); sm += v[k]; }
    #pragma unroll
    for (int off = 32; off; off >>= 1) sm += __shfl_xor(sm, off);
    const float inv = 1.0f / sm;
    float* dst = abuf + ((size_t)(hg * 4 + w) * 512 + i) * 512;
    #pragma unroll
    for (int k = 0; k < 8; ++k) dst[lane + k * 64] = v[k] * inv;
}

// ---------------------------------------------------------------- attn_pair
__global__ __launch_bounds__(256) void k_attn_pair(
    const float* __restrict__ abuf, const float* __restrict__ bpz,
    float* __restrict__ ocat)
{
    __shared__ float al[12][512];
    const int i = blockIdx.x, t = threadIdx.x;
    #pragma unroll
    for (int u = 0; u < 12; ++u) {
        al[u][t] = abuf[(size_t)u * 262144 + (size_t)i * 512 + t];
        al[u][t + 256] = abuf[(size_t)u * 262144 + (size_t)i * 512 + t + 256];
    }
    __syncthreads();
    const int c = t & 31;
    const int h1 = t >> 5;
    const bool dual = (t < 128);
    const float* pz = bpz + ((size_t)i * 44 + 12 + c) * 512;
    const float* a1 = al[h1];
    const float* a2 = al[dual ? h1 + 8 : 0];
    float acc1 = 0.f, acc2 = 0.f;
    for (int j = 0; j < 512; j += 4) {
        float4 p = *(const float4*)&pz[j];
        acc1 = fmaf(a1[j+0], p.x, acc1);
        acc1 = fmaf(a1[j+1], p.y, acc1);
        acc1 = fmaf(a1[j+2], p.z, acc1);
        acc1 = fmaf(a1[j+3], p.w, acc1);
        if (dual) {
            acc2 = fmaf(a2[j+0], p.x, acc2);
            acc2 = fmaf(a2[j+1], p.y, acc2);
            acc2 = fmaf(a2[j+2], p.z, acc2);
            acc2 = fmaf(a2[j+3], p.w, acc2);
        }
    }
    ocat[(size_t)i * 1152 + 576 + h1 * 32 + c] = acc1;
    if (dual) ocat[(size_t)i * 1152 + 576 + (h1 + 8) * 32 + c] = acc2;
}

// ---------------------------------------------------------------- gemm_ov
__global__ __launch_bounds__(256) void k_gemm_ov(
    const float* __restrict__ abuf, const float* __restrict__ vw,
    const float* __restrict__ vpw, float* __restrict__ cbuf)
{
    __shared__ float As[64][68];
    __shared__ float Bs[64][44];
    const int i0 = blockIdx.x * 64, h = blockIdx.y;
    const int t = threadIdx.x;
    const int sr = t >> 4, sk4 = (t & 15) << 2;
    const int r1 = t >> 3;
    const int cb = t & 7;
    float acc[2][5];
    #pragma unroll
    for (int u = 0; u < 5; ++u) { acc[0][u] = 0.f; acc[1][u] = 0.f; }
    for (int kc = 0; kc < 512; kc += 64) {
        __syncthreads();
        #pragma unroll
        for (int rep = 0; rep < 4; ++rep) {
            int row = sr + rep * 16;
            *(float4*)&As[row][sk4] =
                *(const float4*)&abuf[(size_t)h * 262144 + (size_t)(i0 + row) * 512 + kc + sk4];
        }
        #pragma unroll
        for (int u = 0; u < 10; ++u) {
            int idx = t + u * 256;
            int r = idx / 40, cc = idx % 40;
            Bs[r][cc] = (cc < 16) ? vw[(size_t)(kc + r) * 192 + h * 16 + cc]
                                  : vpw[(size_t)(kc + r) * 288 + h * 24 + (cc - 16)];
        }
        __syncthreads();
        #pragma unroll 4
        for (int kk = 0; kk < 64; ++kk) {
            float av1 = As[r1][kk], av2 = As[r1 + 32][kk];
            #pragma unroll
            for (int u = 0; u < 5; ++u) {
                float b = Bs[kk][cb + 8 * u];
                acc[0][u] = fmaf(av1, b, acc[0][u]);
                acc[1][u] = fmaf(av2, b, acc[1][u]);
            }
        }
    }
    #pragma unroll
    for (int u = 0; u < 5; ++u) {
        cbuf[((size_t)h * 512 + i0 + r1) * 40 + cb + 8 * u] = acc[0][u];
        cbuf[((size_t)h * 512 + i0 + r1 + 32) * 40 + cb + 8 * u] = acc[1][u];
    }
}

// ---------------------------------------------------------------- optfin
__global__ __launch_bounds__(256) void k_optfin(
    const float* __restrict__ cbuf, const float* __restrict__ rots,
    const float* __restrict__ trans, float* __restrict__ ocat)
{
    __shared__ float cl[4][12][40];
    const int i0 = blockIdx.x * 4, t = threadIdx.x;
    for (int idx = t; idx < 1920; idx += 256) {
        int ii = idx / 480, rem = idx % 480;
        int h = rem / 40, c = rem % 40;
        cl[ii][h][c] = cbuf[((size_t)h * 512 + i0 + ii) * 40 + c];
    }
    __syncthreads();
    for (int idx = t; idx < 768; idx += 256) {
        int ii = idx / 192, o = idx % 192;
        ocat[(size_t)(i0 + ii) * 1152 + o] = cl[ii][o >> 4][o & 15];
    }
    for (int idx = t; idx < 384; idx += 256) {
        int ii = idx / 96, hp = idx % 96;
        int h = hp >> 3, p = hp & 7;
        int i = i0 + ii;
        const float* R = &rots[(size_t)i * 9];
        float gx = cl[ii][h][16 + p*3 + 0] - trans[(size_t)i*3 + 0];
        float gy = cl[ii][h][16 + p*3 + 1] - trans[(size_t)i*3 + 1];
        float gz = cl[ii][h][16 + p*3 + 2] - trans[(size_t)i*3 + 2];
        float lx = R[0]*gx + R[3]*gy + R[6]*gz;
        float ly = R[1]*gx + R[4]*gy + R[7]*gz;
        float lz = R[2]*gx + R[5]*gy + R[8]*gz;
        float nm = sqrtf(lx*lx + ly*ly + lz*lz + 1e-8f);
        int col = h * 8 + p;
        size_t base = (size_t)i * 1152;
        ocat[base + 192 + col] = lx;
        ocat[base + 288 + col] = ly;
        ocat[base + 384 + col] = lz;
        ocat[base + 480 + col] = nm;
    }
}

// ---------------------------------------------------------------- tlog
__global__ __launch_bounds__(256) void k_tlog(
    const float* __restrict__ sqw, const float* __restrict__ skv,
    const float* __restrict__ trans, const float* __restrict__ mask,
    const float* __restrict__ sp, const float* __restrict__ smask,
    const float* __restrict__ sbwp, float* __restrict__ logits,
    float* __restrict__ stat_m, float* __restrict__ stat_il)
{
    __shared__ float sk_s[32][16];
    __shared__ float sq_s[32][16];
    __shared__ float trans_s[96];
    __shared__ float mask_s[32];
    __shared__ float spm_s[96];
    __shared__ float smask_s[32];
    const int h = blockIdx.y;
    const int m0 = blockIdx.x * 32;
    const int t = threadIdx.x;
    const int tmg = t >> 5, tnl = t & 31;
    const float sbw = softplusf(sbwp[0]);
    for (int idx = t; idx < 512; idx += 256) {
        int row = idx >> 4, c = idx & 15;
        sk_s[row][c] = skv[(size_t)(m0 + row) * 384 + h * 16 + c];
    }
    if (t < 96) spm_s[t] = sp[(size_t)m0 * 3 + t];
    if (t < 32) smask_s[t] = smask[m0 + t];
    __syncthreads();
    float skr[4][16];
    float spx[4], spy[4], spz[4], smk[4];
    #pragma unroll
    for (int mi = 0; mi < 4; ++mi) {
        int row = tmg * 4 + mi;
        #pragma unroll
        for (int c4 = 0; c4 < 16; c4 += 4)
            *(float4*)&skr[mi][c4] = *(float4*)&sk_s[row][c4];
        spx[mi] = spm_s[row*3+0]; spy[mi] = spm_s[row*3+1]; spz[mi] = spm_s[row*3+2];
        smk[mi] = smask_s[row];
    }
    float mxr[4], lr[4];
    #pragma unroll
    for (int mi = 0; mi < 4; ++mi) { mxr[mi] = -1e30f; lr[mi] = 0.f; }
    for (int nt = 0; nt < 16; ++nt) {
        __syncthreads();
        const int nb = nt * 32;
        if (t < 128) {
            int nn = t >> 2, c4 = (t & 3) << 2;
            *(float4*)&sq_s[nn][c4] = *(const float4*)&sqw[(size_t)(nb + nn) * 192 + h * 16 + c4];
        }
        if (t < 96) trans_s[t] = trans[(size_t)nb * 3 + t];
        if (t < 32) mask_s[t] = mask[nb + t];
        __syncthreads();
        float q[16];
        #pragma unroll
        for (int c4 = 0; c4 < 16; c4 += 4)
            *(float4*)&q[c4] = *(float4*)&sq_s[tnl][c4];
        const float tx = trans_s[tnl*3+0], ty = trans_s[tnl*3+1], tz = trans_s[tnl*3+2];
        const float mkn = mask_s[tnl];
        #pragma unroll
        for (int mi = 0; mi < 4; ++mi) {
            float dot = 0.f;
            #pragma unroll
            for (int c = 0; c < 16; ++c) dot = fmaf(skr[mi][c], q[c], dot);
            float dx = tx - spx[mi], dy = ty - spy[mi], dz = tz - spz[mi];
            float mterm = INFV * (mkn * smk[mi] - 1.0f) - 0.5f * sbw * (dx*dx + dy*dy + dz*dz);
            float lg = fmaf(0.25f, dot, mterm);
            logits[((size_t)(m0 + tmg * 4 + mi) * 12 + h) * 512 + nb + tnl] = lg;
            float newm = fmaxf(mxr[mi], lg);
            lr[mi] = lr[mi] * __expf(mxr[mi] - newm) + __expf(lg - newm);
            mxr[mi] = newm;
        }
    }
    #pragma unroll
    for (int off = 1; off < 32; off <<= 1) {
        #pragma unroll
        for (int mi = 0; mi < 4; ++mi) {
            float m2 = __shfl_xor(mxr[mi], off), l2 = __shfl_xor(lr[mi], off);
            float newm = fmaxf(mxr[mi], m2);
            lr[mi] = lr[mi] * __expf(mxr[mi] - newm) + l2 * __expf(m2 - newm);
            mxr[mi] = newm;
        }
    }
    if (tnl == 0) {
        #pragma unroll
        for (int mi = 0; mi < 4; ++mi) {
            int m = m0 + tmg * 4 + mi;
            stat_m[(size_t)m * 12 + h] = mxr[mi];
            stat_il[(size_t)m * 12 + h] = 1.0f / lr[mi];
        }
    }
}

// ---------------------------------------------------------------- rstat
__global__ __launch_bounds__(256) void k_rstat(
    const float* __restrict__ lbuf, float* __restrict__ rspm,
    float* __restrict__ rsps)
{
    __shared__ float smx[4][64], ssm[4][64];
    const int n0 = blockIdx.x * 64, mc = blockIdx.y, h = blockIdx.z;
    const int t = threadIdx.x, ln = t & 63, mg = t >> 6;
    const int mb = mc * 512;
    const int n = n0 + ln;
    float mx = -1e30f, sm = 0.f;
    #pragma unroll 2
    for (int it = 0; it < 128; ++it) {
        int m = mb + it * 4 + mg;
        float lg = lbuf[((size_t)m * 12 + h) * 512 + n];
        float nm = fmaxf(mx, lg);
        sm = sm * __expf(mx - nm) + __expf(lg - nm);
        mx = nm;
    }
    smx[mg][ln] = mx; ssm[mg][ln] = sm;
    __syncthreads();
    if (t < 64) {
        float M = smx[0][t], S = ssm[0][t];
        #pragma unroll
        for (int g = 1; g < 4; ++g) {
            float m2 = smx[g][t], s2 = ssm[g][t];
            float nm = fmaxf(M, m2);
            S = S * __expf(M - nm) + s2 * __expf(m2 - nm);
            M = nm;
        }
        rspm[((size_t)h * 4 + mc) * 512 + n0 + t] = M;
        rsps[((size_t)h * 4 + mc) * 512 + n0 + t] = S;
    }
}

// ---------------------------------------------------------------- rcomb
__global__ __launch_bounds__(256) void k_rcomb(
    const float* __restrict__ rspm, const float* __restrict__ rsps,
    float* __restrict__ rmax, float* __restrict__ rinv)
{
    int gid = blockIdx.x * 256 + threadIdx.x;
    if (gid >= 6144) return;
    int h = gid >> 9, n = gid & 511;
    float M = -1e30f, S = 0.f;
    #pragma unroll
    for (int mc = 0; mc < 4; ++mc) {
        float m2 = rspm[((size_t)h * 4 + mc) * 512 + n];
        float s2 = rsps[((size_t)h * 4 + mc) * 512 + n];
        float nm = fmaxf(M, m2);
        S = S * __expf(M - nm) + s2 * __expf(m2 - nm);
        M = nm;
    }
    rmax[gid] = M;
    rinv[gid] = 1.0f / S;
}

// ---------------------------------------------------------------- pv
__global__ __launch_bounds__(256) void k_pv(
    const float* __restrict__ lbuf, const float* __restrict__ skv,
    const float* __restrict__ rmax, const float* __restrict__ rinv,
    float* __restrict__ pvp)
{
    __shared__ float sv_s[512][17];
    const int n0 = blockIdx.x * 64, mc = blockIdx.y, h = blockIdx.z;
    const int t = threadIdx.x, ln = t & 63, mg = t >> 6;
    const int mb = mc * 512;
    for (int idx = t; idx < 2048; idx += 256) {
        int ml = idx >> 2, c4 = (idx & 3) << 2;
        float4 v4 = *(const float4*)&skv[(size_t)(mb + ml) * 384 + 192 + h * 16 + c4];
        sv_s[ml][c4+0]=v4.x; sv_s[ml][c4+1]=v4.y; sv_s[ml][c4+2]=v4.z; sv_s[ml][c4+3]=v4.w;
    }
    const int n = n0 + ln;
    const float rm = rmax[h * 512 + n], ri = rinv[h * 512 + n];
    float acc[16];
    #pragma unroll
    for (int c = 0; c < 16; ++c) acc[c] = 0.f;
    __syncthreads();
    #pragma unroll 2
    for (int it = 0; it < 128; ++it) {
        int ml = it * 4 + mg;
        float w = __expf(lbuf[((size_t)(mb + ml) * 12 + h) * 512 + n] - rm) * ri;
        #pragma unroll
        for (int c = 0; c < 16; ++c) acc[c] = fmaf(w, sv_s[ml][c], acc[c]);
    }
    __syncthreads();
    float* red = &sv_s[0][0];
    #pragma unroll
    for (int c = 0; c < 16; ++c) red[(mg * 64 + ln) * 17 + c] = acc[c];
    __syncthreads();
    {
        int nl = t >> 2, c4 = (t & 3) << 2;
        float4 o;
        #pragma unroll
        for (int e = 0; e < 4; ++e) {
            float s = 0.f;
            #pragma unroll
            for (int g = 0; g < 4; ++g) s += red[(g * 64 + nl) * 17 + c4 + e];
            (&o.x)[e] = s;
        }
        *(float4*)&pvp[(((size_t)h * 4 + mc) * 512 + n0 + nl) * 16 + c4] = o;
    }
}

// ---------------------------------------------------------------- pvcomb
__global__ __launch_bounds__(256) void k_pvcomb(
    const float* __restrict__ pvp, float* __restrict__ ocat)
{
    int gid = blockIdx.x * 256 + threadIdx.x;
    int n = gid / 192, rem = gid % 192;
    float o = 0.f;
    #pragma unroll
    for (int mc = 0; mc < 4; ++mc)
        o += pvp[(((size_t)(rem >> 4) * 4 + mc) * 512 + n) * 16 + (rem & 15)];
    ocat[(size_t)n * 1152 + 960 + rem] = o;
}

// ---------------------------------------------------------------- tw
__global__ __launch_bounds__(256) void k_tw(
    const float* __restrict__ logits, const float* __restrict__ stat_m,
    const float* __restrict__ stat_il, float* __restrict__ w)
{
    __shared__ float mxs[12], ils[12];
    const int m = blockIdx.x, t = threadIdx.x;
    if (t < 12) { mxs[t] = stat_m[(size_t)m * 12 + t]; ils[t] = stat_il[(size_t)m * 12 + t]; }
    __syncthreads();
    const float* lp = logits + (size_t)m * 12 * 512;
    float a0 = 0.f, a1 = 0.f;
    #pragma unroll
    for (int h = 0; h < 12; ++h) {
        a0 += __expf(lp[h * 512 + t] - mxs[h]) * ils[h];
        a1 += __expf(lp[h * 512 + 256 + t] - mxs[h]) * ils[h];
    }
    w[(size_t)m * 512 + t] = a0 * (1.0f / 12.0f);
    w[(size_t)m * 512 + 256 + t] = a1 * (1.0f / 12.0f);
}

// ---------------------------------------------------------------- surf out
__global__ __launch_bounds__(256) void k_surf_out(
    const float* __restrict__ sfeat, const float* __restrict__ saggw,
    const float* __restrict__ Wso, const float* __restrict__ bso,
    float* __restrict__ out)
{
    __shared__ float wl[12304];
    const int t = threadIdx.x;
    for (int idx = t; idx < 12288; idx += 256) {
        int k = idx >> 4, c = idx & 15;
        wl[(k / 192) * 3076 + (k % 192) * 16 + c] = Wso[idx];
    }
    const int m = blockIdx.x * 64 + (t >> 2);
    const int kq = t & 3;
    const float* src = (kq < 2) ? &sfeat[(size_t)m * 384 + kq * 192]
                                : &saggw[(size_t)m * 384 + (kq - 2) * 192];
    __syncthreads();
    float acc[16];
    #pragma unroll
    for (int c = 0; c < 16; ++c) acc[c] = 0.f;
    const float* wb = &wl[kq * 3076];
    for (int k = 0; k < 192; k += 4) {
        float4 v = *(const float4*)&src[k];
        #pragma unroll
        for (int e = 0; e < 4; ++e) {
            float sv = (&v.x)[e];
            #pragma unroll
            for (int c = 0; c < 16; ++c)
                acc[c] = fmaf(sv, wb[(k + e) * 16 + c], acc[c]);
        }
    }
    #pragma unroll
    for (int c = 0; c < 16; ++c) {
        acc[c] += __shfl_xor(acc[c], 1);
        acc[c] += __shfl_xor(acc[c], 2);
    }
    #pragma unroll
    for (int c = 0; c < 16; ++c) {
        if ((c >> 2) == kq) out[196608 + (size_t)m * 16 + c] = acc[c] + bso[c];
    }
}

// ----------------------------------------------------------------
extern "C" void kernel_launch(void* const* d_in, const int* in_sizes, int n_in,
                              void* d_out, int out_size, void* d_ws, size_t ws_size,
                              hipStream_t stream)
{
    (void)in_sizes; (void)n_in; (void)out_size; (void)ws_size;
    const float* s     = (const float*)d_in[0];
    const float* z     = (const float*)d_in[1];
    const float* rots  = (const float*)d_in[2];
    const float* trans = (const float*)d_in[3];
    const float* mask  = (const float*)d_in[4];
    const float* sp    = (const float*)d_in[5];
    const float* sf    = (const float*)d_in[6];
    const float* smask = (const float*)d_in[7];
    const float* Wq    = (const float*)d_in[8];  const float* bq   = (const float*)d_in[9];
    const float* Wkv   = (const float*)d_in[10]; const float* bkv  = (const float*)d_in[11];
    const float* Wqp   = (const float*)d_in[12]; const float* bqp  = (const float*)d_in[13];
    const float* Wkvp  = (const float*)d_in[14]; const float* bkvp = (const float*)d_in[15];
    const float* Wse   = (const float*)d_in[16]; const float* bse  = (const float*)d_in[17];
    const float* Wsq   = (const float*)d_in[18]; const float* bsq  = (const float*)d_in[19];
    const float* Wsk   = (const float*)d_in[20]; const float* bsk  = (const float*)d_in[21];
    const float* Wsv   = (const float*)d_in[22]; const float* bsv  = (const float*)d_in[23];
    const float* Wb    = (const float*)d_in[24]; const float* bb   = (const float*)d_in[25];
    const float* Wdz   = (const float*)d_in[26]; const float* bdz  = (const float*)d_in[27];
    const float* hw    = (const float*)d_in[28]; const float* sbw  = (const float*)d_in[29];
    const float* Wout  = (const float*)d_in[30]; const float* bout = (const float*)d_in[31];
    const float* Wso   = (const float*)d_in[32]; const float* bso  = (const float*)d_in[33];
    float* out = (float*)d_out;

    float* qw    = (float*)d_ws;
    float* kw    = qw    + (size_t)512 * 192;
    float* vw    = kw    + (size_t)512 * 192;
    float* sqw   = vw    + (size_t)512 * 192;
    float* qpw   = sqw   + (size_t)512 * 192;
    float* kpw   = qpw   + (size_t)512 * 144;
    float* vpw   = kpw   + (size_t)512 * 144;
    float* sfeat = vpw   + (size_t)512 * 288;
    float* skv   = sfeat + (size_t)2048 * 384;
    float* ocat  = skv   + (size_t)2048 * 384;
    float* sagg  = ocat  + (size_t)512 * 1152;
    // region: proj (688K fl) -> bpz (11.5M fl) -> logits (12.6M fl), stream-serialized
    float* region = sagg + (size_t)2048 * 384;
    float* proj   = region;
    float* bpz    = region;
    float* logits = region;
    float* wt1   = region + (size_t)2048 * 12 * 512;
    float* wt2   = wt1   + (size_t)1344 * 384;
    float* wt3   = wt2   + (size_t)384 * 384;
    float* b1    = wt3   + (size_t)384 * 1152;
    float* b2    = b1    + 1344;
    float* st    = b2    + 384;
    float* wbuf  = st    + (size_t)384 * 512;
    float* statm = wbuf  + (size_t)2048 * 512;
    float* stati = statm + (size_t)2048 * 12;
    float* abuf  = stati + (size_t)2048 * 12;      // a[12][512][512]
    float* cbuf  = abuf  + (size_t)12 * 512 * 512; // c[12][512][40]
    float* wz    = cbuf  + (size_t)12 * 512 * 40;  // Wz[44][128]
    float* bz    = wz    + (size_t)44 * 128;       // bz[44]
    float* rspm  = bz    + 64;                     // [12][4][512]
    float* rsps  = rspm  + (size_t)12 * 4 * 512;
    float* rmax  = rsps  + (size_t)12 * 4 * 512;   // [12][512]
    float* rinv  = rmax  + (size_t)12 * 512;
    float* pvp   = rinv  + (size_t)12 * 512;       // [12][4][512][16]

    k_pack<<<dim3(1099), dim3(256), 0, stream>>>(Wq, Wsq, Wkv, Wqp, Wkvp, Wsk, Wsv, Wout,
        bq, bsq, bkv, bqp, bkvp, bsk, bsv, wt1, wt2, wt3, b1, b2);
    k_packz<<<dim3(23), dim3(256), 0, stream>>>(Wb, bb, Wdz, bdz, wz, bz);
    k_transp<<<dim3(12, 16), dim3(256), 0, stream>>>(s, st);
    k_gemm<384, true><<<dim3(21, 8), dim3(256), 0, stream>>>(s, wt1, b1, proj, 1344);
    k_scatter<<<dim3(128), dim3(256), 0, stream>>>(proj, rots, trans,
        qw, kw, vw, sqw, qpw, kpw, vpw);
    k_sfeat<<<dim3(256), dim3(256), 0, stream>>>(sf, Wse, bse, sfeat);
    k_gemm<384, true><<<dim3(6, 32), dim3(256), 0, stream>>>(sfeat, wt2, b2, skv, 384);
    k_zpass<<<dim3(1024), dim3(256), 0, stream>>>(z, wz, bz, bpz);
    k_attn_a<<<dim3(512, 3), dim3(256), 0, stream>>>(qw, kw, qpw, kpw, bpz, mask, hw, abuf);
    k_attn_pair<<<dim3(512), dim3(256), 0, stream>>>(abuf, bpz, ocat);
    k_gemm_ov<<<dim3(8, 12), dim3(256), 0, stream>>>(abuf, vw, vpw, cbuf);
    k_optfin<<<dim3(128), dim3(256), 0, stream>>>(cbuf, rots, trans, ocat);
    k_tlog<<<dim3(64, 12), dim3(256), 0, stream>>>(sqw, skv, trans, mask, sp, smask,
        sbw, logits, statm, stati);
    k_rstat<<<dim3(8, 4, 12), dim3(256), 0, stream>>>(logits, rspm, rsps);
    k_rcomb<<<dim3(24), dim3(256), 0, stream>>>(rspm, rsps, rmax, rinv);
    k_pv<<<dim3(8, 4, 12), dim3(256), 0, stream>>>(logits, skv, rmax, rinv, pvp);
    k_pvcomb<<<dim3(384), dim3(256), 0, stream>>>(pvp, ocat);
    k_tw<<<dim3(2048), dim3(256), 0, stream>>>(logits, statm, stati, wbuf);
    k_gemm<512, false><<<dim3(6, 32), dim3(256), 0, stream>>>(wbuf, st, nullptr, sagg, 384);
    k_surf_out<<<dim3(32), dim3(256), 0, stream>>>(sfeat, sagg, Wso, bso, out);
    k_gemm<1152, true><<<dim3(6, 8), dim3(256), 0, stream>>>(ocat, wt3, bout, out, 384);
}

// Round 13
// 467.945 us; speedup vs baseline: 1.1741x; 1.1120x over previous
//
#include <hip/hip_runtime.h>
#include <cstddef>

// IPA + surface cross-attention, B=1, N=512, M=2048, H=12, C_H=16, C_S=384.
// Round 12: GEMM-ify IPA logits. k_aprep packs 32-dim rows (|qp-kp|^2
// expanded into r_i + c_j - 2qp·kp); k_attn_a v2 = register/LDS-tiled dot
// writing RAW logits + row stats; softmax applied during consumer staging
// (k_attn_pair, k_gemm_ov). k_zpass v5 and rest unchanged from R11.

#define CS 384
#define INFV 100000.0f

__device__ __forceinline__ float softplusf(float x) { return log1pf(__expf(x)); }

// ---------------------------------------------------------------- pack
__global__ __launch_bounds__(256) void k_pack(
    const float* __restrict__ Wq, const float* __restrict__ Wsq,
    const float* __restrict__ Wkv, const float* __restrict__ Wqp,
    const float* __restrict__ Wkvp, const float* __restrict__ Wsk,
    const float* __restrict__ Wsv, const float* __restrict__ Wout,
    const float* __restrict__ bq, const float* __restrict__ bsq,
    const float* __restrict__ bkv, const float* __restrict__ bqp,
    const float* __restrict__ bkvp, const float* __restrict__ bsk,
    const float* __restrict__ bsv,
    float* __restrict__ wt1, float* __restrict__ wt2, float* __restrict__ wt3,
    float* __restrict__ b1, float* __restrict__ b2)
{
    const int b = blockIdx.x, t = threadIdx.x;
    if (b >= 1092) {
        int idx = (b - 1092) * 256 + t;
        if (idx < 1344) {
            float v;
            if (idx < 192) v = bq[idx];
            else if (idx < 384) v = bsq[idx - 192];
            else if (idx < 768) v = bkv[idx - 384];
            else if (idx < 912) v = bqp[idx - 768];
            else v = bkvp[idx - 912];
            b1[idx] = v;
        } else if (idx < 1728) {
            int i2 = idx - 1344;
            b2[i2] = (i2 < 192) ? bsk[i2] : bsv[i2 - 192];
        }
        return;
    }
    const float* src; float* dst; int C, coff, tile, ldd;
    if (b < 72)       { src = Wq;   C = 192; dst = wt1; coff = 0;   ldd = 384;  tile = b; }
    else if (b < 144) { src = Wsq;  C = 192; dst = wt1; coff = 192; ldd = 384;  tile = b - 72; }
    else if (b < 288) { src = Wkv;  C = 384; dst = wt1; coff = 384; ldd = 384;  tile = b - 144; }
    else if (b < 348) { src = Wqp;  C = 144; dst = wt1; coff = 768; ldd = 384;  tile = b - 288; }
    else if (b < 516) { src = Wkvp; C = 432; dst = wt1; coff = 912; ldd = 384;  tile = b - 348; }
    else if (b < 588) { src = Wsk;  C = 192; dst = wt2; coff = 0;   ldd = 384;  tile = b - 516; }
    else if (b < 660) { src = Wsv;  C = 192; dst = wt2; coff = 192; ldd = 384;  tile = b - 588; }
    else              { src = Wout; C = 384; dst = wt3; coff = 0;   ldd = 1152; tile = b - 660; }
    const int cT = (C + 31) >> 5;
    const int tk = tile / cT, tc = tile % cT;
    __shared__ float l[32][33];
    const int tr = t >> 5, tcc = t & 31;
    #pragma unroll
    for (int rr = 0; rr < 4; ++rr) {
        int kloc = tr * 4 + rr;
        int cg = tc * 32 + tcc;
        l[kloc][tcc] = (cg < C) ? src[(size_t)(tk * 32 + kloc) * C + cg] : 0.f;
    }
    __syncthreads();
    #pragma unroll
    for (int rr = 0; rr < 4; ++rr) {
        int cloc = tr * 4 + rr;
        int cg = tc * 32 + cloc;
        if (cg < C) dst[(size_t)(coff + cg) * ldd + tk * 32 + tcc] = l[tcc][cloc];
    }
}

// ---------------------------------------------------------------- packz
__global__ __launch_bounds__(256) void k_packz(
    const float* __restrict__ Wb, const float* __restrict__ bb,
    const float* __restrict__ Wdz, const float* __restrict__ bdz,
    float* __restrict__ wz, float* __restrict__ bz)
{
    const float s3 = 0.5773502691896258f;
    int idx = blockIdx.x * 256 + threadIdx.x;
    if (idx < 5632) {
        int c = idx >> 7, kk = idx & 127;
        wz[idx] = (c < 12) ? s3 * Wb[kk * 12 + c] : Wdz[kk * 32 + (c - 12)];
    } else if (idx < 5676) {
        int c = idx - 5632;
        bz[c] = (c < 12) ? s3 * bb[c] : bdz[c - 12];
    }
}

// ---------------------------------------------------------------- transpose
__global__ __launch_bounds__(256) void k_transp(
    const float* __restrict__ A, float* __restrict__ At)
{
    __shared__ float tile[32][33];
    const int r0 = blockIdx.y * 32, c0 = blockIdx.x * 32;
    const int tr = threadIdx.x >> 5, tc = threadIdx.x & 31;
    #pragma unroll
    for (int rr = 0; rr < 4; ++rr)
        tile[tr + rr * 8][tc] = A[(size_t)(r0 + tr + rr * 8) * 384 + c0 + tc];
    __syncthreads();
    #pragma unroll
    for (int rr = 0; rr < 4; ++rr)
        At[(size_t)(c0 + tr + rr * 8) * 512 + r0 + tc] = tile[tc][tr + rr * 8];
}

// ---------------------------------------------------------------- gemm
template<int KTOT, bool HB>
__global__ __launch_bounds__(256) void k_gemm(
    const float* __restrict__ A, const float* __restrict__ Wt,
    const float* __restrict__ bias, float* __restrict__ C, int ldc)
{
    __shared__ float As[64][68];
    __shared__ float Ws[64][68];
    const int t = threadIdx.x;
    const int c0 = blockIdx.x * 64, m0 = blockIdx.y * 64;
    const int sr = t >> 4, sk4 = (t & 15) << 2;
    const int wid = t >> 6, lane = t & 63;
    const int wr = (wid >> 1) * 32, wc = (wid & 1) * 32;
    const int lr = lane >> 3, lc = lane & 7;
    float acc[4][4];
    #pragma unroll
    for (int j = 0; j < 4; ++j) {
        float bv = HB ? bias[c0 + wc + lc + 8 * j] : 0.f;
        #pragma unroll
        for (int i = 0; i < 4; ++i) acc[i][j] = bv;
    }
    for (int kc = 0; kc < KTOT; kc += 64) {
        __syncthreads();
        #pragma unroll
        for (int rep = 0; rep < 4; ++rep) {
            int row = sr + rep * 16;
            *(float4*)&As[row][sk4] = *(const float4*)&A[(size_t)(m0 + row) * KTOT + kc + sk4];
            *(float4*)&Ws[row][sk4] = *(const float4*)&Wt[(size_t)(c0 + row) * KTOT + kc + sk4];
        }
        __syncthreads();
        #pragma unroll 4
        for (int k4 = 0; k4 < 16; ++k4) {
            float4 a[4], w[4];
            #pragma unroll
            for (int i = 0; i < 4; ++i) a[i] = *(float4*)&As[wr + lr + 8 * i][k4 * 4];
            #pragma unroll
            for (int j = 0; j < 4; ++j) w[j] = *(float4*)&Ws[wc + lc + 8 * j][k4 * 4];
            #pragma unroll
            for (int i = 0; i < 4; ++i) {
                #pragma unroll
                for (int j = 0; j < 4; ++j) {
                    acc[i][j] = fmaf(a[i].x, w[j].x, acc[i][j]);
                    acc[i][j] = fmaf(a[i].y, w[j].y, acc[i][j]);
                    acc[i][j] = fmaf(a[i].z, w[j].z, acc[i][j]);
                    acc[i][j] = fmaf(a[i].w, w[j].w, acc[i][j]);
                }
            }
        }
    }
    #pragma unroll
    for (int i = 0; i < 4; ++i) {
        #pragma unroll
        for (int j = 0; j < 4; ++j)
            C[(size_t)(m0 + wr + lr + 8 * i) * ldc + c0 + wc + lc + 8 * j] = acc[i][j];
    }
}

// ---------------------------------------------------------------- scatter
__global__ __launch_bounds__(256) void k_scatter(
    const float* __restrict__ proj, const float* __restrict__ rots,
    const float* __restrict__ trans,
    float* __restrict__ qw, float* __restrict__ kw, float* __restrict__ vw,
    float* __restrict__ sqw, float* __restrict__ qpw, float* __restrict__ kpw,
    float* __restrict__ vpw)
{
    __shared__ float p[4][1344];
    const int n0 = blockIdx.x * 4, t = threadIdx.x;
    for (int idx = t; idx < 1344; idx += 256) {
        #pragma unroll
        for (int r = 0; r < 4; ++r) p[r][idx] = proj[(size_t)(n0 + r) * 1344 + idx];
    }
    __syncthreads();
    for (int idx = t; idx < 3072; idx += 256) {
        int r = idx / 768, c = idx % 768;
        int n = n0 + r;
        float v = p[r][c];
        if (c < 192) qw[(size_t)n * 192 + c] = v;
        else if (c < 384) sqw[(size_t)n * 192 + (c - 192)] = v;
        else {
            int cc = c - 384, h = cc >> 5, sub = cc & 31;
            if (sub < 16) kw[(size_t)n * 192 + h * 16 + sub] = v;
            else          vw[(size_t)n * 192 + h * 16 + (sub - 16)] = v;
        }
    }
    for (int idx = t; idx < 2304; idx += 256) {
        int r = idx / 576, rem = idx % 576;
        int n = n0 + r;
        const float* R = &rots[(size_t)n * 9];
        const float* tr = &trans[(size_t)n * 3];
        if (rem < 144) {
            int pp = rem / 3, d = rem % 3;
            float v = fmaf(R[d*3+0], p[r][768 + pp],
                      fmaf(R[d*3+1], p[r][768 + 48 + pp],
                      fmaf(R[d*3+2], p[r][768 + 96 + pp], tr[d])));
            qpw[(size_t)n * 144 + pp * 3 + d] = v;
        } else {
            int rem2 = rem - 144; int pp = rem2 / 3, d = rem2 % 3;
            float v = fmaf(R[d*3+0], p[r][912 + pp],
                      fmaf(R[d*3+1], p[r][912 + 144 + pp],
                      fmaf(R[d*3+2], p[r][912 + 288 + pp], tr[d])));
            int h = pp / 12, ii = pp % 12;
            if (ii < 4) kpw[(size_t)n * 144 + h * 12 + ii * 3 + d] = v;
            else        vpw[(size_t)n * 288 + h * 24 + (ii - 4) * 3 + d] = v;
        }
    }
}

// ---------------------------------------------------------------- sfeat
__global__ __launch_bounds__(256) void k_sfeat(
    const float* __restrict__ sf, const float* __restrict__ Wse,
    const float* __restrict__ bse, float* __restrict__ sfeat)
{
    __shared__ float wl[16 * 384];
    __shared__ float sfl[8][16];
    const int m0 = blockIdx.x * 8, t = threadIdx.x;
    for (int idx = t; idx < 6144; idx += 256) wl[idx] = Wse[idx];
    if (t < 128) sfl[t >> 4][t & 15] = sf[(size_t)(m0 + (t >> 4)) * 16 + (t & 15)];
    __syncthreads();
    #pragma unroll
    for (int u = 0; u < 12; ++u) {
        int idx = t + u * 256;
        int r = idx / 384, c = idx % 384;
        float a = bse[c];
        #pragma unroll
        for (int kk = 0; kk < 16; ++kk) a = fmaf(sfl[r][kk], wl[kk * 384 + c], a);
        sfeat[(size_t)(m0 + r) * 384 + c] = a;
    }
}

// ---------------------------------------------------------------- zpass v5
__global__ __launch_bounds__(256) void k_zpass(
    const float* __restrict__ z, const float* __restrict__ wz,
    const float* __restrict__ bz, float* __restrict__ bpz)
{
    __shared__ float zt[256][36];
    __shared__ float wt[44][32];
    const int t = threadIdx.x;
    const int jg0 = blockIdx.x * 256;
    const int i = jg0 >> 9;
    const int jloc = jg0 & 511;
    const int jl = t & 63;
    const int cgs = __builtin_amdgcn_readfirstlane(t >> 6);
    float acc[4][11];
    #pragma unroll
    for (int u = 0; u < 11; ++u) {
        float b = bz[cgs * 11 + u];
        acc[0][u] = b; acc[1][u] = b; acc[2][u] = b; acc[3][u] = b;
    }
    for (int kc = 0; kc < 128; kc += 32) {
        __syncthreads();
        for (int idx = t; idx < 352; idx += 256) {
            int c = idx >> 3, k4 = (idx & 7) << 2;
            *(float4*)&wt[c][k4] = *(const float4*)&wz[c * 128 + kc + k4];
        }
        #pragma unroll
        for (int u = 0; u < 8; ++u) {
            int idx = t + u * 256;
            int r = idx >> 3, k4 = (idx & 7) << 2;
            *(float4*)&zt[r][k4] = *(const float4*)&z[((size_t)(jg0 + r)) * 128 + kc + k4];
        }
        __syncthreads();
        const float* wbase = &wt[cgs * 11][0];
        #pragma unroll 2
        for (int k4 = 0; k4 < 32; k4 += 4) {
            float4 z0 = *(float4*)&zt[jl][k4];
            float4 z1 = *(float4*)&zt[jl + 64][k4];
            float4 z2 = *(float4*)&zt[jl + 128][k4];
            float4 z3 = *(float4*)&zt[jl + 192][k4];
            #pragma unroll
            for (int u = 0; u < 11; ++u) {
                float4 wv = *(const float4*)&wbase[u * 32 + k4];
                acc[0][u] = fmaf(z0.x, wv.x, fmaf(z0.y, wv.y,
                            fmaf(z0.z, wv.z, fmaf(z0.w, wv.w, acc[0][u]))));
                acc[1][u] = fmaf(z1.x, wv.x, fmaf(z1.y, wv.y,
                            fmaf(z1.z, wv.z, fmaf(z1.w, wv.w, acc[1][u]))));
                acc[2][u] = fmaf(z2.x, wv.x, fmaf(z2.y, wv.y,
                            fmaf(z2.z, wv.z, fmaf(z2.w, wv.w, acc[2][u]))));
                acc[3][u] = fmaf(z3.x, wv.x, fmaf(z3.y, wv.y,
                            fmaf(z3.z, wv.z, fmaf(z3.w, wv.w, acc[3][u]))));
            }
        }
    }
    #pragma unroll
    for (int u = 0; u < 11; ++u) {
        size_t base = ((size_t)i * 44 + cgs * 11 + u) * 512 + jloc;
        bpz[base + jl]       = acc[0][u];
        bpz[base + 64 + jl]  = acc[1][u];
        bpz[base + 128 + jl] = acc[2][u];
        bpz[base + 192 + jl] = acc[3][u];
    }
}

// ---------------------------------------------------------------- aprep
// A[h][i][32] = [0.1443*q | -2*cpt*qp | r_i | 1 | m_i | 0]
// B[h][j][32] = [k | kp | 1 | c_j | m_j | 0]; r=cpt*Σqp², c=cpt*Σkp².
__global__ __launch_bounds__(256) void k_aprep(
    const float* __restrict__ qw, const float* __restrict__ qpw,
    const float* __restrict__ kw, const float* __restrict__ kpw,
    const float* __restrict__ mask, const float* __restrict__ hwp,
    float* __restrict__ aq, float* __restrict__ ak)
{
    __shared__ float cpt[12], sq2[12], sk2[12];
    const int i = blockIdx.x, t = threadIdx.x;
    if (t < 12) {
        float c = -0.5f * 0.13608276348795434f * softplusf(hwp[t]);
        cpt[t] = c;
        float s = 0.f, s2 = 0.f;
        #pragma unroll
        for (int p = 0; p < 12; ++p) {
            float v = qpw[(size_t)i * 144 + t * 12 + p]; s = fmaf(v, v, s);
            float w = kpw[(size_t)i * 144 + t * 12 + p]; s2 = fmaf(w, w, s2);
        }
        sq2[t] = s; sk2[t] = s2;
    }
    __syncthreads();
    const float mi = mask[i];
    for (int idx = t; idx < 384; idx += 256) {
        int h = idx >> 5, d = idx & 31;
        float va, vb;
        if (d < 16) {
            va = 0.14433756729740643f * qw[(size_t)i * 192 + h * 16 + d];
            vb = kw[(size_t)i * 192 + h * 16 + d];
        } else if (d < 28) {
            float qp = qpw[(size_t)i * 144 + h * 12 + (d - 16)];
            va = -2.f * cpt[h] * qp;
            vb = kpw[(size_t)i * 144 + h * 12 + (d - 16)];
        } else if (d == 28) { va = cpt[h] * sq2[h]; vb = 1.f; }
        else if (d == 29)   { va = 1.f; vb = cpt[h] * sk2[h]; }
        else if (d == 30)   { va = mi; vb = mi; }
        else                { va = 0.f; vb = 0.f; }
        aq[((size_t)h * 512 + i) * 32 + d] = va;
        ak[((size_t)h * 512 + i) * 32 + d] = vb;
    }
}

// ---------------------------------------------------------------- attn_a v2
// RAW logits[h][i][j] = dot30(A_i, B_j) + bpz[i][h][j] + INFV*(mi*mj-1)
// + per-(h,i) stats (max, 1/sum). Block: 16 i x 512 j, grid (32, 12).
__global__ __launch_bounds__(256) void k_attn_a(
    const float* __restrict__ aq, const float* __restrict__ ak,
    const float* __restrict__ bpz, float* __restrict__ abuf,
    float* __restrict__ astm, float* __restrict__ asti)
{
    __shared__ float aqs[16][32];
    __shared__ float bt[32][36];
    const int h = blockIdx.y, i0 = blockIdx.x * 16;
    const int t = threadIdx.x;
    const int ig = t >> 5, tnl = t & 31;
    if (t < 128)
        *(float4*)&aqs[t >> 3][(t & 7) << 2] =
            *(const float4*)&aq[((size_t)h * 512 + i0 + (t >> 3)) * 32 + ((t & 7) << 2)];
    __syncthreads();
    float ar[2][32];
    #pragma unroll
    for (int r = 0; r < 2; ++r)
        #pragma unroll
        for (int d4 = 0; d4 < 32; d4 += 4)
            *(float4*)&ar[r][d4] = *(float4*)&aqs[ig * 2 + r][d4];
    float mx[2] = {-1e30f, -1e30f}, sm[2] = {0.f, 0.f};
    for (int jt = 0; jt < 16; ++jt) {
        __syncthreads();
        {
            int r = t >> 3, d4 = (t & 7) << 2;
            *(float4*)&bt[r][d4] =
                *(const float4*)&ak[((size_t)h * 512 + jt * 32 + r) * 32 + d4];
        }
        __syncthreads();
        const int j = jt * 32 + tnl;
        float br[32];
        #pragma unroll
        for (int d4 = 0; d4 < 32; d4 += 4)
            *(float4*)&br[d4] = *(float4*)&bt[tnl][d4];
        #pragma unroll
        for (int r = 0; r < 2; ++r) {
            const int i = i0 + ig * 2 + r;
            float dot = 0.f;
            #pragma unroll
            for (int d = 0; d < 30; ++d) dot = fmaf(ar[r][d], br[d], dot);
            float lg = dot + bpz[((size_t)i * 44 + h) * 512 + j];
            lg += INFV * (ar[r][30] * br[30] - 1.0f);
            abuf[((size_t)h * 512 + i) * 512 + j] = lg;
            float nm = fmaxf(mx[r], lg);
            sm[r] = sm[r] * __expf(mx[r] - nm) + __expf(lg - nm);
            mx[r] = nm;
        }
    }
    #pragma unroll
    for (int off = 1; off < 32; off <<= 1) {
        #pragma unroll
        for (int r = 0; r < 2; ++r) {
            float m2 = __shfl_xor(mx[r], off), s2 = __shfl_xor(sm[r], off);
            float nm = fmaxf(mx[r], m2);
            sm[r] = sm[r] * __expf(mx[r] - nm) + s2 * __expf(m2 - nm);
            mx[r] = nm;
        }
    }
    if (tnl == 0) {
        #pragma unroll
        for (int r = 0; r < 2; ++r) {
            int i = i0 + ig * 2 + r;
            astm[(size_t)h * 512 + i] = mx[r];
            asti[(size_t)h * 512 + i] = 1.0f / sm[r];
        }
    }
}

// ---------------------------------------------------------------- attn_pair
// o_pair from RAW logits: a = exp(raw - m_h)*inv_h applied during staging.
__global__ __launch_bounds__(256) void k_attn_pair(
    const float* __restrict__ abuf, const float* __restrict__ bpz,
    const float* __restrict__ astm, const float* __restrict__ asti,
    float* __restrict__ ocat)
{
    __shared__ float al[12][512];
    __shared__ float mh[12], ih[12];
    const int i = blockIdx.x, t = threadIdx.x;
    if (t < 12) { mh[t] = astm[(size_t)t * 512 + i]; ih[t] = asti[(size_t)t * 512 + i]; }
    __syncthreads();
    #pragma unroll
    for (int u = 0; u < 12; ++u) {
        float r0 = abuf[(size_t)u * 262144 + (size_t)i * 512 + t];
        float r1 = abuf[(size_t)u * 262144 + (size_t)i * 512 + t + 256];
        al[u][t] = __expf(r0 - mh[u]) * ih[u];
        al[u][t + 256] = __expf(r1 - mh[u]) * ih[u];
    }
    __syncthreads();
    const int c = t & 31;
    const int h1 = t >> 5;
    const bool dual = (t < 128);
    const float* pz = bpz + ((size_t)i * 44 + 12 + c) * 512;
    const float* a1 = al[h1];
    const float* a2 = al[dual ? h1 + 8 : 0];
    float acc1 = 0.f, acc2 = 0.f;
    for (int j = 0; j < 512; j += 4) {
        float4 p = *(const float4*)&pz[j];
        acc1 = fmaf(a1[j+0], p.x, acc1);
        acc1 = fmaf(a1[j+1], p.y, acc1);
        acc1 = fmaf(a1[j+2], p.z, acc1);
        acc1 = fmaf(a1[j+3], p.w, acc1);
        if (dual) {
            acc2 = fmaf(a2[j+0], p.x, acc2);
            acc2 = fmaf(a2[j+1], p.y, acc2);
            acc2 = fmaf(a2[j+2], p.z, acc2);
            acc2 = fmaf(a2[j+3], p.w, acc2);
        }
    }
    ocat[(size_t)i * 1152 + 576 + h1 * 32 + c] = acc1;
    if (dual) ocat[(size_t)i * 1152 + 576 + (h1 + 8) * 32 + c] = acc2;
}

// ---------------------------------------------------------------- gemm_ov
// softmax applied during As staging from RAW logits.
__global__ __launch_bounds__(256) void k_gemm_ov(
    const float* __restrict__ abuf, const float* __restrict__ vw,
    const float* __restrict__ vpw, const float* __restrict__ astm,
    const float* __restrict__ asti, float* __restrict__ cbuf)
{
    __shared__ float As[64][68];
    __shared__ float Bs[64][44];
    __shared__ float ms[64], is_[64];
    const int i0 = blockIdx.x * 64, h = blockIdx.y;
    const int t = threadIdx.x;
    const int sr = t >> 4, sk4 = (t & 15) << 2;
    const int r1 = t >> 3;
    const int cb = t & 7;
    if (t < 64) {
        ms[t] = astm[(size_t)h * 512 + i0 + t];
        is_[t] = asti[(size_t)h * 512 + i0 + t];
    }
    float acc[2][5];
    #pragma unroll
    for (int u = 0; u < 5; ++u) { acc[0][u] = 0.f; acc[1][u] = 0.f; }
    for (int kc = 0; kc < 512; kc += 64) {
        __syncthreads();
        #pragma unroll
        for (int rep = 0; rep < 4; ++rep) {
            int row = sr + rep * 16;
            float4 raw = *(const float4*)&abuf[(size_t)h * 262144 +
                                               (size_t)(i0 + row) * 512 + kc + sk4];
            float m = ms[row], iv = is_[row];
            float4 w;
            w.x = __expf(raw.x - m) * iv;
            w.y = __expf(raw.y - m) * iv;
            w.z = __expf(raw.z - m) * iv;
            w.w = __expf(raw.w - m) * iv;
            *(float4*)&As[row][sk4] = w;
        }
        #pragma unroll
        for (int u = 0; u < 10; ++u) {
            int idx = t + u * 256;
            int r = idx / 40, cc = idx % 40;
            Bs[r][cc] = (cc < 16) ? vw[(size_t)(kc + r) * 192 + h * 16 + cc]
                                  : vpw[(size_t)(kc + r) * 288 + h * 24 + (cc - 16)];
        }
        __syncthreads();
        #pragma unroll 4
        for (int kk = 0; kk < 64; ++kk) {
            float av1 = As[r1][kk], av2 = As[r1 + 32][kk];
            #pragma unroll
            for (int u = 0; u < 5; ++u) {
                float b = Bs[kk][cb + 8 * u];
                acc[0][u] = fmaf(av1, b, acc[0][u]);
                acc[1][u] = fmaf(av2, b, acc[1][u]);
            }
        }
    }
    #pragma unroll
    for (int u = 0; u < 5; ++u) {
        cbuf[((size_t)h * 512 + i0 + r1) * 40 + cb + 8 * u] = acc[0][u];
        cbuf[((size_t)h * 512 + i0 + r1 + 32) * 40 + cb + 8 * u] = acc[1][u];
    }
}

// ---------------------------------------------------------------- optfin
__global__ __launch_bounds__(256) void k_optfin(
    const float* __restrict__ cbuf, const float* __restrict__ rots,
    const float* __restrict__ trans, float* __restrict__ ocat)
{
    __shared__ float cl[4][12][40];
    const int i0 = blockIdx.x * 4, t = threadIdx.x;
    for (int idx = t; idx < 1920; idx += 256) {
        int ii = idx / 480, rem = idx % 480;
        int h = rem / 40, c = rem % 40;
        cl[ii][h][c] = cbuf[((size_t)h * 512 + i0 + ii) * 40 + c];
    }
    __syncthreads();
    for (int idx = t; idx < 768; idx += 256) {
        int ii = idx / 192, o = idx % 192;
        ocat[(size_t)(i0 + ii) * 1152 + o] = cl[ii][o >> 4][o & 15];
    }
    for (int idx = t; idx < 384; idx += 256) {
        int ii = idx / 96, hp = idx % 96;
        int h = hp >> 3, p = hp & 7;
        int i = i0 + ii;
        const float* R = &rots[(size_t)i * 9];
        float gx = cl[ii][h][16 + p*3 + 0] - trans[(size_t)i*3 + 0];
        float gy = cl[ii][h][16 + p*3 + 1] - trans[(size_t)i*3 + 1];
        float gz = cl[ii][h][16 + p*3 + 2] - trans[(size_t)i*3 + 2];
        float lx = R[0]*gx + R[3]*gy + R[6]*gz;
        float ly = R[1]*gx + R[4]*gy + R[7]*gz;
        float lz = R[2]*gx + R[5]*gy + R[8]*gz;
        float nm = sqrtf(lx*lx + ly*ly + lz*lz + 1e-8f);
        int col = h * 8 + p;
        size_t base = (size_t)i * 1152;
        ocat[base + 192 + col] = lx;
        ocat[base + 288 + col] = ly;
        ocat[base + 384 + col] = lz;
        ocat[base + 480 + col] = nm;
    }
}

// ---------------------------------------------------------------- tlog
__global__ __launch_bounds__(256) void k_tlog(
    const float* __restrict__ sqw, const float* __restrict__ skv,
    const float* __restrict__ trans, const float* __restrict__ mask,
    const float* __restrict__ sp, const float* __restrict__ smask,
    const float* __restrict__ sbwp, float* __restrict__ logits,
    float* __restrict__ stat_m, float* __restrict__ stat_il)
{
    __shared__ float sk_s[32][16];
    __shared__ float sq_s[32][16];
    __shared__ float trans_s[96];
    __shared__ float mask_s[32];
    __shared__ float spm_s[96];
    __shared__ float smask_s[32];
    const int h = blockIdx.y;
    const int m0 = blockIdx.x * 32;
    const int t = threadIdx.x;
    const int tmg = t >> 5, tnl = t & 31;
    const float sbw = softplusf(sbwp[0]);
    for (int idx = t; idx < 512; idx += 256) {
        int row = idx >> 4, c = idx & 15;
        sk_s[row][c] = skv[(size_t)(m0 + row) * 384 + h * 16 + c];
    }
    if (t < 96) spm_s[t] = sp[(size_t)m0 * 3 + t];
    if (t < 32) smask_s[t] = smask[m0 + t];
    __syncthreads();
    float skr[4][16];
    float spx[4], spy[4], spz[4], smk[4];
    #pragma unroll
    for (int mi = 0; mi < 4; ++mi) {
        int row = tmg * 4 + mi;
        #pragma unroll
        for (int c4 = 0; c4 < 16; c4 += 4)
            *(float4*)&skr[mi][c4] = *(float4*)&sk_s[row][c4];
        spx[mi] = spm_s[row*3+0]; spy[mi] = spm_s[row*3+1]; spz[mi] = spm_s[row*3+2];
        smk[mi] = smask_s[row];
    }
    float mxr[4], lr[4];
    #pragma unroll
    for (int mi = 0; mi < 4; ++mi) { mxr[mi] = -1e30f; lr[mi] = 0.f; }
    for (int nt = 0; nt < 16; ++nt) {
        __syncthreads();
        const int nb = nt * 32;
        if (t < 128) {
            int nn = t >> 2, c4 = (t & 3) << 2;
            *(float4*)&sq_s[nn][c4] = *(const float4*)&sqw[(size_t)(nb + nn) * 192 + h * 16 + c4];
        }
        if (t < 96) trans_s[t] = trans[(size_t)nb * 3 + t];
        if (t < 32) mask_s[t] = mask[nb + t];
        __syncthreads();
        float q[16];
        #pragma unroll
        for (int c4 = 0; c4 < 16; c4 += 4)
            *(float4*)&q[c4] = *(float4*)&sq_s[tnl][c4];
        const float tx = trans_s[tnl*3+0], ty = trans_s[tnl*3+1], tz = trans_s[tnl*3+2];
        const float mkn = mask_s[tnl];
        #pragma unroll
        for (int mi = 0; mi < 4; ++mi) {
            float dot = 0.f;
            #pragma unroll
            for (int c = 0; c < 16; ++c) dot = fmaf(skr[mi][c], q[c], dot);
            float dx = tx - spx[mi], dy = ty - spy[mi], dz = tz - spz[mi];
            float mterm = INFV * (mkn * smk[mi] - 1.0f) - 0.5f * sbw * (dx*dx + dy*dy + dz*dz);
            float lg = fmaf(0.25f, dot, mterm);
            logits[((size_t)(m0 + tmg * 4 + mi) * 12 + h) * 512 + nb + tnl] = lg;
            float newm = fmaxf(mxr[mi], lg);
            lr[mi] = lr[mi] * __expf(mxr[mi] - newm) + __expf(lg - newm);
            mxr[mi] = newm;
        }
    }
    #pragma unroll
    for (int off = 1; off < 32; off <<= 1) {
        #pragma unroll
        for (int mi = 0; mi < 4; ++mi) {
            float m2 = __shfl_xor(mxr[mi], off), l2 = __shfl_xor(lr[mi], off);
            float newm = fmaxf(mxr[mi], m2);
            lr[mi] = lr[mi] * __expf(mxr[mi] - newm) + l2 * __expf(m2 - newm);
            mxr[mi] = newm;
        }
    }
    if (tnl == 0) {
        #pragma unroll
        for (int mi = 0; mi < 4; ++mi) {
            int m = m0 + tmg * 4 + mi;
            stat_m[(size_t)m * 12 + h] = mxr[mi];
            stat_il[(size_t)m * 12 + h] = 1.0f / lr[mi];
        }
    }
}

// ---------------------------------------------------------------- rstat
__global__ __launch_bounds__(256) void k_rstat(
    const float* __restrict__ lbuf, float* __restrict__ rspm,
    float* __restrict__ rsps)
{
    __shared__ float smx[4][64], ssm[4][64];
    const int n0 = blockIdx.x * 64, mc = blockIdx.y, h = blockIdx.z;
    const int t = threadIdx.x, ln = t & 63, mg = t >> 6;
    const int mb = mc * 512;
    const int n = n0 + ln;
    float mx = -1e30f, sm = 0.f;
    #pragma unroll 2
    for (int it = 0; it < 128; ++it) {
        int m = mb + it * 4 + mg;
        float lg = lbuf[((size_t)m * 12 + h) * 512 + n];
        float nm = fmaxf(mx, lg);
        sm = sm * __expf(mx - nm) + __expf(lg - nm);
        mx = nm;
    }
    smx[mg][ln] = mx; ssm[mg][ln] = sm;
    __syncthreads();
    if (t < 64) {
        float M = smx[0][t], S = ssm[0][t];
        #pragma unroll
        for (int g = 1; g < 4; ++g) {
            float m2 = smx[g][t], s2 = ssm[g][t];
            float nm = fmaxf(M, m2);
            S = S * __expf(M - nm) + s2 * __expf(m2 - nm);
            M = nm;
        }
        rspm[((size_t)h * 4 + mc) * 512 + n0 + t] = M;
        rsps[((size_t)h * 4 + mc) * 512 + n0 + t] = S;
    }
}

// ---------------------------------------------------------------- rcomb
__global__ __launch_bounds__(256) void k_rcomb(
    const float* __restrict__ rspm, const float* __restrict__ rsps,
    float* __restrict__ rmax, float* __restrict__ rinv)
{
    int gid = blockIdx.x * 256 + threadIdx.x;
    if (gid >= 6144) return;
    int h = gid >> 9, n = gid & 511;
    float M = -1e30f, S = 0.f;
    #pragma unroll
    for (int mc = 0; mc < 4; ++mc) {
        float m2 = rspm[((size_t)h * 4 + mc) * 512 + n];
        float s2 = rsps[((size_t)h * 4 + mc) * 512 + n];
        float nm = fmaxf(M, m2);
        S = S * __expf(M - nm) + s2 * __expf(m2 - nm);
        M = nm;
    }
    rmax[gid] = M;
    rinv[gid] = 1.0f / S;
}

// ---------------------------------------------------------------- pv
__global__ __launch_bounds__(256) void k_pv(
    const float* __restrict__ lbuf, const float* __restrict__ skv,
    const float* __restrict__ rmax, const float* __restrict__ rinv,
    float* __restrict__ pvp)
{
    __shared__ float sv_s[512][17];
    const int n0 = blockIdx.x * 64, mc = blockIdx.y, h = blockIdx.z;
    const int t = threadIdx.x, ln = t & 63, mg = t >> 6;
    const int mb = mc * 512;
    for (int idx = t; idx < 2048; idx += 256) {
        int ml = idx >> 2, c4 = (idx & 3) << 2;
        float4 v4 = *(const float4*)&skv[(size_t)(mb + ml) * 384 + 192 + h * 16 + c4];
        sv_s[ml][c4+0]=v4.x; sv_s[ml][c4+1]=v4.y; sv_s[ml][c4+2]=v4.z; sv_s[ml][c4+3]=v4.w;
    }
    const int n = n0 + ln;
    const float rm = rmax[h * 512 + n], ri = rinv[h * 512 + n];
    float acc[16];
    #pragma unroll
    for (int c = 0; c < 16; ++c) acc[c] = 0.f;
    __syncthreads();
    #pragma unroll 2
    for (int it = 0; it < 128; ++it) {
        int ml = it * 4 + mg;
        float w = __expf(lbuf[((size_t)(mb + ml) * 12 + h) * 512 + n] - rm) * ri;
        #pragma unroll
        for (int c = 0; c < 16; ++c) acc[c] = fmaf(w, sv_s[ml][c], acc[c]);
    }
    __syncthreads();
    float* red = &sv_s[0][0];
    #pragma unroll
    for (int c = 0; c < 16; ++c) red[(mg * 64 + ln) * 17 + c] = acc[c];
    __syncthreads();
    {
        int nl = t >> 2, c4 = (t & 3) << 2;
        float4 o;
        #pragma unroll
        for (int e = 0; e < 4; ++e) {
            float s = 0.f;
            #pragma unroll
            for (int g = 0; g < 4; ++g) s += red[(g * 64 + nl) * 17 + c4 + e];
            (&o.x)[e] = s;
        }
        *(float4*)&pvp[(((size_t)h * 4 + mc) * 512 + n0 + nl) * 16 + c4] = o;
    }
}

// ---------------------------------------------------------------- pvcomb
__global__ __launch_bounds__(256) void k_pvcomb(
    const float* __restrict__ pvp, float* __restrict__ ocat)
{
    int gid = blockIdx.x * 256 + threadIdx.x;
    int n = gid / 192, rem = gid % 192;
    float o = 0.f;
    #pragma unroll
    for (int mc = 0; mc < 4; ++mc)
        o += pvp[(((size_t)(rem >> 4) * 4 + mc) * 512 + n) * 16 + (rem & 15)];
    ocat[(size_t)n * 1152 + 960 + rem] = o;
}

// ---------------------------------------------------------------- tw
__global__ __launch_bounds__(256) void k_tw(
    const float* __restrict__ logits, const float* __restrict__ stat_m,
    const float* __restrict__ stat_il, float* __restrict__ w)
{
    __shared__ float mxs[12], ils[12];
    const int m = blockIdx.x, t = threadIdx.x;
    if (t < 12) { mxs[t] = stat_m[(size_t)m * 12 + t]; ils[t] = stat_il[(size_t)m * 12 + t]; }
    __syncthreads();
    const float* lp = logits + (size_t)m * 12 * 512;
    float a0 = 0.f, a1 = 0.f;
    #pragma unroll
    for (int h = 0; h < 12; ++h) {
        a0 += __expf(lp[h * 512 + t] - mxs[h]) * ils[h];
        a1 += __expf(lp[h * 512 + 256 + t] - mxs[h]) * ils[h];
    }
    w[(size_t)m * 512 + t] = a0 * (1.0f / 12.0f);
    w[(size_t)m * 512 + 256 + t] = a1 * (1.0f / 12.0f);
}

// ---------------------------------------------------------------- surf out
__global__ __launch_bounds__(256) void k_surf_out(
    const float* __restrict__ sfeat, const float* __restrict__ saggw,
    const float* __restrict__ Wso, const float* __restrict__ bso,
    float* __restrict__ out)
{
    __shared__ float wl[12304];
    const int t = threadIdx.x;
    for (int idx = t; idx < 12288; idx += 256) {
        int k = idx >> 4, c = idx & 15;
        wl[(k / 192) * 3076 + (k % 192) * 16 + c] = Wso[idx];
    }
    const int m = blockIdx.x * 64 + (t >> 2);
    const int kq = t & 3;
    const float* src = (kq < 2) ? &sfeat[(size_t)m * 384 + kq * 192]
                                : &saggw[(size_t)m * 384 + (kq - 2) * 192];
    __syncthreads();
    float acc[16];
    #pragma unroll
    for (int c = 0; c < 16; ++c) acc[c] = 0.f;
    const float* wb = &wl[kq * 3076];
    for (int k = 0; k < 192; k += 4) {
        float4 v = *(const float4*)&src[k];
        #pragma unroll
        for (int e = 0; e < 4; ++e) {
            float sv = (&v.x)[e];
            #pragma unroll
            for (int c = 0; c < 16; ++c)
                acc[c] = fmaf(sv, wb[(k + e) * 16 + c], acc[c]);
        }
    }
    #pragma unroll
    for (int c = 0; c < 16; ++c) {
        acc[c] += __shfl_xor(acc[c], 1);
        acc[c] += __shfl_xor(acc[c], 2);
    }
    #pragma unroll
    for (int c = 0; c < 16; ++c) {
        if ((c >> 2) == kq) out[196608 + (size_t)m * 16 + c] = acc[c] + bso[c];
    }
}

// ----------------------------------------------------------------
extern "C" void kernel_launch(void* const* d_in, const int* in_sizes, int n_in,
                              void* d_out, int out_size, void* d_ws, size_t ws_size,
                              hipStream_t stream)
{
    (void)in_sizes; (void)n_in; (void)out_size; (void)ws_size;
    const float* s     = (const float*)d_in[0];
    const float* z     = (const float*)d_in[1];
    const float* rots  = (const float*)d_in[2];
    const float* trans = (const float*)d_in[3];
    const float* mask  = (const float*)d_in[4];
    const float* sp    = (const float*)d_in[5];
    const float* sf    = (const float*)d_in[6];
    const float* smask = (const float*)d_in[7];
    const float* Wq    = (const float*)d_in[8];  const float* bq   = (const float*)d_in[9];
    const float* Wkv   = (const float*)d_in[10]; const float* bkv  = (const float*)d_in[11];
    const float* Wqp   = (const float*)d_in[12]; const float* bqp  = (const float*)d_in[13];
    const float* Wkvp  = (const float*)d_in[14]; const float* bkvp = (const float*)d_in[15];
    const float* Wse   = (const float*)d_in[16]; const float* bse  = (const float*)d_in[17];
    const float* Wsq   = (const float*)d_in[18]; const float* bsq  = (const float*)d_in[19];
    const float* Wsk   = (const float*)d_in[20]; const float* bsk  = (const float*)d_in[21];
    const float* Wsv   = (const float*)d_in[22]; const float* bsv  = (const float*)d_in[23];
    const float* Wb    = (const float*)d_in[24]; const float* bb   = (const float*)d_in[25];
    const float* Wdz   = (const float*)d_in[26]; const float* bdz  = (const float*)d_in[27];
    const float* hw    = (const float*)d_in[28]; const float* sbw  = (const float*)d_in[29];
    const float* Wout  = (const float*)d_in[30]; const float* bout = (const float*)d_in[31];
    const float* Wso   = (const float*)d_in[32]; const float* bso  = (const float*)d_in[33];
    float* out = (float*)d_out;

    float* qw    = (float*)d_ws;
    float* kw    = qw    + (size_t)512 * 192;
    float* vw    = kw    + (size_t)512 * 192;
    float* sqw   = vw    + (size_t)512 * 192;
    float* qpw   = sqw   + (size_t)512 * 192;
    float* kpw   = qpw   + (size_t)512 * 144;
    float* vpw   = kpw   + (size_t)512 * 144;
    float* sfeat = vpw   + (size_t)512 * 288;
    float* skv   = sfeat + (size_t)2048 * 384;
    float* ocat  = skv   + (size_t)2048 * 384;
    float* sagg  = ocat  + (size_t)512 * 1152;
    // region: proj (688K fl) -> bpz (11.5M fl) -> logits (12.6M fl), stream-serialized
    float* region = sagg + (size_t)2048 * 384;
    float* proj   = region;
    float* bpz    = region;
    float* logits = region;
    float* wt1   = region + (size_t)2048 * 12 * 512;
    float* wt2   = wt1   + (size_t)1344 * 384;
    float* wt3   = wt2   + (size_t)384 * 384;
    float* b1    = wt3   + (size_t)384 * 1152;
    float* b2    = b1    + 1344;
    float* st    = b2    + 384;
    float* wbuf  = st    + (size_t)384 * 512;
    float* statm = wbuf  + (size_t)2048 * 512;
    float* stati = statm + (size_t)2048 * 12;
    float* abuf  = stati + (size_t)2048 * 12;      // a[12][512][512] (raw logits)
    float* cbuf  = abuf  + (size_t)12 * 512 * 512; // c[12][512][40]
    float* wz    = cbuf  + (size_t)12 * 512 * 40;  // Wz[44][128]
    float* bz    = wz    + (size_t)44 * 128;       // bz[44]
    float* rspm  = bz    + 64;                     // [12][4][512]
    float* rsps  = rspm  + (size_t)12 * 4 * 512;
    float* rmax  = rsps  + (size_t)12 * 4 * 512;   // [12][512]
    float* rinv  = rmax  + (size_t)12 * 512;
    float* pvp   = rinv  + (size_t)12 * 512;       // [12][4][512][16]
    float* aq    = pvp   + (size_t)12 * 4 * 512 * 16; // [12][512][32]
    float* ak    = aq    + (size_t)12 * 512 * 32;
    float* astm  = ak    + (size_t)12 * 512 * 32;  // [12][512]
    float* asti  = astm  + (size_t)12 * 512;

    k_pack<<<dim3(1099), dim3(256), 0, stream>>>(Wq, Wsq, Wkv, Wqp, Wkvp, Wsk, Wsv, Wout,
        bq, bsq, bkv, bqp, bkvp, bsk, bsv, wt1, wt2, wt3, b1, b2);
    k_packz<<<dim3(23), dim3(256), 0, stream>>>(Wb, bb, Wdz, bdz, wz, bz);
    k_transp<<<dim3(12, 16), dim3(256), 0, stream>>>(s, st);
    k_gemm<384, true><<<dim3(21, 8), dim3(256), 0, stream>>>(s, wt1, b1, proj, 1344);
    k_scatter<<<dim3(128), dim3(256), 0, stream>>>(proj, rots, trans,
        qw, kw, vw, sqw, qpw, kpw, vpw);
    k_aprep<<<dim3(512), dim3(256), 0, stream>>>(qw, qpw, kw, kpw, mask, hw, aq, ak);
    k_sfeat<<<dim3(256), dim3(256), 0, stream>>>(sf, Wse, bse, sfeat);
    k_gemm<384, true><<<dim3(6, 32), dim3(256), 0, stream>>>(sfeat, wt2, b2, skv, 384);
    k_zpass<<<dim3(1024), dim3(256), 0, stream>>>(z, wz, bz, bpz);
    k_attn_a<<<dim3(32, 12), dim3(256), 0, stream>>>(aq, ak, bpz, abuf, astm, asti);
    k_attn_pair<<<dim3(512), dim3(256), 0, stream>>>(abuf, bpz, astm, asti, ocat);
    k_gemm_ov<<<dim3(8, 12), dim3(256), 0, stream>>>(abuf, vw, vpw, astm, asti, cbuf);
    k_optfin<<<dim3(128), dim3(256), 0, stream>>>(cbuf, rots, trans, ocat);
    k_tlog<<<dim3(64, 12), dim3(256), 0, stream>>>(sqw, skv, trans, mask, sp, smask,
        sbw, logits, statm, stati);
    k_rstat<<<dim3(8, 4, 12), dim3(256), 0, stream>>>(logits, rspm, rsps);
    k_rcomb<<<dim3(24), dim3(256), 0, stream>>>(rspm, rsps, rmax, rinv);
    k_pv<<<dim3(8, 4, 12), dim3(256), 0, stream>>>(logits, skv, rmax, rinv, pvp);
    k_pvcomb<<<dim3(384), dim3(256), 0, stream>>>(pvp, ocat);
    k_tw<<<dim3(2048), dim3(256), 0, stream>>>(logits, statm, stati, wbuf);
    k_gemm<512, false><<<dim3(6, 32), dim3(256), 0, stream>>>(wbuf, st, nullptr, sagg, 384);
    k_surf_out<<<dim3(32), dim3(256), 0, stream>>>(sfeat, sagg, Wso, bso, out);
    k_gemm<1152, true><<<dim3(6, 8), dim3(256), 0, stream>>>(ocat, wt3, bout, out, 384);
}

// Round 14
// 467.337 us; speedup vs baseline: 1.1756x; 1.0013x over previous
//
#include <hip/hip_runtime.h>
#include <cstddef>

// IPA + surface cross-attention, B=1, N=512, M=2048, H=12, C_H=16, C_S=384.
// Round 12: GEMM-ify IPA logits. k_aprep packs 32-dim rows (|qp-kp|^2
// expanded into r_i + c_j - 2qp·kp); k_attn_a v2 = register/LDS-tiled dot
// writing RAW logits + row stats; softmax applied during consumer staging
// (k_attn_pair, k_gemm_ov). k_zpass v5 and rest unchanged from R11.

#define CS 384
#define INFV 100000.0f

__device__ __forceinline__ float softplusf(float x) { return log1pf(__expf(x)); }

// ---------------------------------------------------------------- pack
__global__ __launch_bounds__(256) void k_pack(
    const float* __restrict__ Wq, const float* __restrict__ Wsq,
    const float* __restrict__ Wkv, const float* __restrict__ Wqp,
    const float* __restrict__ Wkvp, const float* __restrict__ Wsk,
    const float* __restrict__ Wsv, const float* __restrict__ Wout,
    const float* __restrict__ bq, const float* __restrict__ bsq,
    const float* __restrict__ bkv, const float* __restrict__ bqp,
    const float* __restrict__ bkvp, const float* __restrict__ bsk,
    const float* __restrict__ bsv,
    float* __restrict__ wt1, float* __restrict__ wt2, float* __restrict__ wt3,
    float* __restrict__ b1, float* __restrict__ b2)
{
    const int b = blockIdx.x, t = threadIdx.x;
    if (b >= 1092) {
        int idx = (b - 1092) * 256 + t;
        if (idx < 1344) {
            float v;
            if (idx < 192) v = bq[idx];
            else if (idx < 384) v = bsq[idx - 192];
            else if (idx < 768) v = bkv[idx - 384];
            else if (idx < 912) v = bqp[idx - 768];
            else v = bkvp[idx - 912];
            b1[idx] = v;
        } else if (idx < 1728) {
            int i2 = idx - 1344;
            b2[i2] = (i2 < 192) ? bsk[i2] : bsv[i2 - 192];
        }
        return;
    }
    const float* src; float* dst; int C, coff, tile, ldd;
    if (b < 72)       { src = Wq;   C = 192; dst = wt1; coff = 0;   ldd = 384;  tile = b; }
    else if (b < 144) { src = Wsq;  C = 192; dst = wt1; coff = 192; ldd = 384;  tile = b - 72; }
    else if (b < 288) { src = Wkv;  C = 384; dst = wt1; coff = 384; ldd = 384;  tile = b - 144; }
    else if (b < 348) { src = Wqp;  C = 144; dst = wt1; coff = 768; ldd = 384;  tile = b - 288; }
    else if (b < 516) { src = Wkvp; C = 432; dst = wt1; coff = 912; ldd = 384;  tile = b - 348; }
    else if (b < 588) { src = Wsk;  C = 192; dst = wt2; coff = 0;   ldd = 384;  tile = b - 516; }
    else if (b < 660) { src = Wsv;  C = 192; dst = wt2; coff = 192; ldd = 384;  tile = b - 588; }
    else              { src = Wout; C = 384; dst = wt3; coff = 0;   ldd = 1152; tile = b - 660; }
    const int cT = (C + 31) >> 5;
    const int tk = tile / cT, tc = tile % cT;
    __shared__ float l[32][33];
    const int tr = t >> 5, tcc = t & 31;
    #pragma unroll
    for (int rr = 0; rr < 4; ++rr) {
        int kloc = tr * 4 + rr;
        int cg = tc * 32 + tcc;
        l[kloc][tcc] = (cg < C) ? src[(size_t)(tk * 32 + kloc) * C + cg] : 0.f;
    }
    __syncthreads();
    #pragma unroll
    for (int rr = 0; rr < 4; ++rr) {
        int cloc = tr * 4 + rr;
        int cg = tc * 32 + cloc;
        if (cg < C) dst[(size_t)(coff + cg) * ldd + tk * 32 + tcc] = l[tcc][cloc];
    }
}

// ---------------------------------------------------------------- packz
__global__ __launch_bounds__(256) void k_packz(
    const float* __restrict__ Wb, const float* __restrict__ bb,
    const float* __restrict__ Wdz, const float* __restrict__ bdz,
    float* __restrict__ wz, float* __restrict__ bz)
{
    const float s3 = 0.5773502691896258f;
    int idx = blockIdx.x * 256 + threadIdx.x;
    if (idx < 5632) {
        int c = idx >> 7, kk = idx & 127;
        wz[idx] = (c < 12) ? s3 * Wb[kk * 12 + c] : Wdz[kk * 32 + (c - 12)];
    } else if (idx < 5676) {
        int c = idx - 5632;
        bz[c] = (c < 12) ? s3 * bb[c] : bdz[c - 12];
    }
}

// ---------------------------------------------------------------- transpose
__global__ __launch_bounds__(256) void k_transp(
    const float* __restrict__ A, float* __restrict__ At)
{
    __shared__ float tile[32][33];
    const int r0 = blockIdx.y * 32, c0 = blockIdx.x * 32;
    const int tr = threadIdx.x >> 5, tc = threadIdx.x & 31;
    #pragma unroll
    for (int rr = 0; rr < 4; ++rr)
        tile[tr + rr * 8][tc] = A[(size_t)(r0 + tr + rr * 8) * 384 + c0 + tc];
    __syncthreads();
    #pragma unroll
    for (int rr = 0; rr < 4; ++rr)
        At[(size_t)(c0 + tr + rr * 8) * 512 + r0 + tc] = tile[tc][tr + rr * 8];
}

// ---------------------------------------------------------------- gemm
template<int KTOT, bool HB>
__global__ __launch_bounds__(256) void k_gemm(
    const float* __restrict__ A, const float* __restrict__ Wt,
    const float* __restrict__ bias, float* __restrict__ C, int ldc)
{
    __shared__ float As[64][68];
    __shared__ float Ws[64][68];
    const int t = threadIdx.x;
    const int c0 = blockIdx.x * 64, m0 = blockIdx.y * 64;
    const int sr = t >> 4, sk4 = (t & 15) << 2;
    const int wid = t >> 6, lane = t & 63;
    const int wr = (wid >> 1) * 32, wc = (wid & 1) * 32;
    const int lr = lane >> 3, lc = lane & 7;
    float acc[4][4];
    #pragma unroll
    for (int j = 0; j < 4; ++j) {
        float bv = HB ? bias[c0 + wc + lc + 8 * j] : 0.f;
        #pragma unroll
        for (int i = 0; i < 4; ++i) acc[i][j] = bv;
    }
    for (int kc = 0; kc < KTOT; kc += 64) {
        __syncthreads();
        #pragma unroll
        for (int rep = 0; rep < 4; ++rep) {
            int row = sr + rep * 16;
            *(float4*)&As[row][sk4] = *(const float4*)&A[(size_t)(m0 + row) * KTOT + kc + sk4];
            *(float4*)&Ws[row][sk4] = *(const float4*)&Wt[(size_t)(c0 + row) * KTOT + kc + sk4];
        }
        __syncthreads();
        #pragma unroll 4
        for (int k4 = 0; k4 < 16; ++k4) {
            float4 a[4], w[4];
            #pragma unroll
            for (int i = 0; i < 4; ++i) a[i] = *(float4*)&As[wr + lr + 8 * i][k4 * 4];
            #pragma unroll
            for (int j = 0; j < 4; ++j) w[j] = *(float4*)&Ws[wc + lc + 8 * j][k4 * 4];
            #pragma unroll
            for (int i = 0; i < 4; ++i) {
                #pragma unroll
                for (int j = 0; j < 4; ++j) {
                    acc[i][j] = fmaf(a[i].x, w[j].x, acc[i][j]);
                    acc[i][j] = fmaf(a[i].y, w[j].y, acc[i][j]);
                    acc[i][j] = fmaf(a[i].z, w[j].z, acc[i][j]);
                    acc[i][j] = fmaf(a[i].w, w[j].w, acc[i][j]);
                }
            }
        }
    }
    #pragma unroll
    for (int i = 0; i < 4; ++i) {
        #pragma unroll
        for (int j = 0; j < 4; ++j)
            C[(size_t)(m0 + wr + lr + 8 * i) * ldc + c0 + wc + lc + 8 * j] = acc[i][j];
    }
}

// ---------------------------------------------------------------- scatter
__global__ __launch_bounds__(256) void k_scatter(
    const float* __restrict__ proj, const float* __restrict__ rots,
    const float* __restrict__ trans,
    float* __restrict__ qw, float* __restrict__ kw, float* __restrict__ vw,
    float* __restrict__ sqw, float* __restrict__ qpw, float* __restrict__ kpw,
    float* __restrict__ vpw)
{
    __shared__ float p[4][1344];
    const int n0 = blockIdx.x * 4, t = threadIdx.x;
    for (int idx = t; idx < 1344; idx += 256) {
        #pragma unroll
        for (int r = 0; r < 4; ++r) p[r][idx] = proj[(size_t)(n0 + r) * 1344 + idx];
    }
    __syncthreads();
    for (int idx = t; idx < 3072; idx += 256) {
        int r = idx / 768, c = idx % 768;
        int n = n0 + r;
        float v = p[r][c];
        if (c < 192) qw[(size_t)n * 192 + c] = v;
        else if (c < 384) sqw[(size_t)n * 192 + (c - 192)] = v;
        else {
            int cc = c - 384, h = cc >> 5, sub = cc & 31;
            if (sub < 16) kw[(size_t)n * 192 + h * 16 + sub] = v;
            else          vw[(size_t)n * 192 + h * 16 + (sub - 16)] = v;
        }
    }
    for (int idx = t; idx < 2304; idx += 256) {
        int r = idx / 576, rem = idx % 576;
        int n = n0 + r;
        const float* R = &rots[(size_t)n * 9];
        const float* tr = &trans[(size_t)n * 3];
        if (rem < 144) {
            int pp = rem / 3, d = rem % 3;
            float v = fmaf(R[d*3+0], p[r][768 + pp],
                      fmaf(R[d*3+1], p[r][768 + 48 + pp],
                      fmaf(R[d*3+2], p[r][768 + 96 + pp], tr[d])));
            qpw[(size_t)n * 144 + pp * 3 + d] = v;
        } else {
            int rem2 = rem - 144; int pp = rem2 / 3, d = rem2 % 3;
            float v = fmaf(R[d*3+0], p[r][912 + pp],
                      fmaf(R[d*3+1], p[r][912 + 144 + pp],
                      fmaf(R[d*3+2], p[r][912 + 288 + pp], tr[d])));
            int h = pp / 12, ii = pp % 12;
            if (ii < 4) kpw[(size_t)n * 144 + h * 12 + ii * 3 + d] = v;
            else        vpw[(size_t)n * 288 + h * 24 + (ii - 4) * 3 + d] = v;
        }
    }
}

// ---------------------------------------------------------------- sfeat
__global__ __launch_bounds__(256) void k_sfeat(
    const float* __restrict__ sf, const float* __restrict__ Wse,
    const float* __restrict__ bse, float* __restrict__ sfeat)
{
    __shared__ float wl[16 * 384];
    __shared__ float sfl[8][16];
    const int m0 = blockIdx.x * 8, t = threadIdx.x;
    for (int idx = t; idx < 6144; idx += 256) wl[idx] = Wse[idx];
    if (t < 128) sfl[t >> 4][t & 15] = sf[(size_t)(m0 + (t >> 4)) * 16 + (t & 15)];
    __syncthreads();
    #pragma unroll
    for (int u = 0; u < 12; ++u) {
        int idx = t + u * 256;
        int r = idx / 384, c = idx % 384;
        float a = bse[c];
        #pragma unroll
        for (int kk = 0; kk < 16; ++kk) a = fmaf(sfl[r][kk], wl[kk * 384 + c], a);
        sfeat[(size_t)(m0 + r) * 384 + c] = a;
    }
}

// ---------------------------------------------------------------- zpass v5
__global__ __launch_bounds__(256) void k_zpass(
    const float* __restrict__ z, const float* __restrict__ wz,
    const float* __restrict__ bz, float* __restrict__ bpz)
{
    __shared__ float zt[256][36];
    __shared__ float wt[44][32];
    const int t = threadIdx.x;
    const int jg0 = blockIdx.x * 256;
    const int i = jg0 >> 9;
    const int jloc = jg0 & 511;
    const int jl = t & 63;
    const int cgs = __builtin_amdgcn_readfirstlane(t >> 6);
    float acc[4][11];
    #pragma unroll
    for (int u = 0; u < 11; ++u) {
        float b = bz[cgs * 11 + u];
        acc[0][u] = b; acc[1][u] = b; acc[2][u] = b; acc[3][u] = b;
    }
    for (int kc = 0; kc < 128; kc += 32) {
        __syncthreads();
        for (int idx = t; idx < 352; idx += 256) {
            int c = idx >> 3, k4 = (idx & 7) << 2;
            *(float4*)&wt[c][k4] = *(const float4*)&wz[c * 128 + kc + k4];
        }
        #pragma unroll
        for (int u = 0; u < 8; ++u) {
            int idx = t + u * 256;
            int r = idx >> 3, k4 = (idx & 7) << 2;
            *(float4*)&zt[r][k4] = *(const float4*)&z[((size_t)(jg0 + r)) * 128 + kc + k4];
        }
        __syncthreads();
        const float* wbase = &wt[cgs * 11][0];
        #pragma unroll 2
        for (int k4 = 0; k4 < 32; k4 += 4) {
            float4 z0 = *(float4*)&zt[jl][k4];
            float4 z1 = *(float4*)&zt[jl + 64][k4];
            float4 z2 = *(float4*)&zt[jl + 128][k4];
            float4 z3 = *(float4*)&zt[jl + 192][k4];
            #pragma unroll
            for (int u = 0; u < 11; ++u) {
                float4 wv = *(const float4*)&wbase[u * 32 + k4];
                acc[0][u] = fmaf(z0.x, wv.x, fmaf(z0.y, wv.y,
                            fmaf(z0.z, wv.z, fmaf(z0.w, wv.w, acc[0][u]))));
                acc[1][u] = fmaf(z1.x, wv.x, fmaf(z1.y, wv.y,
                            fmaf(z1.z, wv.z, fmaf(z1.w, wv.w, acc[1][u]))));
                acc[2][u] = fmaf(z2.x, wv.x, fmaf(z2.y, wv.y,
                            fmaf(z2.z, wv.z, fmaf(z2.w, wv.w, acc[2][u]))));
                acc[3][u] = fmaf(z3.x, wv.x, fmaf(z3.y, wv.y,
                            fmaf(z3.z, wv.z, fmaf(z3.w, wv.w, acc[3][u]))));
            }
        }
    }
    #pragma unroll
    for (int u = 0; u < 11; ++u) {
        size_t base = ((size_t)i * 44 + cgs * 11 + u) * 512 + jloc;
        bpz[base + jl]       = acc[0][u];
        bpz[base + 64 + jl]  = acc[1][u];
        bpz[base + 128 + jl] = acc[2][u];
        bpz[base + 192 + jl] = acc[3][u];
    }
}

// ---------------------------------------------------------------- aprep
// A[h][i][32] = [0.1443*q | -2*cpt*qp | r_i | 1 | m_i | 0]
// B[h][j][32] = [k | kp | 1 | c_j | m_j | 0]; r=cpt*Σqp², c=cpt*Σkp².
__global__ __launch_bounds__(256) void k_aprep(
    const float* __restrict__ qw, const float* __restrict__ qpw,
    const float* __restrict__ kw, const float* __restrict__ kpw,
    const float* __restrict__ mask, const float* __restrict__ hwp,
    float* __restrict__ aq, float* __restrict__ ak)
{
    __shared__ float cpt[12], sq2[12], sk2[12];
    const int i = blockIdx.x, t = threadIdx.x;
    if (t < 12) {
        float c = -0.5f * 0.13608276348795434f * softplusf(hwp[t]);
        cpt[t] = c;
        float s = 0.f, s2 = 0.f;
        #pragma unroll
        for (int p = 0; p < 12; ++p) {
            float v = qpw[(size_t)i * 144 + t * 12 + p]; s = fmaf(v, v, s);
            float w = kpw[(size_t)i * 144 + t * 12 + p]; s2 = fmaf(w, w, s2);
        }
        sq2[t] = s; sk2[t] = s2;
    }
    __syncthreads();
    const float mi = mask[i];
    for (int idx = t; idx < 384; idx += 256) {
        int h = idx >> 5, d = idx & 31;
        float va, vb;
        if (d < 16) {
            va = 0.14433756729740643f * qw[(size_t)i * 192 + h * 16 + d];
            vb = kw[(size_t)i * 192 + h * 16 + d];
        } else if (d < 28) {
            float qp = qpw[(size_t)i * 144 + h * 12 + (d - 16)];
            va = -2.f * cpt[h] * qp;
            vb = kpw[(size_t)i * 144 + h * 12 + (d - 16)];
        } else if (d == 28) { va = cpt[h] * sq2[h]; vb = 1.f; }
        else if (d == 29)   { va = 1.f; vb = cpt[h] * sk2[h]; }
        else if (d == 30)   { va = mi; vb = mi; }
        else                { va = 0.f; vb = 0.f; }
        aq[((size_t)h * 512 + i) * 32 + d] = va;
        ak[((size_t)h * 512 + i) * 32 + d] = vb;
    }
}

// ---------------------------------------------------------------- attn_a v2
// RAW logits[h][i][j] = dot30(A_i, B_j) + bpz[i][h][j] + INFV*(mi*mj-1)
// + per-(h,i) stats (max, 1/sum). Block: 16 i x 512 j, grid (32, 12).
__global__ __launch_bounds__(256) void k_attn_a(
    const float* __restrict__ aq, const float* __restrict__ ak,
    const float* __restrict__ bpz, float* __restrict__ abuf,
    float* __restrict__ astm, float* __restrict__ asti)
{
    __shared__ float aqs[16][32];
    __shared__ float bt[32][36];
    const int h = blockIdx.y, i0 = blockIdx.x * 16;
    const int t = threadIdx.x;
    const int ig = t >> 5, tnl = t & 31;
    if (t < 128)
        *(float4*)&aqs[t >> 3][(t & 7) << 2] =
            *(const float4*)&aq[((size_t)h * 512 + i0 + (t >> 3)) * 32 + ((t & 7) << 2)];
    __syncthreads();
    float ar[2][32];
    #pragma unroll
    for (int r = 0; r < 2; ++r)
        #pragma unroll
        for (int d4 = 0; d4 < 32; d4 += 4)
            *(float4*)&ar[r][d4] = *(float4*)&aqs[ig * 2 + r][d4];
    float mx[2] = {-1e30f, -1e30f}, sm[2] = {0.f, 0.f};
    for (int jt = 0; jt < 16; ++jt) {
        __syncthreads();
        {
            int r = t >> 3, d4 = (t & 7) << 2;
            *(float4*)&bt[r][d4] =
                *(const float4*)&ak[((size_t)h * 512 + jt * 32 + r) * 32 + d4];
        }
        __syncthreads();
        const int j = jt * 32 + tnl;
        float br[32];
        #pragma unroll
        for (int d4 = 0; d4 < 32; d4 += 4)
            *(float4*)&br[d4] = *(float4*)&bt[tnl][d4];
        #pragma unroll
        for (int r = 0; r < 2; ++r) {
            const int i = i0 + ig * 2 + r;
            float dot = 0.f;
            #pragma unroll
            for (int d = 0; d < 30; ++d) dot = fmaf(ar[r][d], br[d], dot);
            float lg = dot + bpz[((size_t)i * 44 + h) * 512 + j];
            lg += INFV * (ar[r][30] * br[30] - 1.0f);
            abuf[((size_t)h * 512 + i) * 512 + j] = lg;
            float nm = fmaxf(mx[r], lg);
            sm[r] = sm[r] * __expf(mx[r] - nm) + __expf(lg - nm);
            mx[r] = nm;
        }
    }
    #pragma unroll
    for (int off = 1; off < 32; off <<= 1) {
        #pragma unroll
        for (int r = 0; r < 2; ++r) {
            float m2 = __shfl_xor(mx[r], off), s2 = __shfl_xor(sm[r], off);
            float nm = fmaxf(mx[r], m2);
            sm[r] = sm[r] * __expf(mx[r] - nm) + s2 * __expf(m2 - nm);
            mx[r] = nm;
        }
    }
    if (tnl == 0) {
        #pragma unroll
        for (int r = 0; r < 2; ++r) {
            int i = i0 + ig * 2 + r;
            astm[(size_t)h * 512 + i] = mx[r];
            asti[(size_t)h * 512 + i] = 1.0f / sm[r];
        }
    }
}

// ---------------------------------------------------------------- attn_pair
// o_pair from RAW logits: a = exp(raw - m_h)*inv_h applied during staging.
__global__ __launch_bounds__(256) void k_attn_pair(
    const float* __restrict__ abuf, const float* __restrict__ bpz,
    const float* __restrict__ astm, const float* __restrict__ asti,
    float* __restrict__ ocat)
{
    __shared__ float al[12][512];
    __shared__ float mh[12], ih[12];
    const int i = blockIdx.x, t = threadIdx.x;
    if (t < 12) { mh[t] = astm[(size_t)t * 512 + i]; ih[t] = asti[(size_t)t * 512 + i]; }
    __syncthreads();
    #pragma unroll
    for (int u = 0; u < 12; ++u) {
        float r0 = abuf[(size_t)u * 262144 + (size_t)i * 512 + t];
        float r1 = abuf[(size_t)u * 262144 + (size_t)i * 512 + t + 256];
        al[u][t] = __expf(r0 - mh[u]) * ih[u];
        al[u][t + 256] = __expf(r1 - mh[u]) * ih[u];
    }
    __syncthreads();
    const int c = t & 31;
    const int h1 = t >> 5;
    const bool dual = (t < 128);
    const float* pz = bpz + ((size_t)i * 44 + 12 + c) * 512;
    const float* a1 = al[h1];
    const float* a2 = al[dual ? h1 + 8 : 0];
    float acc1 = 0.f, acc2 = 0.f;
    for (int j = 0; j < 512; j += 4) {
        float4 p = *(const float4*)&pz[j];
        acc1 = fmaf(a1[j+0], p.x, acc1);
        acc1 = fmaf(a1[j+1], p.y, acc1);
        acc1 = fmaf(a1[j+2], p.z, acc1);
        acc1 = fmaf(a1[j+3], p.w, acc1);
        if (dual) {
            acc2 = fmaf(a2[j+0], p.x, acc2);
            acc2 = fmaf(a2[j+1], p.y, acc2);
            acc2 = fmaf(a2[j+2], p.z, acc2);
            acc2 = fmaf(a2[j+3], p.w, acc2);
        }
    }
    ocat[(size_t)i * 1152 + 576 + h1 * 32 + c] = acc1;
    if (dual) ocat[(size_t)i * 1152 + 576 + (h1 + 8) * 32 + c] = acc2;
}

// ---------------------------------------------------------------- gemm_ov
// softmax applied during As staging from RAW logits.
__global__ __launch_bounds__(256) void k_gemm_ov(
    const float* __restrict__ abuf, const float* __restrict__ vw,
    const float* __restrict__ vpw, const float* __restrict__ astm,
    const float* __restrict__ asti, float* __restrict__ cbuf)
{
    __shared__ float As[64][68];
    __shared__ float Bs[64][44];
    __shared__ float ms[64], is_[64];
    const int i0 = blockIdx.x * 64, h = blockIdx.y;
    const int t = threadIdx.x;
    const int sr = t >> 4, sk4 = (t & 15) << 2;
    const int r1 = t >> 3;
    const int cb = t & 7;
    if (t < 64) {
        ms[t] = astm[(size_t)h * 512 + i0 + t];
        is_[t] = asti[(size_t)h * 512 + i0 + t];
    }
    float acc[2][5];
    #pragma unroll
    for (int u = 0; u < 5; ++u) { acc[0][u] = 0.f; acc[1][u] = 0.f; }
    for (int kc = 0; kc < 512; kc += 64) {
        __syncthreads();
        #pragma unroll
        for (int rep = 0; rep < 4; ++rep) {
            int row = sr + rep * 16;
            float4 raw = *(const float4*)&abuf[(size_t)h * 262144 +
                                               (size_t)(i0 + row) * 512 + kc + sk4];
            float m = ms[row], iv = is_[row];
            float4 w;
            w.x = __expf(raw.x - m) * iv;
            w.y = __expf(raw.y - m) * iv;
            w.z = __expf(raw.z - m) * iv;
            w.w = __expf(raw.w - m) * iv;
            *(float4*)&As[row][sk4] = w;
        }
        #pragma unroll
        for (int u = 0; u < 10; ++u) {
            int idx = t + u * 256;
            int r = idx / 40, cc = idx % 40;
            Bs[r][cc] = (cc < 16) ? vw[(size_t)(kc + r) * 192 + h * 16 + cc]
                                  : vpw[(size_t)(kc + r) * 288 + h * 24 + (cc - 16)];
        }
        __syncthreads();
        #pragma unroll 4
        for (int kk = 0; kk < 64; ++kk) {
            float av1 = As[r1][kk], av2 = As[r1 + 32][kk];
            #pragma unroll
            for (int u = 0; u < 5; ++u) {
                float b = Bs[kk][cb + 8 * u];
                acc[0][u] = fmaf(av1, b, acc[0][u]);
                acc[1][u] = fmaf(av2, b, acc[1][u]);
            }
        }
    }
    #pragma unroll
    for (int u = 0; u < 5; ++u) {
        cbuf[((size_t)h * 512 + i0 + r1) * 40 + cb + 8 * u] = acc[0][u];
        cbuf[((size_t)h * 512 + i0 + r1 + 32) * 40 + cb + 8 * u] = acc[1][u];
    }
}

// ---------------------------------------------------------------- optfin
__global__ __launch_bounds__(256) void k_optfin(
    const float* __restrict__ cbuf, const float* __restrict__ rots,
    const float* __restrict__ trans, float* __restrict__ ocat)
{
    __shared__ float cl[4][12][40];
    const int i0 = blockIdx.x * 4, t = threadIdx.x;
    for (int idx = t; idx < 1920; idx += 256) {
        int ii = idx / 480, rem = idx % 480;
        int h = rem / 40, c = rem % 40;
        cl[ii][h][c] = cbuf[((size_t)h * 512 + i0 + ii) * 40 + c];
    }
    __syncthreads();
    for (int idx = t; idx < 768; idx += 256) {
        int ii = idx / 192, o = idx % 192;
        ocat[(size_t)(i0 + ii) * 1152 + o] = cl[ii][o >> 4][o & 15];
    }
    for (int idx = t; idx < 384; idx += 256) {
        int ii = idx / 96, hp = idx % 96;
        int h = hp >> 3, p = hp & 7;
        int i = i0 + ii;
        const float* R = &rots[(size_t)i * 9];
        float gx = cl[ii][h][16 + p*3 + 0] - trans[(size_t)i*3 + 0];
        float gy = cl[ii][h][16 + p*3 + 1] - trans[(size_t)i*3 + 1];
        float gz = cl[ii][h][16 + p*3 + 2] - trans[(size_t)i*3 + 2];
        float lx = R[0]*gx + R[3]*gy + R[6]*gz;
        float ly = R[1]*gx + R[4]*gy + R[7]*gz;
        float lz = R[2]*gx + R[5]*gy + R[8]*gz;
        float nm = sqrtf(lx*lx + ly*ly + lz*lz + 1e-8f);
        int col = h * 8 + p;
        size_t base = (size_t)i * 1152;
        ocat[base + 192 + col] = lx;
        ocat[base + 288 + col] = ly;
        ocat[base + 384 + col] = lz;
        ocat[base + 480 + col] = nm;
    }
}

// ---------------------------------------------------------------- tlog
__global__ __launch_bounds__(256) void k_tlog(
    const float* __restrict__ sqw, const float* __restrict__ skv,
    const float* __restrict__ trans, const float* __restrict__ mask,
    const float* __restrict__ sp, const float* __restrict__ smask,
    const float* __restrict__ sbwp, float* __restrict__ logits,
    float* __restrict__ stat_m, float* __restrict__ stat_il)
{
    __shared__ float sk_s[32][16];
    __shared__ float sq_s[32][16];
    __shared__ float trans_s[96];
    __shared__ float mask_s[32];
    __shared__ float spm_s[96];
    __shared__ float smask_s[32];
    const int h = blockIdx.y;
    const int m0 = blockIdx.x * 32;
    const int t = threadIdx.x;
    const int tmg = t >> 5, tnl = t & 31;
    const float sbw = softplusf(sbwp[0]);
    for (int idx = t; idx < 512; idx += 256) {
        int row = idx >> 4, c = idx & 15;
        sk_s[row][c] = skv[(size_t)(m0 + row) * 384 + h * 16 + c];
    }
    if (t < 96) spm_s[t] = sp[(size_t)m0 * 3 + t];
    if (t < 32) smask_s[t] = smask[m0 + t];
    __syncthreads();
    float skr[4][16];
    float spx[4], spy[4], spz[4], smk[4];
    #pragma unroll
    for (int mi = 0; mi < 4; ++mi) {
        int row = tmg * 4 + mi;
        #pragma unroll
        for (int c4 = 0; c4 < 16; c4 += 4)
            *(float4*)&skr[mi][c4] = *(float4*)&sk_s[row][c4];
        spx[mi] = spm_s[row*3+0]; spy[mi] = spm_s[row*3+1]; spz[mi] = spm_s[row*3+2];
        smk[mi] = smask_s[row];
    }
    float mxr[4], lr[4];
    #pragma unroll
    for (int mi = 0; mi < 4; ++mi) { mxr[mi] = -1e30f; lr[mi] = 0.f; }
    for (int nt = 0; nt < 16; ++nt) {
        __syncthreads();
        const int nb = nt * 32;
        if (t < 128) {
            int nn = t >> 2, c4 = (t & 3) << 2;
            *(float4*)&sq_s[nn][c4] = *(const float4*)&sqw[(size_t)(nb + nn) * 192 + h * 16 + c4];
        }
        if (t < 96) trans_s[t] = trans[(size_t)nb * 3 + t];
        if (t < 32) mask_s[t] = mask[nb + t];
        __syncthreads();
        float q[16];
        #pragma unroll
        for (int c4 = 0; c4 < 16; c4 += 4)
            *(float4*)&q[c4] = *(float4*)&sq_s[tnl][c4];
        const float tx = trans_s[tnl*3+0], ty = trans_s[tnl*3+1], tz = trans_s[tnl*3+2];
        const float mkn = mask_s[tnl];
        #pragma unroll
        for (int mi = 0; mi < 4; ++mi) {
            float dot = 0.f;
            #pragma unroll
            for (int c = 0; c < 16; ++c) dot = fmaf(skr[mi][c], q[c], dot);
            float dx = tx - spx[mi], dy = ty - spy[mi], dz = tz - spz[mi];
            float mterm = INFV * (mkn * smk[mi] - 1.0f) - 0.5f * sbw * (dx*dx + dy*dy + dz*dz);
            float lg = fmaf(0.25f, dot, mterm);
            logits[((size_t)(m0 + tmg * 4 + mi) * 12 + h) * 512 + nb + tnl] = lg;
            float newm = fmaxf(mxr[mi], lg);
            lr[mi] = lr[mi] * __expf(mxr[mi] - newm) + __expf(lg - newm);
            mxr[mi] = newm;
        }
    }
    #pragma unroll
    for (int off = 1; off < 32; off <<= 1) {
        #pragma unroll
        for (int mi = 0; mi < 4; ++mi) {
            float m2 = __shfl_xor(mxr[mi], off), l2 = __shfl_xor(lr[mi], off);
            float newm = fmaxf(mxr[mi], m2);
            lr[mi] = lr[mi] * __expf(mxr[mi] - newm) + l2 * __expf(m2 - newm);
            mxr[mi] = newm;
        }
    }
    if (tnl == 0) {
        #pragma unroll
        for (int mi = 0; mi < 4; ++mi) {
            int m = m0 + tmg * 4 + mi;
            stat_m[(size_t)m * 12 + h] = mxr[mi];
            stat_il[(size_t)m * 12 + h] = 1.0f / lr[mi];
        }
    }
}

// ---------------------------------------------------------------- rstat
__global__ __launch_bounds__(256) void k_rstat(
    const float* __restrict__ lbuf, float* __restrict__ rspm,
    float* __restrict__ rsps)
{
    __shared__ float smx[4][64], ssm[4][64];
    const int n0 = blockIdx.x * 64, mc = blockIdx.y, h = blockIdx.z;
    const int t = threadIdx.x, ln = t & 63, mg = t >> 6;
    const int mb = mc * 512;
    const int n = n0 + ln;
    float mx = -1e30f, sm = 0.f;
    #pragma unroll 2
    for (int it = 0; it < 128; ++it) {
        int m = mb + it * 4 + mg;
        float lg = lbuf[((size_t)m * 12 + h) * 512 + n];
        float nm = fmaxf(mx, lg);
        sm = sm * __expf(mx - nm) + __expf(lg - nm);
        mx = nm;
    }
    smx[mg][ln] = mx; ssm[mg][ln] = sm;
    __syncthreads();
    if (t < 64) {
        float M = smx[0][t], S = ssm[0][t];
        #pragma unroll
        for (int g = 1; g < 4; ++g) {
            float m2 = smx[g][t], s2 = ssm[g][t];
            float nm = fmaxf(M, m2);
            S = S * __expf(M - nm) + s2 * __expf(m2 - nm);
            M = nm;
        }
        rspm[((size_t)h * 4 + mc) * 512 + n0 + t] = M;
        rsps[((size_t)h * 4 + mc) * 512 + n0 + t] = S;
    }
}

// ---------------------------------------------------------------- rcomb
__global__ __launch_bounds__(256) void k_rcomb(
    const float* __restrict__ rspm, const float* __restrict__ rsps,
    float* __restrict__ rmax, float* __restrict__ rinv)
{
    int gid = blockIdx.x * 256 + threadIdx.x;
    if (gid >= 6144) return;
    int h = gid >> 9, n = gid & 511;
    float M = -1e30f, S = 0.f;
    #pragma unroll
    for (int mc = 0; mc < 4; ++mc) {
        float m2 = rspm[((size_t)h * 4 + mc) * 512 + n];
        float s2 = rsps[((size_t)h * 4 + mc) * 512 + n];
        float nm = fmaxf(M, m2);
        S = S * __expf(M - nm) + s2 * __expf(m2 - nm);
        M = nm;
    }
    rmax[gid] = M;
    rinv[gid] = 1.0f / S;
}

// ---------------------------------------------------------------- pv
__global__ __launch_bounds__(256) void k_pv(
    const float* __restrict__ lbuf, const float* __restrict__ skv,
    const float* __restrict__ rmax, const float* __restrict__ rinv,
    float* __restrict__ pvp)
{
    __shared__ float sv_s[512][17];
    const int n0 = blockIdx.x * 64, mc = blockIdx.y, h = blockIdx.z;
    const int t = threadIdx.x, ln = t & 63, mg = t >> 6;
    const int mb = mc * 512;
    for (int idx = t; idx < 2048; idx += 256) {
        int ml = idx >> 2, c4 = (idx & 3) << 2;
        float4 v4 = *(const float4*)&skv[(size_t)(mb + ml) * 384 + 192 + h * 16 + c4];
        sv_s[ml][c4+0]=v4.x; sv_s[ml][c4+1]=v4.y; sv_s[ml][c4+2]=v4.z; sv_s[ml][c4+3]=v4.w;
    }
    const int n = n0 + ln;
    const float rm = rmax[h * 512 + n], ri = rinv[h * 512 + n];
    float acc[16];
    #pragma unroll
    for (int c = 0; c < 16; ++c) acc[c] = 0.f;
    __syncthreads();
    #pragma unroll 2
    for (int it = 0; it < 128; ++it) {
        int ml = it * 4 + mg;
        float w = __expf(lbuf[((size_t)(mb + ml) * 12 + h) * 512 + n] - rm) * ri;
        #pragma unroll
        for (int c = 0; c < 16; ++c) acc[c] = fmaf(w, sv_s[ml][c], acc[c]);
    }
    __syncthreads();
    float* red = &sv_s[0][0];
    #pragma unroll
    for (int c = 0; c < 16; ++c) red[(mg * 64 + ln) * 17 + c] = acc[c];
    __syncthreads();
    {
        int nl = t >> 2, c4 = (t & 3) << 2;
        float4 o;
        #pragma unroll
        for (int e = 0; e < 4; ++e) {
            float s = 0.f;
            #pragma unroll
            for (int g = 0; g < 4; ++g) s += red[(g * 64 + nl) * 17 + c4 + e];
            (&o.x)[e] = s;
        }
        *(float4*)&pvp[(((size_t)h * 4 + mc) * 512 + n0 + nl) * 16 + c4] = o;
    }
}

// ---------------------------------------------------------------- pvcomb
__global__ __launch_bounds__(256) void k_pvcomb(
    const float* __restrict__ pvp, float* __restrict__ ocat)
{
    int gid = blockIdx.x * 256 + threadIdx.x;
    int n = gid / 192, rem = gid % 192;
    float o = 0.f;
    #pragma unroll
    for (int mc = 0; mc < 4; ++mc)
        o += pvp[(((size_t)(rem >> 4) * 4 + mc) * 512 + n) * 16 + (rem & 15)];
    ocat[(size_t)n * 1152 + 960 + rem] = o;
}

// ---------------------------------------------------------------- tw
__global__ __launch_bounds__(256) void k_tw(
    const float* __restrict__ logits, const float* __restrict__ stat_m,
    const float* __restrict__ stat_il, float* __restrict__ w)
{
    __shared__ float mxs[12], ils[12];
    const int m = blockIdx.x, t = threadIdx.x;
    if (t < 12) { mxs[t] = stat_m[(size_t)m * 12 + t]; ils[t] = stat_il[(size_t)m * 12 + t]; }
    __syncthreads();
    const float* lp = logits + (size_t)m * 12 * 512;
    float a0 = 0.f, a1 = 0.f;
    #pragma unroll
    for (int h = 0; h < 12; ++h) {
        a0 += __expf(lp[h * 512 + t] - mxs[h]) * ils[h];
        a1 += __expf(lp[h * 512 + 256 + t] - mxs[h]) * ils[h];
    }
    w[(size_t)m * 512 + t] = a0 * (1.0f / 12.0f);
    w[(size_t)m * 512 + 256 + t] = a1 * (1.0f / 12.0f);
}

// ---------------------------------------------------------------- surf out
__global__ __launch_bounds__(256) void k_surf_out(
    const float* __restrict__ sfeat, const float* __restrict__ saggw,
    const float* __restrict__ Wso, const float* __restrict__ bso,
    float* __restrict__ out)
{
    __shared__ float wl[12304];
    const int t = threadIdx.x;
    for (int idx = t; idx < 12288; idx += 256) {
        int k = idx >> 4, c = idx & 15;
        wl[(k / 192) * 3076 + (k % 192) * 16 + c] = Wso[idx];
    }
    const int m = blockIdx.x * 64 + (t >> 2);
    const int kq = t & 3;
    const float* src = (kq < 2) ? &sfeat[(size_t)m * 384 + kq * 192]
                                : &saggw[(size_t)m * 384 + (kq - 2) * 192];
    __syncthreads();
    float acc[16];
    #pragma unroll
    for (int c = 0; c < 16; ++c) acc[c] = 0.f;
    const float* wb = &wl[kq * 3076];
    for (int k = 0; k < 192; k += 4) {
        float4 v = *(const float4*)&src[k];
        #pragma unroll
        for (int e = 0; e < 4; ++e) {
            float sv = (&v.x)[e];
            #pragma unroll
            for (int c = 0; c < 16; ++c)
                acc[c] = fmaf(sv, wb[(k + e) * 16 + c], acc[c]);
        }
    }
    #pragma unroll
    for (int c = 0; c < 16; ++c) {
        acc[c] += __shfl_xor(acc[c], 1);
        acc[c] += __shfl_xor(acc[c], 2);
    }
    #pragma unroll
    for (int c = 0; c < 16; ++c) {
        if ((c >> 2) == kq) out[196608 + (size_t)m * 16 + c] = acc[c] + bso[c];
    }
}

// ----------------------------------------------------------------
extern "C" void kernel_launch(void* const* d_in, const int* in_sizes, int n_in,
                              void* d_out, int out_size, void* d_ws, size_t ws_size,
                              hipStream_t stream)
{
    (void)in_sizes; (void)n_in; (void)out_size; (void)ws_size;
    const float* s     = (const float*)d_in[0];
    const float* z     = (const float*)d_in[1];
    const float* rots  = (const float*)d_in[2];
    const float* trans = (const float*)d_in[3];
    const float* mask  = (const float*)d_in[4];
    const float* sp    = (const float*)d_in[5];
    const float* sf    = (const float*)d_in[6];
    const float* smask = (const float*)d_in[7];
    const float* Wq    = (const float*)d_in[8];  const float* bq   = (const float*)d_in[9];
    const float* Wkv   = (const float*)d_in[10]; const float* bkv  = (const float*)d_in[11];
    const float* Wqp   = (const float*)d_in[12]; const float* bqp  = (const float*)d_in[13];
    const float* Wkvp  = (const float*)d_in[14]; const float* bkvp = (const float*)d_in[15];
    const float* Wse   = (const float*)d_in[16]; const float* bse  = (const float*)d_in[17];
    const float* Wsq   = (const float*)d_in[18]; const float* bsq  = (const float*)d_in[19];
    const float* Wsk   = (const float*)d_in[20]; const float* bsk  = (const float*)d_in[21];
    const float* Wsv   = (const float*)d_in[22]; const float* bsv  = (const float*)d_in[23];
    const float* Wb    = (const float*)d_in[24]; const float* bb   = (const float*)d_in[25];
    const float* Wdz   = (const float*)d_in[26]; const float* bdz  = (const float*)d_in[27];
    const float* hw    = (const float*)d_in[28]; const float* sbw  = (const float*)d_in[29];
    const float* Wout  = (const float*)d_in[30]; const float* bout = (const float*)d_in[31];
    const float* Wso   = (const float*)d_in[32]; const float* bso  = (const float*)d_in[33];
    float* out = (float*)d_out;

    float* qw    = (float*)d_ws;
    float* kw    = qw    + (size_t)512 * 192;
    float* vw    = kw    + (size_t)512 * 192;
    float* sqw   = vw    + (size_t)512 * 192;
    float* qpw   = sqw   + (size_t)512 * 192;
    float* kpw   = qpw   + (size_t)512 * 144;
    float* vpw   = kpw   + (size_t)512 * 144;
    float* sfeat = vpw   + (size_t)512 * 288;
    float* skv   = sfeat + (size_t)2048 * 384;
    float* ocat  = skv   + (size_t)2048 * 384;
    float* sagg  = ocat  + (size_t)512 * 1152;
    // region: proj (688K fl) -> bpz (11.5M fl) -> logits (12.6M fl), stream-serialized
    float* region = sagg + (size_t)2048 * 384;
    float* proj   = region;
    float* bpz    = region;
    float* logits = region;
    float* wt1   = region + (size_t)2048 * 12 * 512;
    float* wt2   = wt1   + (size_t)1344 * 384;
    float* wt3   = wt2   + (size_t)384 * 384;
    float* b1    = wt3   + (size_t)384 * 1152;
    float* b2    = b1    + 1344;
    float* st    = b2    + 384;
    float* wbuf  = st    + (size_t)384 * 512;
    float* statm = wbuf  + (size_t)2048 * 512;
    float* stati = statm + (size_t)2048 * 12;
    float* abuf  = stati + (size_t)2048 * 12;      // a[12][512][512] (raw logits)
    float* cbuf  = abuf  + (size_t)12 * 512 * 512; // c[12][512][40]
    float* wz    = cbuf  + (size_t)12 * 512 * 40;  // Wz[44][128]
    float* bz    = wz    + (size_t)44 * 128;       // bz[44]
    float* rspm  = bz    + 64;                     // [12][4][512]
    float* rsps  = rspm  + (size_t)12 * 4 * 512;
    float* rmax  = rsps  + (size_t)12 * 4 * 512;   // [12][512]
    float* rinv  = rmax  + (size_t)12 * 512;
    float* pvp   = rinv  + (size_t)12 * 512;       // [12][4][512][16]
    float* aq    = pvp   + (size_t)12 * 4 * 512 * 16; // [12][512][32]
    float* ak    = aq    + (size_t)12 * 512 * 32;
    float* astm  = ak    + (size_t)12 * 512 * 32;  // [12][512]
    float* asti  = astm  + (size_t)12 * 512;

    k_pack<<<dim3(1099), dim3(256), 0, stream>>>(Wq, Wsq, Wkv, Wqp, Wkvp, Wsk, Wsv, Wout,
        bq, bsq, bkv, bqp, bkvp, bsk, bsv, wt1, wt2, wt3, b1, b2);
    k_packz<<<dim3(23), dim3(256), 0, stream>>>(Wb, bb, Wdz, bdz, wz, bz);
    k_transp<<<dim3(12, 16), dim3(256), 0, stream>>>(s, st);
    k_gemm<384, true><<<dim3(21, 8), dim3(256), 0, stream>>>(s, wt1, b1, proj, 1344);
    k_scatter<<<dim3(128), dim3(256), 0, stream>>>(proj, rots, trans,
        qw, kw, vw, sqw, qpw, kpw, vpw);
    k_aprep<<<dim3(512), dim3(256), 0, stream>>>(qw, qpw, kw, kpw, mask, hw, aq, ak);
    k_sfeat<<<dim3(256), dim3(256), 0, stream>>>(sf, Wse, bse, sfeat);
    k_gemm<384, true><<<dim3(6, 32), dim3(256), 0, stream>>>(sfeat, wt2, b2, skv, 384);
    k_zpass<<<dim3(1024), dim3(256), 0, stream>>>(z, wz, bz, bpz);
    k_attn_a<<<dim3(32, 12), dim3(256), 0, stream>>>(aq, ak, bpz, abuf, astm, asti);
    k_attn_pair<<<dim3(512), dim3(256), 0, stream>>>(abuf, bpz, astm, asti, ocat);
    k_gemm_ov<<<dim3(8, 12), dim3(256), 0, stream>>>(abuf, vw, vpw, astm, asti, cbuf);
    k_optfin<<<dim3(128), dim3(256), 0, stream>>>(cbuf, rots, trans, ocat);
    k_tlog<<<dim3(64, 12), dim3(256), 0, stream>>>(sqw, skv, trans, mask, sp, smask,
        sbw, logits, statm, stati);
    k_rstat<<<dim3(8, 4, 12), dim3(256), 0, stream>>>(logits, rspm, rsps);
    k_rcomb<<<dim3(24), dim3(256), 0, stream>>>(rspm, rsps, rmax, rinv);
    k_pv<<<dim3(8, 4, 12), dim3(256), 0, stream>>>(logits, skv, rmax, rinv, pvp);
    k_pvcomb<<<dim3(384), dim3(256), 0, stream>>>(pvp, ocat);
    k_tw<<<dim3(2048), dim3(256), 0, stream>>>(logits, statm, stati, wbuf);
    k_gemm<512, false><<<dim3(6, 32), dim3(256), 0, stream>>>(wbuf, st, nullptr, sagg, 384);
    k_surf_out<<<dim3(32), dim3(256), 0, stream>>>(sfeat, sagg, Wso, bso, out);
    k_gemm<1152, true><<<dim3(6, 8), dim3(256), 0, stream>>>(ocat, wt3, bout, out, 384);
}